// Round 9
// baseline (333.364 us; speedup 1.0000x reference)
//
#include <hip/hip_runtime.h>
#include <cmath>

// ---------------------------------------------------------------------------
// GraphTransformer on MI355X.  N=8192, D=128, k=7, OUT=1.
// Attention: split-bf16 (hi/lo) MFMA flash, fixed max (logits bounded).
//   FROZEN config (every deviation regressed):
//   - QK^T 3-term split (round-10: plain bf16 QK flips kNN neighbors)
//   - NO register prefetch of K tiles (round-8 spills) -- global_load_lds
//   - PSTR=40 row stride for P (round-12)
//   - swapped QK^T (A=K,B=Q) + packed-b64 P round-trip (r15)
//   - branchless med3 top-K insert in kNN (r16)
//   - cross-tile PV pipeline (r17); cvt_pk exp pack (r20, VALU -4pts)
//   - ANS=8 / grid 512 (r19 ERRATum: finer key-split didn't raise occupancy)
//   - r20 falsifier FIRED: VALU cut moved dur <1us -> window is stall-bound
//     at the __syncthreads vmcnt(0) drains, not issue-bound.
// Round-21 (this round): T4 counted-vmcnt pipeline.  K/V double-buffered
// again (74KB LDS is free: occupancy grid-limited at 2 blocks/CU), K staged
// TWO windows ahead, V one ahead.  __syncthreads replaced by:
//   barrier1 = s_waitcnt lgkmcnt(0); s_barrier        (reads retired)
//   barrier2 = s_waitcnt vmcnt(8);   s_barrier        (K(t+1),V(t) landed;
//              K(t+2),V(t+1) stay IN FLIGHT across the barrier)
// -> staged loads get a full window (~7Kcyc) to land instead of ~400cyc.
// sched_barrier(0) after every barrier; "memory"-clobbered waitcnts.
// Bit-identical numerics (same data, same MFMA order).
// kNN: swapped-operand bf16 MFMA, per-lane register top-10 (u32-packed),
// in-kernel lq-merge -> candV, parallel final merge, exact fp32 re-rank.
// GCN tail: fp32 VALU, gather1+m2 fused.
// ---------------------------------------------------------------------------

typedef unsigned short ushort_t;

constexpr int   NN    = 8192;
constexpr int   DD    = 128;
constexpr int   KNB   = 7;
constexpr int   NL    = 10;              // per-lane kept candidates (knn)
constexpr int   NCAND = 12;              // merged candidates per node
constexpr float SCALE = 0.088388347648318447f;   // 1/sqrt(128)

using bf16x8 = __attribute__((ext_vector_type(8))) short;   // 8 bf16 = 4 VGPR
using f32x4  = __attribute__((ext_vector_type(4))) float;   // mfma acc

#define MFMA16(a, b, c) __builtin_amdgcn_mfma_f32_16x16x32_bf16((a), (b), (c), 0, 0, 0)

__device__ __forceinline__ ushort_t f2b(float f) {
    union { float f; unsigned int u; } v; v.f = f;
    return (ushort_t)((v.u + 0x8000u) >> 16);
}
__device__ __forceinline__ float b2f(ushort_t h) {
    union { unsigned int u; float f; } v; v.u = ((unsigned int)h) << 16;
    return v.f;
}

// direct global->LDS copy, 16B per lane; LDS dest is wave-uniform base + lane*16
__device__ __forceinline__ void gload16(const void* g, void* l) {
    __builtin_amdgcn_global_load_lds(
        (const __attribute__((address_space(1))) unsigned int*)g,
        (__attribute__((address_space(3))) unsigned int*)l, 16, 0, 0);
}

__device__ __forceinline__ unsigned umin_(unsigned a, unsigned b) { return a < b ? a : b; }
__device__ __forceinline__ unsigned umax_(unsigned a, unsigned b) { return a > b ? a : b; }

// Branchless top-K keep-smallest insert into ASCENDING sorted list
// (a[0] best .. a[K-1] worst).  med3 identity: since a[p-1] <= a[p],
//   new a[p] = med3(x, a[p-1], a[p]) = min(max(x, a[p-1]), a[p]).
// Kept SET identical to a guarded strict-less shift insert.  2 VALU
// ops/element, no branch, no divergence.
template<int K>
__device__ __forceinline__ void ins_asc(unsigned* a, unsigned x)
{
    #pragma unroll
    for (int p = K - 1; p >= 1; --p)
        a[p] = umin_(umax_(x, a[p - 1]), a[p]);
    a[0] = umin_(a[0], x);
}

// ---------------- projections: Q,K (split bf16), V (f32), skip (f32) -------
__global__ __launch_bounds__(128)
void proj_kernel(const float* __restrict__ x,
                 const float* __restrict__ Wq, const float* __restrict__ bq,
                 const float* __restrict__ Wk, const float* __restrict__ bk,
                 const float* __restrict__ Wv, const float* __restrict__ bv,
                 const float* __restrict__ Ws, const float* __restrict__ bs,
                 ushort_t* __restrict__ Qhi, ushort_t* __restrict__ Qlo,
                 ushort_t* __restrict__ Khi, ushort_t* __restrict__ Klo,
                 float* __restrict__ Vf, float* __restrict__ HS)
{
    __shared__ float xs[4][DD];
    const int i0 = blockIdx.x * 4, t = threadIdx.x;
    #pragma unroll
    for (int r = 0; r < 4; ++r) xs[r][t] = x[(i0 + r) * DD + t];
    __syncthreads();
    float aq[4] = {0,0,0,0}, ak[4] = {0,0,0,0}, av[4] = {0,0,0,0}, ah[4] = {0,0,0,0};
    #pragma unroll 4
    for (int c = 0; c < DD; ++c) {
        const float wq = Wq[c * DD + t], wk = Wk[c * DD + t];
        const float wv = Wv[c * DD + t], ws = Ws[c * DD + t];
        #pragma unroll
        for (int r = 0; r < 4; ++r) {
            const float xv = xs[r][c];
            aq[r] = fmaf(xv, wq, aq[r]); ak[r] = fmaf(xv, wk, ak[r]);
            av[r] = fmaf(xv, wv, av[r]); ah[r] = fmaf(xv, ws, ah[r]);
        }
    }
    #pragma unroll
    for (int r = 0; r < 4; ++r) {
        const int o = (i0 + r) * DD + t;
        const float q = aq[r] + bq[t];
        const float k = ak[r] + bk[t];
        const ushort_t qh = f2b(q); Qhi[o] = qh; Qlo[o] = f2b(q - b2f(qh));
        const ushort_t kh = f2b(k); Khi[o] = kh; Klo[o] = f2b(k - b2f(kh));
        Vf[o] = av[r] + bv[t];
        HS[o] = ah[r] + bs[t];
    }
}

// ---------------- V transpose + split: VT{hi,lo}[f][n] = split(V[n][f]) ----
__global__ __launch_bounds__(256)
void vt_kernel(const float* __restrict__ Vf,
               ushort_t* __restrict__ VThi, ushort_t* __restrict__ VTlo)
{
    __shared__ float tile[64 * 132];
    const int k0 = blockIdx.x * 64, t = threadIdx.x;
    #pragma unroll
    for (int p = 0; p < 8; ++p) {
        const int slot = t + p * 256;        // 2048 slots: 64 rows x 32 f4-chunks
        const int r = slot >> 5, c4 = slot & 31;
        *reinterpret_cast<float4*>(&tile[r * 132 + c4 * 4]) =
            *reinterpret_cast<const float4*>(Vf + (k0 + r) * DD + c4 * 4);
    }
    __syncthreads();
    #pragma unroll
    for (int p = 0; p < 4; ++p) {
        const int slot = t + p * 256;        // 1024 slots: 128 feats x 8 chunks
        const int f = slot >> 3, kc = slot & 7;
        ushort_t hh[8], ll[8];
        #pragma unroll
        for (int i = 0; i < 8; ++i) {
            const float v = tile[(kc * 8 + i) * 132 + f];
            hh[i] = f2b(v); ll[i] = f2b(v - b2f(hh[i]));
        }
        *reinterpret_cast<uint4*>(VThi + f * NN + k0 + kc * 8) =
            *reinterpret_cast<const uint4*>(hh);
        *reinterpret_cast<uint4*>(VTlo + f * NN + k0 + kc * 8) =
            *reinterpret_cast<const uint4*>(ll);
    }
}

// ---------------- split-bf16 MFMA flash attention, fixed max ---------------
// 256-thread blocks (4 waves x 32 queries = 128 queries/block), grid 512.
// K/V DOUBLE-buffered via global_load_lds; K staged 2 windows ahead, V 1.
// Counted-vmcnt barriers (never 0 mid-loop); 2 blocks/CU.
constexpr int ANS  = 8;                 // key slices
constexpr int AKS  = NN / ANS;          // 1024 keys per slice
constexpr int BK   = 32;                // keys per tile
constexpr int PSTR = 40;                // P row stride (frozen)
constexpr int KSTR = 136;               // (knn kernel LDS stride; unchanged)

__global__ __launch_bounds__(256, 2)
void attn_kernel(const ushort_t* __restrict__ Qhi, const ushort_t* __restrict__ Qlo,
                 const ushort_t* __restrict__ Khg, const ushort_t* __restrict__ Klg,
                 const ushort_t* __restrict__ Vhg, const ushort_t* __restrict__ Vlg,
                 float* __restrict__ Opart, float* __restrict__ lpart)
{
    // K tiles: 32 rows x 128 bf16, linear rows; chunk XOR-swizzled (c^row&7)
    //          on global source + read side -> conflict-free ds_read_b128.
    // V tiles: 128 rows x 32 bf16, chunk XOR-swizzled (c^(row>>1)&3).
    // P strip: 16 rows x PSTR per wave (row = query lc; sub0/sub1 reuse).
    // Buffer map: K(t) in K?s[t&1], V(t) in V?s[t&1].
    __shared__ __align__(16) ushort_t Khs[2][BK * DD];
    __shared__ __align__(16) ushort_t Kls[2][BK * DD];
    __shared__ __align__(16) ushort_t Vhs[2][DD * BK];
    __shared__ __align__(16) ushort_t Vls[2][DD * BK];
    __shared__ __align__(16) ushort_t Phs[4][16 * PSTR];
    __shared__ __align__(16) ushort_t Pls[4][16 * PSTR];

    const int t  = threadIdx.x;
    const int w  = t >> 6, l = t & 63;
    const int lc = l & 15, lq = l >> 4;
    const int b  = blockIdx.x;
    const int s  = b >> 6;              // slice 0..7
    const int qb = b & 63;
    const int i0 = qb * 128;
    const int k0 = s * AKS;
    ushort_t* Pwh = Phs[w];
    ushort_t* Pwl = Pls[w];

    // staging coordinates (per thread, loop-invariant).
    const int lrK = w * 4 + (l >> 4);
    const int kchunk = ((l & 15) ^ (lrK & 7)) * 8;
    const ushort_t* gKh = Khg + (size_t)(k0 + lrK) * DD + kchunk;
    const ushort_t* gKl = Klg + (size_t)(k0 + lrK) * DD + kchunk;
    const int lrV = w * 16 + (l >> 2);
    const int vchunk = ((l & 3) ^ ((l >> 3) & 3)) * 8;
    const ushort_t* gVh = Vhg + (size_t)lrV * NN + k0 + vchunk;
    const ushort_t* gVl = Vlg + (size_t)lrV * NN + k0 + vchunk;

#define STAGE_K(buf, koff) do {                                              \
    gload16(gKh + (size_t)(koff) * DD,        &Khs[buf][(w * 4) * DD]);      \
    gload16(gKh + (size_t)((koff) + 16) * DD, &Khs[buf][(16 + w * 4) * DD]); \
    gload16(gKl + (size_t)(koff) * DD,        &Kls[buf][(w * 4) * DD]);      \
    gload16(gKl + (size_t)((koff) + 16) * DD, &Kls[buf][(16 + w * 4) * DD]); \
  } while (0)
#define STAGE_V(buf, koff) do {                                              \
    gload16(gVh + (koff),                     &Vhs[buf][(w * 16) * BK]);     \
    gload16(gVh + (size_t)64 * NN + (koff),   &Vhs[buf][(64 + w * 16) * BK]);\
    gload16(gVl + (koff),                     &Vls[buf][(w * 16) * BK]);     \
    gload16(gVl + (size_t)64 * NN + (koff),   &Vls[buf][(64 + w * 16) * BK]);\
  } while (0)
#define LGKM0() asm volatile("s_waitcnt lgkmcnt(0)" ::: "memory")
#define VMW(n)  asm volatile("s_waitcnt vmcnt(" #n ")" ::: "memory")
#define BARRIER() do { __builtin_amdgcn_s_barrier(); \
                       __builtin_amdgcn_sched_barrier(0); } while (0)

    bf16x8 qh[2][4], ql[2][4];
    #pragma unroll
    for (int sub = 0; sub < 2; ++sub) {
        const int row = i0 + w * 32 + sub * 16 + lc;
        #pragma unroll
        for (int kb = 0; kb < 4; ++kb) {
            qh[sub][kb] = *reinterpret_cast<const bf16x8*>(Qhi + row * DD + kb * 32 + lq * 8);
            ql[sub][kb] = *reinterpret_cast<const bf16x8*>(Qlo + row * DD + kb * 32 + lq * 8);
        }
    }

    const f32x4 zz = {0.f, 0.f, 0.f, 0.f};
    f32x4 oacc[2][8];
    #pragma unroll
    for (int sub = 0; sub < 2; ++sub)
        #pragma unroll
        for (int ft = 0; ft < 8; ++ft) oacc[sub][ft] = zz;
    float lrow[2] = {0.f, 0.f};         // per-lane partial denom, query = lc

    bf16x8 pah[2] = {}, pal[2] = {};    // carried P fragments (tile t-1)
    const int vc = (lq ^ ((lc >> 1) & 3)) * 8;   // V read-side unswizzle

    // prologue: K(0), K(1), V(0) issued; wait K(0) (allow 8 newer in flight)
    STAGE_K(0, 0);
    STAGE_K(1, BK);
    STAGE_V(0, 0);
    VMW(8);
    BARRIER();

    constexpr int NT = AKS / BK;        // 32 tiles
    for (int it = 0; it < NT; ++it) {
        const int jt  = k0 + it * BK;
        const int cur = it & 1;
        const ushort_t* Kh = Khs[cur];
        const ushort_t* Kl = Kls[cur];
        const ushort_t* Vph = Vhs[cur ^ 1];   // V(t-1)
        const ushort_t* Vpl = Vls[cur ^ 1];

        // ---- S^T = K Q^T (swapped: A=K, B=Q; bit-identical products) ----
        f32x4 sacc[2][2];               // [sub][kt]
        #pragma unroll
        for (int sub = 0; sub < 2; ++sub)
            #pragma unroll
            for (int kt = 0; kt < 2; ++kt) sacc[sub][kt] = zz;
        __builtin_amdgcn_s_setprio(1);
        #pragma unroll
        for (int kt = 0; kt < 2; ++kt) {
            const int kro = (kt * 16 + lc) * DD;
            #pragma unroll
            for (int kb = 0; kb < 4; ++kb) {
                const int cp = ((kb * 4 + lq) ^ (lc & 7)) * 8;  // read-side unswizzle
                const bf16x8 kh = *reinterpret_cast<const bf16x8*>(&Kh[kro + cp]);
                const bf16x8 kl = *reinterpret_cast<const bf16x8*>(&Kl[kro + cp]);
                #pragma unroll
                for (int sub = 0; sub < 2; ++sub) {
                    sacc[sub][kt] = MFMA16(kh, qh[sub][kb], sacc[sub][kt]);
                    sacc[sub][kt] = MFMA16(kh, ql[sub][kb], sacc[sub][kt]);
                    sacc[sub][kt] = MFMA16(kl, qh[sub][kb], sacc[sub][kt]);
                }
            }
        }
        __builtin_amdgcn_s_setprio(0);

        // ---- O += P(t-1) V(t-1) ----
        if (it > 0) {
            __builtin_amdgcn_s_setprio(1);
            #pragma unroll
            for (int ft = 0; ft < 8; ++ft) {
                const bf16x8 vh = *reinterpret_cast<const bf16x8*>(
                    &Vph[(ft * 16 + lc) * BK + vc]);
                const bf16x8 vl = *reinterpret_cast<const bf16x8*>(
                    &Vpl[(ft * 16 + lc) * BK + vc]);
                #pragma unroll
                for (int sub = 0; sub < 2; ++sub) {
                    oacc[sub][ft] = MFMA16(pah[sub], vh, oacc[sub][ft]);
                    oacc[sub][ft] = MFMA16(pal[sub], vh, oacc[sub][ft]);
                    oacc[sub][ft] = MFMA16(pah[sub], vl, oacc[sub][ft]);
                }
            }
            __builtin_amdgcn_s_setprio(0);
        }

        // barrier1: all waves' K(t)/V(t-1) ds_reads retired (lgkm only —
        // staged loads stay in flight).
        LGKM0();
        BARRIER();

        // deep prefetch: K(t+2) overwrites K(t)'s buffer (reads retired);
        // V(t+1) overwrites V(t-1)'s buffer (reads retired).
        if (it <= NT - 3) STAGE_K(cur, (it + 2) * BK);
        if (it <= NT - 2) STAGE_V(cur ^ 1, (it + 1) * BK);

        if ((jt & ~127) == i0) {            // diagonal mask
            #pragma unroll
            for (int sub = 0; sub < 2; ++sub) {
                const int gq = i0 + w * 32 + sub * 16 + lc;
                #pragma unroll
                for (int kt = 0; kt < 2; ++kt)
                    #pragma unroll
                    for (int r = 0; r < 4; ++r) {
                        const int gk = jt + kt * 16 + lq * 4 + r;
                        if (gk == gq) sacc[sub][kt][r] = -INFINITY;
                    }
            }
        }
        // ---- P = exp(S*SCALE): cvt_pk split; b64 write, b128 read to regs
        #pragma unroll
        for (int sub = 0; sub < 2; ++sub) {
            #pragma unroll
            for (int kt = 0; kt < 2; ++kt) {
                unsigned wh[2], wl[2];
                #pragma unroll
                for (int rr = 0; rr < 2; ++rr) {
                    const float p0 = __expf(sacc[sub][kt][rr * 2 + 0] * SCALE);
                    const float p1 = __expf(sacc[sub][kt][rr * 2 + 1] * SCALE);
                    lrow[sub] += p0;
                    lrow[sub] += p1;
                    unsigned hpk;
                    asm("v_cvt_pk_bf16_f32 %0, %1, %2"
                        : "=v"(hpk) : "v"(p0), "v"(p1));
                    wh[rr] = hpk;
                    const float h0 = __uint_as_float(hpk << 16);
                    const float h1 = __uint_as_float(hpk & 0xFFFF0000u);
                    unsigned lpk;
                    asm("v_cvt_pk_bf16_f32 %0, %1, %2"
                        : "=v"(lpk) : "v"(p0 - h0), "v"(p1 - h1));
                    wl[rr] = lpk;
                }
                const int eo = lc * PSTR + kt * 16 + lq * 4;
                *reinterpret_cast<uint2*>(&Pwh[eo]) = make_uint2(wh[0], wh[1]);
                *reinterpret_cast<uint2*>(&Pwl[eo]) = make_uint2(wl[0], wl[1]);
            }
            pah[sub] = *reinterpret_cast<const bf16x8*>(&Pwh[lc * PSTR + lq * 8]);
            pal[sub] = *reinterpret_cast<const bf16x8*>(&Pwl[lc * PSTR + lq * 8]);
        }

        // barrier2: K(t+1), V(t) landed block-wide; K(t+2)/V(t+1) (the 8
        // newest loads) stay in flight across the barrier.
        if (it <= NT - 3)      { VMW(8); }
        else if (it == NT - 2) { VMW(4); }
        else                   { VMW(0); }
        BARRIER();
    }
    // ---- epilogue: PV(NT-1); V(NT-1) in buffer (NT-1)&1 ----
    {
        const ushort_t* Vh = Vhs[(NT - 1) & 1];
        const ushort_t* Vl = Vls[(NT - 1) & 1];
        #pragma unroll
        for (int ft = 0; ft < 8; ++ft) {
            const bf16x8 vh = *reinterpret_cast<const bf16x8*>(
                &Vh[(ft * 16 + lc) * BK + vc]);
            const bf16x8 vl = *reinterpret_cast<const bf16x8*>(
                &Vl[(ft * 16 + lc) * BK + vc]);
            #pragma unroll
            for (int sub = 0; sub < 2; ++sub) {
                oacc[sub][ft] = MFMA16(pah[sub], vh, oacc[sub][ft]);
                oacc[sub][ft] = MFMA16(pal[sub], vh, oacc[sub][ft]);
                oacc[sub][ft] = MFMA16(pah[sub], vl, oacc[sub][ft]);
            }
        }
    }
#undef STAGE_K
#undef STAGE_V
#undef LGKM0
#undef VMW
#undef BARRIER

    // denom: lane holds partial for query=lc over keys lq*4+r; reduce over lq.
    #pragma unroll
    for (int sub = 0; sub < 2; ++sub) {
        float ps = lrow[sub];
        ps += __shfl_xor(ps, 16, 64);
        ps += __shfl_xor(ps, 32, 64);
        lrow[sub] = ps;
    }
    #pragma unroll
    for (int sub = 0; sub < 2; ++sub) {
        #pragma unroll
        for (int r = 0; r < 4; ++r) {
            const int row = i0 + w * 32 + sub * 16 + lq * 4 + r;
            float* po = Opart + ((size_t)s * NN + row) * DD;
            #pragma unroll
            for (int ft = 0; ft < 8; ++ft) po[ft * 16 + lc] = oacc[sub][ft][r];
        }
        if (l < 16)
            lpart[s * NN + i0 + w * 32 + sub * 16 + l] = lrow[sub];
    }
}

// ------- merge slices + skip, emit H (in-place over HS), Hhi, SQ -----------
// float4-vectorized: 32 threads per node, 4 features per thread.
__global__ __launch_bounds__(256)
void attn_merge_kernel(const float* __restrict__ Opart, const float* __restrict__ lpart,
                       const float* __restrict__ HS, float* __restrict__ H,
                       ushort_t* __restrict__ Hhi, float* __restrict__ SQ)
{
    const int t = threadIdx.x;
    const int gid = blockIdx.x * 256 + t;
    const int i = gid >> 5;             // node
    const int f = (gid & 31) * 4;       // feature quad
    float ls = 0.f;
    float4 o = {0.f, 0.f, 0.f, 0.f};
    #pragma unroll
    for (int s = 0; s < ANS; ++s) {
        ls += lpart[s * NN + i];
        const float4 ov = *reinterpret_cast<const float4*>(
            Opart + ((size_t)s * NN + i) * DD + f);
        o.x += ov.x; o.y += ov.y; o.z += ov.z; o.w += ov.w;
    }
    const float4 hs = *reinterpret_cast<const float4*>(HS + i * DD + f);
    const float inv = 1.f / ls;
    float4 h;
    h.x = o.x * inv + hs.x; h.y = o.y * inv + hs.y;
    h.z = o.z * inv + hs.z; h.w = o.w * inv + hs.w;
    *reinterpret_cast<float4*>(H + i * DD + f) = h;
    ushort_t hb[4] = {f2b(h.x), f2b(h.y), f2b(h.z), f2b(h.w)};
    *reinterpret_cast<uint2*>(Hhi + i * DD + f) = *reinterpret_cast<const uint2*>(hb);
    float sq = h.x * h.x + h.y * h.y + h.z * h.z + h.w * h.w;
    sq += __shfl_xor(sq, 1, 64);
    sq += __shfl_xor(sq, 2, 64);
    sq += __shfl_xor(sq, 4, 64);
    sq += __shfl_xor(sq, 8, 64);
    sq += __shfl_xor(sq, 16, 64);       // xor<32 stays within the 32-lane node group
    if ((t & 31) == 0) SQ[i] = sq;
}

// ---------------- kNN: swapped-operand MFMA, register top-NL (u32) ---------
constexpr int KNSL = 16;                // key slices (512 keys each)
constexpr int KSL  = NN / KNSL;         // 512

__global__ __launch_bounds__(256, 4)
void knn_kernel(const ushort_t* __restrict__ Hhi, const float* __restrict__ SQg,
                unsigned* __restrict__ candV)
{
    __shared__ __align__(16) ushort_t Khi[64 * KSTR];
    __shared__ __align__(16) float sqs[64];

    const int t  = threadIdx.x;
    const int w  = t >> 6, l = t & 63;
    const int lc = l & 15, lq = l >> 4;
    const int b  = blockIdx.x;
    const int s  = b >> 6;              // slice 0..15
    const int qb = b & 63;
    const int i0 = qb * 128;
    const int k0 = s * KSL;

    const int kr = t >> 4, kc2 = t & 15;   // staging coords (4 chunks of 16 rows)

    const int gq0 = i0 + w * 32 + lc;          // sub=0 query
    const int gq1 = gq0 + 16;                  // sub=1 query
    const float sqi0 = SQg[gq0];
    const float sqi1 = SQg[gq1];

    bf16x8 qf[2][4];                    // B operand: B[n=query=lc][k=lq*8+j]
    #pragma unroll
    for (int sub = 0; sub < 2; ++sub) {
        const int row = i0 + w * 32 + sub * 16 + lc;
        #pragma unroll
        for (int kb = 0; kb < 4; ++kb)
            qf[sub][kb] = *reinterpret_cast<const bf16x8*>(Hhi + row * DD + kb * 32 + lq * 8);
    }

    unsigned lists[2][NL];              // ascending: [0] best .. [NL-1] worst
    #pragma unroll
    for (int sub = 0; sub < 2; ++sub)
        #pragma unroll
        for (int p = 0; p < NL; ++p) lists[sub][p] = 0xFFFFFFFFu;

    // prefetch tile 0 (knn has VGPR headroom, no spill at 4 waves/EU)
    uint4 pk[4]; float psq;
    #pragma unroll
    for (int p = 0; p < 4; ++p)
        pk[p] = *reinterpret_cast<const uint4*>(Hhi + (k0 + kr + p * 16) * DD + kc2 * 8);
    psq = (t < 64) ? SQg[k0 + t] : 0.f;

    const f32x4 zz = {0.f, 0.f, 0.f, 0.f};
    for (int jt0 = 0; jt0 < KSL; jt0 += 64) {
        const int jt = k0 + jt0;
        __syncthreads();                 // prev K-frag reads done
        #pragma unroll
        for (int p = 0; p < 4; ++p)
            *reinterpret_cast<uint4*>(&Khi[(kr + p * 16) * KSTR + kc2 * 8]) = pk[p];
        if (t < 64) sqs[t] = psq;
        __syncthreads();
        if (jt0 + 64 < KSL) {            // prefetch next during compute
            const int jn = jt + 64;
            #pragma unroll
            for (int p = 0; p < 4; ++p)
                pk[p] = *reinterpret_cast<const uint4*>(Hhi + (jn + kr + p * 16) * DD + kc2 * 8);
            psq = (t < 64) ? SQg[jn + t] : 0.f;
        }

        f32x4 acc[2][4];                 // [sub][kt]
        #pragma unroll
        for (int sub = 0; sub < 2; ++sub)
            #pragma unroll
            for (int kt = 0; kt < 4; ++kt) acc[sub][kt] = zz;
        #pragma unroll
        for (int kt = 0; kt < 4; ++kt) {
            #pragma unroll
            for (int kb = 0; kb < 4; ++kb) {
                const bf16x8 kf = *reinterpret_cast<const bf16x8*>(
                    &Khi[(kt * 16 + lc) * KSTR + kb * 32 + lq * 8]);
                acc[0][kt] = MFMA16(kf, qf[0][kb], acc[0][kt]);   // A=key, B=query
                acc[1][kt] = MFMA16(kf, qf[1][kb], acc[1][kt]);
            }
        }

        const bool ovl = ((jt & ~127) == i0);
        #pragma unroll
        for (int kt = 0; kt < 4; ++kt) {
            const float4 sq4 = *reinterpret_cast<const float4*>(&sqs[kt * 16 + lq * 4]);
            const float sqj[4] = {sq4.x, sq4.y, sq4.z, sq4.w};
            #pragma unroll
            for (int r = 0; r < 4; ++r) {
                const int gk = jt + kt * 16 + lq * 4 + r;
                float d0 = fmaf(-2.f, acc[0][kt][r], sqi0 + sqj[r]);
                float d1 = fmaf(-2.f, acc[1][kt][r], sqi1 + sqj[r]);
                if (ovl) {
                    if (gk == gq0) d0 = INFINITY;
                    if (gk == gq1) d1 = INFINITY;
                }
                const unsigned u0 = (__float_as_uint(d0) & 0xFFFFE000u) | (unsigned)gk;
                const unsigned u1 = (__float_as_uint(d1) & 0xFFFFE000u) | (unsigned)gk;
                ins_asc<NL>(lists[0], u0);
                ins_asc<NL>(lists[1], u1);
            }
        }
    }

    // ---- in-kernel lq-merge: Khi is dead, reuse as scratch ----
    __syncthreads();                     // all waves done with Khi MFMA reads
    unsigned* msw = reinterpret_cast<unsigned*>(Khi) + w * (16 * 4 * NL);
    #pragma unroll
    for (int sub = 0; sub < 2; ++sub) {
        #pragma unroll
        for (int p = 0; p < NL; ++p)
            msw[lc * (4 * NL) + lq * NL + p] = lists[sub][p];
        __syncthreads();
        if (lq == 0) {                   // 16 lanes/wave: one query each
            unsigned bk[NL];             // seed with lane-0 list (ascending)
            #pragma unroll
            for (int p = 0; p < NL; ++p) bk[p] = msw[lc * (4 * NL) + p];
            #pragma unroll
            for (int o = 1; o < 4; ++o)
                #pragma unroll
                for (int e = 0; e < NL; ++e)
                    ins_asc<NL>(bk, msw[lc * (4 * NL) + o * NL + e]);
            const int node = i0 + w * 32 + sub * 16 + lc;
            #pragma unroll
            for (int p = 0; p < NL; ++p)
                candV[((size_t)s * NL + p) * NN + node] = bk[p];
        }
        __syncthreads();
    }
}

// ------- final merge: 16 slice lists -> top-12 candidates per node ---------
__global__ __launch_bounds__(64)
void knn_merge_kernel(const unsigned* __restrict__ candV, int* __restrict__ CAND)
{
    const int q = blockIdx.x * 64 + threadIdx.x;
    unsigned bk[NCAND];
    #pragma unroll
    for (int p = 0; p < NCAND; ++p) bk[p] = 0xFFFFFFFFu;
    for (int s = 0; s < KNSL; ++s)
        #pragma unroll
        for (int e = 0; e < NL; ++e)
            ins_asc<NCAND>(bk, candV[((size_t)s * NL + e) * NN + q]);
    #pragma unroll
    for (int p = 0; p < NCAND; ++p)
        CAND[q * NCAND + p] = (int)(bk[p] & 8191u);
}

// ---------------- exact fp32 re-rank of candidates -> IDX ----------------
__global__ __launch_bounds__(256)
void rerank_kernel(const float* __restrict__ H, const float* __restrict__ SQ,
                   const int* __restrict__ CAND, int* __restrict__ IDX)
{
    const int t = threadIdx.x;
    const int w = t >> 6, l = t & 63;
    const int node = blockIdx.x * 4 + w;
    const float h0 = H[node * DD + l];
    const float h1 = H[node * DD + 64 + l];
    float dk[NCAND]; int di[NCAND];
    #pragma unroll
    for (int c = 0; c < NCAND; ++c) {
        const int j = CAND[node * NCAND + c];
        float p = h0 * H[j * DD + l] + h1 * H[j * DD + 64 + l];
        p += __shfl_xor(p, 1, 64);
        p += __shfl_xor(p, 2, 64);
        p += __shfl_xor(p, 4, 64);
        p += __shfl_xor(p, 8, 64);
        p += __shfl_xor(p, 16, 64);
        p += __shfl_xor(p, 32, 64);
        dk[c] = SQ[j] - 2.f * p;
        di[c] = j;
    }
    if (l == 0) {
        #pragma unroll
        for (int s = 0; s < KNB; ++s) {
            int best = s;
            #pragma unroll
            for (int c = s + 1; c < NCAND; ++c) {
                const bool lt = (dk[c] < dk[best]) ||
                                (dk[c] == dk[best] && di[c] < di[best]);
                if (lt) best = c;
            }
            const float tk = dk[s]; dk[s] = dk[best]; dk[best] = tk;
            const int   ti = di[s]; di[s] = di[best]; di[best] = ti;
            IDX[node * KNB + s] = di[s];
        }
    }
}

// ---------------- M1 = H @ W1 (f32, 4 rows/block) ----------------
__global__ __launch_bounds__(128)
void mat1_kernel(const float* __restrict__ Hin, const float* __restrict__ W,
                 float* __restrict__ M)
{
    __shared__ float xs[4][DD];
    const int i0 = blockIdx.x * 4, t = threadIdx.x;
    #pragma unroll
    for (int r = 0; r < 4; ++r) xs[r][t] = Hin[(i0 + r) * DD + t];
    __syncthreads();
    float a[4] = {0,0,0,0};
    #pragma unroll 4
    for (int c = 0; c < DD; ++c) {
        const float wv = W[c * DD + t];
        #pragma unroll
        for (int r = 0; r < 4; ++r) a[r] = fmaf(xs[r][c], wv, a[r]);
    }
    #pragma unroll
    for (int r = 0; r < 4; ++r) M[(i0 + r) * DD + t] = a[r];
}

// -------- fused: H1 = relu((sum_nbr M1 + M1)/8 + b1); M2 = H1.W2 ----------
__global__ __launch_bounds__(128)
void g1m2_kernel(const float* __restrict__ M1, const int* __restrict__ IDX,
                 const float* __restrict__ b1, const float* __restrict__ W2,
                 float* __restrict__ M2)
{
    __shared__ float red[128];
    const int i = blockIdx.x, t = threadIdx.x;
    float s = M1[i * DD + t];
    #pragma unroll
    for (int p = 0; p < KNB; ++p) s += M1[IDX[i * KNB + p] * DD + t];
    const float h1 = fmaxf(s * 0.125f + b1[t], 0.f);
    red[t] = h1 * W2[t];
    __syncthreads();
    for (int s2 = 64; s2 > 0; s2 >>= 1) {
        if (t < s2) red[t] += red[t + s2];
        __syncthreads();
    }
    if (t == 0) M2[i] = red[0];
}

// ---------------- out = (sum_nbr M2 + M2)/8 + b2 ----------------
__global__ __launch_bounds__(256)
void out_kernel(const float* __restrict__ M2, const int* __restrict__ IDX,
                const float* __restrict__ b2, float* __restrict__ out)
{
    const int i = blockIdx.x * 256 + threadIdx.x;
    if (i < NN) {
        float s = M2[i];
        #pragma unroll
        for (int p = 0; p < KNB; ++p) s += M2[IDX[i * KNB + p]];
        out[i] = s * 0.125f + b2[0];
    }
}

// ---------------------------------------------------------------------------
extern "C" void kernel_launch(void* const* d_in, const int* in_sizes, int n_in,
                              void* d_out, int out_size, void* d_ws, size_t ws_size,
                              hipStream_t stream)
{
    const float* x   = (const float*)d_in[0];
    const float* Wq  = (const float*)d_in[1];
    const float* bq  = (const float*)d_in[2];
    const float* Wk  = (const float*)d_in[3];
    const float* bk  = (const float*)d_in[4];
    const float* Wv  = (const float*)d_in[5];
    const float* bv  = (const float*)d_in[6];
    const float* Wsk = (const float*)d_in[7];
    const float* bsk = (const float*)d_in[8];
    const float* W1  = (const float*)d_in[9];
    const float* b1  = (const float*)d_in[10];
    const float* W2  = (const float*)d_in[11];
    const float* b2  = (const float*)d_in[12];

    constexpr size_t MB = 1024 * 1024;
    char* W = (char*)d_ws;
    // persistent: [0,8) Q/K splits, [8,12) VT splits, [12,16) HS (->H in place)
    ushort_t* Qhi  = (ushort_t*)(W + 0 * MB);
    ushort_t* Qlo  = (ushort_t*)(W + 2 * MB);
    ushort_t* Khi  = (ushort_t*)(W + 4 * MB);
    ushort_t* Klo  = (ushort_t*)(W + 6 * MB);
    ushort_t* VThi = (ushort_t*)(W + 8 * MB);
    ushort_t* VTlo = (ushort_t*)(W + 10 * MB);
    float*    HS   = (float*)(W + 12 * MB);
    float*    H    = HS;                                   // in-place merge
    ushort_t* Hhi  = Qhi;            // Q dead after attn; Hhi written by merge
    // small: [16,17)
    float* lpart = (float*)(W + 16 * MB);                  // 256KB
    float* SQ    = (float*)(W + 16 * MB + 256 * 1024);     // 32KB
    float* M2    = SQ + NN;                                // 32KB
    int*   IDX   = (int*)(M2 + NN);                        // 224KB
    // union: [17,49):
    //   Vf32  [17,21)   dead after vt
    //   Opart [17,49)   dead after attn_merge
    //   candV [17,22.25) written by knn, dead after knn_merge (5.25MB)
    //   CAND  [23,23.4) written by knn_merge, dead after rerank
    //   M1    [24,28)   written by mat1
    float*    Vf32  = (float*)(W + 17 * MB);
    float*    Opart = (float*)(W + 17 * MB);
    unsigned* candV = (unsigned*)(W + 17 * MB);
    int*      CAND  = (int*)(W + 23 * MB);
    float*    M1    = (float*)(W + 24 * MB);

    proj_kernel<<<NN / 4, 128, 0, stream>>>(x, Wq, bq, Wk, bk, Wv, bv, Wsk, bsk,
                                            Qhi, Qlo, Khi, Klo, Vf32, HS);
    vt_kernel<<<NN / 64, 256, 0, stream>>>(Vf32, VThi, VTlo);
    attn_kernel<<<ANS * 64, 256, 0, stream>>>(Qhi, Qlo, Khi, Klo, VThi, VTlo,
                                              Opart, lpart);
    attn_merge_kernel<<<(NN * 32) / 256, 256, 0, stream>>>(Opart, lpart, HS, H,
                                                           Hhi, SQ);
    knn_kernel<<<KNSL * 64, 256, 0, stream>>>(Hhi, SQ, candV);
    knn_merge_kernel<<<NN / 64, 64, 0, stream>>>(candV, CAND);
    rerank_kernel<<<NN / 4, 256, 0, stream>>>(H, SQ, CAND, IDX);
    mat1_kernel<<<NN / 4, 128, 0, stream>>>(H, W1, M1);
    g1m2_kernel<<<NN, 128, 0, stream>>>(M1, IDX, b1, W2, M2);
    out_kernel<<<NN / 256, 256, 0, stream>>>(M2, IDX, b2, (float*)d_out);
}

// Round 10
// 332.235 us; speedup vs baseline: 1.0034x; 1.0034x over previous
//
#include <hip/hip_runtime.h>
#include <cmath>

// ---------------------------------------------------------------------------
// GraphTransformer on MI355X.  N=8192, D=128, k=7, OUT=1.
// Attention: split-bf16 (hi/lo) MFMA flash, fixed max (logits bounded).
//   FROZEN config (every deviation regressed):
//   - QK^T 3-term split (round-10: plain bf16 QK flips kNN neighbors)
//   - NO register prefetch of K tiles (round-8 spills) -- global_load_lds
//   - PSTR=40 row stride for P (round-12)
//   - swapped QK^T (A=K,B=Q) + packed-b64 P round-trip (r15)
//   - branchless med3 top-K insert in kNN (r16)
//   - cross-tile PV pipeline (r17); cvt_pk exp pack (r20)
//   - ANS=8 / grid 512 (r19 ERRATum: finer key-split didn't raise occupancy)
//   - T4 counted-vmcnt pipeline: K/V dbuf, K staged 2 windows ahead, V 1;
//     barrier1 = lgkmcnt(0)+s_barrier, barrier2 = vmcnt(8)+s_barrier (r21:
//     attn 97->93.6us, best)
// Round-22 (this round): attn is only 28% of the pipeline now; tail ~200us.
// proj_kernel reads ALL FOUR weight matrices per block: 2048 blocks x 256KB
// = 512MB L2 traffic (~15us floor).  Blocked to 8 rows/block -> 256MB, grid
// 1024 (still 2 waves/SIMD for latency hiding).  mat1 likewise 128->64MB.
// Per-row accumulation chains unchanged -> bit-identical outputs, zero kNN
// risk.  attn untouched.
// kNN: swapped-operand bf16 MFMA, per-lane register top-10 (u32-packed),
// in-kernel lq-merge -> candV, parallel final merge, exact fp32 re-rank.
// GCN tail: fp32 VALU, gather1+m2 fused.
// ---------------------------------------------------------------------------

typedef unsigned short ushort_t;

constexpr int   NN    = 8192;
constexpr int   DD    = 128;
constexpr int   KNB   = 7;
constexpr int   NL    = 10;              // per-lane kept candidates (knn)
constexpr int   NCAND = 12;              // merged candidates per node
constexpr float SCALE = 0.088388347648318447f;   // 1/sqrt(128)

using bf16x8 = __attribute__((ext_vector_type(8))) short;   // 8 bf16 = 4 VGPR
using f32x4  = __attribute__((ext_vector_type(4))) float;   // mfma acc

#define MFMA16(a, b, c) __builtin_amdgcn_mfma_f32_16x16x32_bf16((a), (b), (c), 0, 0, 0)

__device__ __forceinline__ ushort_t f2b(float f) {
    union { float f; unsigned int u; } v; v.f = f;
    return (ushort_t)((v.u + 0x8000u) >> 16);
}
__device__ __forceinline__ float b2f(ushort_t h) {
    union { unsigned int u; float f; } v; v.u = ((unsigned int)h) << 16;
    return v.f;
}

// direct global->LDS copy, 16B per lane; LDS dest is wave-uniform base + lane*16
__device__ __forceinline__ void gload16(const void* g, void* l) {
    __builtin_amdgcn_global_load_lds(
        (const __attribute__((address_space(1))) unsigned int*)g,
        (__attribute__((address_space(3))) unsigned int*)l, 16, 0, 0);
}

__device__ __forceinline__ unsigned umin_(unsigned a, unsigned b) { return a < b ? a : b; }
__device__ __forceinline__ unsigned umax_(unsigned a, unsigned b) { return a > b ? a : b; }

// Branchless top-K keep-smallest insert into ASCENDING sorted list
// (a[0] best .. a[K-1] worst).  med3 identity: since a[p-1] <= a[p],
//   new a[p] = med3(x, a[p-1], a[p]) = min(max(x, a[p-1]), a[p]).
// Kept SET identical to a guarded strict-less shift insert.  2 VALU
// ops/element, no branch, no divergence.
template<int K>
__device__ __forceinline__ void ins_asc(unsigned* a, unsigned x)
{
    #pragma unroll
    for (int p = K - 1; p >= 1; --p)
        a[p] = umin_(umax_(x, a[p - 1]), a[p]);
    a[0] = umin_(a[0], x);
}

// ---------------- projections: Q,K (split bf16), V (f32), skip (f32) -------
// 8 rows/block: W L2 traffic 512->256MB; per-row accumulation unchanged.
constexpr int PR = 8;
__global__ __launch_bounds__(128)
void proj_kernel(const float* __restrict__ x,
                 const float* __restrict__ Wq, const float* __restrict__ bq,
                 const float* __restrict__ Wk, const float* __restrict__ bk,
                 const float* __restrict__ Wv, const float* __restrict__ bv,
                 const float* __restrict__ Ws, const float* __restrict__ bs,
                 ushort_t* __restrict__ Qhi, ushort_t* __restrict__ Qlo,
                 ushort_t* __restrict__ Khi, ushort_t* __restrict__ Klo,
                 float* __restrict__ Vf, float* __restrict__ HS)
{
    __shared__ float xs[PR][DD];
    const int i0 = blockIdx.x * PR, t = threadIdx.x;
    #pragma unroll
    for (int r = 0; r < PR; ++r) xs[r][t] = x[(i0 + r) * DD + t];
    __syncthreads();
    float aq[PR], ak[PR], av[PR], ah[PR];
    #pragma unroll
    for (int r = 0; r < PR; ++r) { aq[r] = 0.f; ak[r] = 0.f; av[r] = 0.f; ah[r] = 0.f; }
    #pragma unroll 4
    for (int c = 0; c < DD; ++c) {
        const float wq = Wq[c * DD + t], wk = Wk[c * DD + t];
        const float wv = Wv[c * DD + t], ws = Ws[c * DD + t];
        #pragma unroll
        for (int r = 0; r < PR; ++r) {
            const float xv = xs[r][c];
            aq[r] = fmaf(xv, wq, aq[r]); ak[r] = fmaf(xv, wk, ak[r]);
            av[r] = fmaf(xv, wv, av[r]); ah[r] = fmaf(xv, ws, ah[r]);
        }
    }
    #pragma unroll
    for (int r = 0; r < PR; ++r) {
        const int o = (i0 + r) * DD + t;
        const float q = aq[r] + bq[t];
        const float k = ak[r] + bk[t];
        const ushort_t qh = f2b(q); Qhi[o] = qh; Qlo[o] = f2b(q - b2f(qh));
        const ushort_t kh = f2b(k); Khi[o] = kh; Klo[o] = f2b(k - b2f(kh));
        Vf[o] = av[r] + bv[t];
        HS[o] = ah[r] + bs[t];
    }
}

// ---------------- V transpose + split: VT{hi,lo}[f][n] = split(V[n][f]) ----
__global__ __launch_bounds__(256)
void vt_kernel(const float* __restrict__ Vf,
               ushort_t* __restrict__ VThi, ushort_t* __restrict__ VTlo)
{
    __shared__ float tile[64 * 132];
    const int k0 = blockIdx.x * 64, t = threadIdx.x;
    #pragma unroll
    for (int p = 0; p < 8; ++p) {
        const int slot = t + p * 256;        // 2048 slots: 64 rows x 32 f4-chunks
        const int r = slot >> 5, c4 = slot & 31;
        *reinterpret_cast<float4*>(&tile[r * 132 + c4 * 4]) =
            *reinterpret_cast<const float4*>(Vf + (k0 + r) * DD + c4 * 4);
    }
    __syncthreads();
    #pragma unroll
    for (int p = 0; p < 4; ++p) {
        const int slot = t + p * 256;        // 1024 slots: 128 feats x 8 chunks
        const int f = slot >> 3, kc = slot & 7;
        ushort_t hh[8], ll[8];
        #pragma unroll
        for (int i = 0; i < 8; ++i) {
            const float v = tile[(kc * 8 + i) * 132 + f];
            hh[i] = f2b(v); ll[i] = f2b(v - b2f(hh[i]));
        }
        *reinterpret_cast<uint4*>(VThi + f * NN + k0 + kc * 8) =
            *reinterpret_cast<const uint4*>(hh);
        *reinterpret_cast<uint4*>(VTlo + f * NN + k0 + kc * 8) =
            *reinterpret_cast<const uint4*>(ll);
    }
}

// ---------------- split-bf16 MFMA flash attention, fixed max ---------------
// 256-thread blocks (4 waves x 32 queries = 128 queries/block), grid 512.
// K/V DOUBLE-buffered via global_load_lds; K staged 2 windows ahead, V 1.
// Counted-vmcnt barriers (never 0 mid-loop); 2 blocks/CU.
constexpr int ANS  = 8;                 // key slices
constexpr int AKS  = NN / ANS;          // 1024 keys per slice
constexpr int BK   = 32;                // keys per tile
constexpr int PSTR = 40;                // P row stride (frozen)
constexpr int KSTR = 136;               // (knn kernel LDS stride; unchanged)

__global__ __launch_bounds__(256, 2)
void attn_kernel(const ushort_t* __restrict__ Qhi, const ushort_t* __restrict__ Qlo,
                 const ushort_t* __restrict__ Khg, const ushort_t* __restrict__ Klg,
                 const ushort_t* __restrict__ Vhg, const ushort_t* __restrict__ Vlg,
                 float* __restrict__ Opart, float* __restrict__ lpart)
{
    // K tiles: 32 rows x 128 bf16, linear rows; chunk XOR-swizzled (c^row&7)
    //          on global source + read side -> conflict-free ds_read_b128.
    // V tiles: 128 rows x 32 bf16, chunk XOR-swizzled (c^(row>>1)&3).
    // P strip: 16 rows x PSTR per wave (row = query lc; sub0/sub1 reuse).
    // Buffer map: K(t) in K?s[t&1], V(t) in V?s[t&1].
    __shared__ __align__(16) ushort_t Khs[2][BK * DD];
    __shared__ __align__(16) ushort_t Kls[2][BK * DD];
    __shared__ __align__(16) ushort_t Vhs[2][DD * BK];
    __shared__ __align__(16) ushort_t Vls[2][DD * BK];
    __shared__ __align__(16) ushort_t Phs[4][16 * PSTR];
    __shared__ __align__(16) ushort_t Pls[4][16 * PSTR];

    const int t  = threadIdx.x;
    const int w  = t >> 6, l = t & 63;
    const int lc = l & 15, lq = l >> 4;
    const int b  = blockIdx.x;
    const int s  = b >> 6;              // slice 0..7
    const int qb = b & 63;
    const int i0 = qb * 128;
    const int k0 = s * AKS;
    ushort_t* Pwh = Phs[w];
    ushort_t* Pwl = Pls[w];

    // staging coordinates (per thread, loop-invariant).
    const int lrK = w * 4 + (l >> 4);
    const int kchunk = ((l & 15) ^ (lrK & 7)) * 8;
    const ushort_t* gKh = Khg + (size_t)(k0 + lrK) * DD + kchunk;
    const ushort_t* gKl = Klg + (size_t)(k0 + lrK) * DD + kchunk;
    const int lrV = w * 16 + (l >> 2);
    const int vchunk = ((l & 3) ^ ((l >> 3) & 3)) * 8;
    const ushort_t* gVh = Vhg + (size_t)lrV * NN + k0 + vchunk;
    const ushort_t* gVl = Vlg + (size_t)lrV * NN + k0 + vchunk;

#define STAGE_K(buf, koff) do {                                              \
    gload16(gKh + (size_t)(koff) * DD,        &Khs[buf][(w * 4) * DD]);      \
    gload16(gKh + (size_t)((koff) + 16) * DD, &Khs[buf][(16 + w * 4) * DD]); \
    gload16(gKl + (size_t)(koff) * DD,        &Kls[buf][(w * 4) * DD]);      \
    gload16(gKl + (size_t)((koff) + 16) * DD, &Kls[buf][(16 + w * 4) * DD]); \
  } while (0)
#define STAGE_V(buf, koff) do {                                              \
    gload16(gVh + (koff),                     &Vhs[buf][(w * 16) * BK]);     \
    gload16(gVh + (size_t)64 * NN + (koff),   &Vhs[buf][(64 + w * 16) * BK]);\
    gload16(gVl + (koff),                     &Vls[buf][(w * 16) * BK]);     \
    gload16(gVl + (size_t)64 * NN + (koff),   &Vls[buf][(64 + w * 16) * BK]);\
  } while (0)
#define LGKM0() asm volatile("s_waitcnt lgkmcnt(0)" ::: "memory")
#define VMW(n)  asm volatile("s_waitcnt vmcnt(" #n ")" ::: "memory")
#define BARRIER() do { __builtin_amdgcn_s_barrier(); \
                       __builtin_amdgcn_sched_barrier(0); } while (0)

    bf16x8 qh[2][4], ql[2][4];
    #pragma unroll
    for (int sub = 0; sub < 2; ++sub) {
        const int row = i0 + w * 32 + sub * 16 + lc;
        #pragma unroll
        for (int kb = 0; kb < 4; ++kb) {
            qh[sub][kb] = *reinterpret_cast<const bf16x8*>(Qhi + row * DD + kb * 32 + lq * 8);
            ql[sub][kb] = *reinterpret_cast<const bf16x8*>(Qlo + row * DD + kb * 32 + lq * 8);
        }
    }

    const f32x4 zz = {0.f, 0.f, 0.f, 0.f};
    f32x4 oacc[2][8];
    #pragma unroll
    for (int sub = 0; sub < 2; ++sub)
        #pragma unroll
        for (int ft = 0; ft < 8; ++ft) oacc[sub][ft] = zz;
    float lrow[2] = {0.f, 0.f};         // per-lane partial denom, query = lc

    bf16x8 pah[2] = {}, pal[2] = {};    // carried P fragments (tile t-1)
    const int vc = (lq ^ ((lc >> 1) & 3)) * 8;   // V read-side unswizzle

    // prologue: K(0), K(1), V(0) issued; wait K(0) (allow 8 newer in flight)
    STAGE_K(0, 0);
    STAGE_K(1, BK);
    STAGE_V(0, 0);
    VMW(8);
    BARRIER();

    constexpr int NT = AKS / BK;        // 32 tiles
    for (int it = 0; it < NT; ++it) {
        const int jt  = k0 + it * BK;
        const int cur = it & 1;
        const ushort_t* Kh = Khs[cur];
        const ushort_t* Kl = Kls[cur];
        const ushort_t* Vph = Vhs[cur ^ 1];   // V(t-1)
        const ushort_t* Vpl = Vls[cur ^ 1];

        // ---- S^T = K Q^T (swapped: A=K, B=Q; bit-identical products) ----
        f32x4 sacc[2][2];               // [sub][kt]
        #pragma unroll
        for (int sub = 0; sub < 2; ++sub)
            #pragma unroll
            for (int kt = 0; kt < 2; ++kt) sacc[sub][kt] = zz;
        __builtin_amdgcn_s_setprio(1);
        #pragma unroll
        for (int kt = 0; kt < 2; ++kt) {
            const int kro = (kt * 16 + lc) * DD;
            #pragma unroll
            for (int kb = 0; kb < 4; ++kb) {
                const int cp = ((kb * 4 + lq) ^ (lc & 7)) * 8;  // read-side unswizzle
                const bf16x8 kh = *reinterpret_cast<const bf16x8*>(&Kh[kro + cp]);
                const bf16x8 kl = *reinterpret_cast<const bf16x8*>(&Kl[kro + cp]);
                #pragma unroll
                for (int sub = 0; sub < 2; ++sub) {
                    sacc[sub][kt] = MFMA16(kh, qh[sub][kb], sacc[sub][kt]);
                    sacc[sub][kt] = MFMA16(kh, ql[sub][kb], sacc[sub][kt]);
                    sacc[sub][kt] = MFMA16(kl, qh[sub][kb], sacc[sub][kt]);
                }
            }
        }
        __builtin_amdgcn_s_setprio(0);

        // ---- O += P(t-1) V(t-1) ----
        if (it > 0) {
            __builtin_amdgcn_s_setprio(1);
            #pragma unroll
            for (int ft = 0; ft < 8; ++ft) {
                const bf16x8 vh = *reinterpret_cast<const bf16x8*>(
                    &Vph[(ft * 16 + lc) * BK + vc]);
                const bf16x8 vl = *reinterpret_cast<const bf16x8*>(
                    &Vpl[(ft * 16 + lc) * BK + vc]);
                #pragma unroll
                for (int sub = 0; sub < 2; ++sub) {
                    oacc[sub][ft] = MFMA16(pah[sub], vh, oacc[sub][ft]);
                    oacc[sub][ft] = MFMA16(pal[sub], vh, oacc[sub][ft]);
                    oacc[sub][ft] = MFMA16(pah[sub], vl, oacc[sub][ft]);
                }
            }
            __builtin_amdgcn_s_setprio(0);
        }

        // barrier1: all waves' K(t)/V(t-1) ds_reads retired (lgkm only —
        // staged loads stay in flight).
        LGKM0();
        BARRIER();

        // deep prefetch: K(t+2) overwrites K(t)'s buffer (reads retired);
        // V(t+1) overwrites V(t-1)'s buffer (reads retired).
        if (it <= NT - 3) STAGE_K(cur, (it + 2) * BK);
        if (it <= NT - 2) STAGE_V(cur ^ 1, (it + 1) * BK);

        if ((jt & ~127) == i0) {            // diagonal mask
            #pragma unroll
            for (int sub = 0; sub < 2; ++sub) {
                const int gq = i0 + w * 32 + sub * 16 + lc;
                #pragma unroll
                for (int kt = 0; kt < 2; ++kt)
                    #pragma unroll
                    for (int r = 0; r < 4; ++r) {
                        const int gk = jt + kt * 16 + lq * 4 + r;
                        if (gk == gq) sacc[sub][kt][r] = -INFINITY;
                    }
            }
        }
        // ---- P = exp(S*SCALE): cvt_pk split; b64 write, b128 read to regs
        #pragma unroll
        for (int sub = 0; sub < 2; ++sub) {
            #pragma unroll
            for (int kt = 0; kt < 2; ++kt) {
                unsigned wh[2], wl[2];
                #pragma unroll
                for (int rr = 0; rr < 2; ++rr) {
                    const float p0 = __expf(sacc[sub][kt][rr * 2 + 0] * SCALE);
                    const float p1 = __expf(sacc[sub][kt][rr * 2 + 1] * SCALE);
                    lrow[sub] += p0;
                    lrow[sub] += p1;
                    unsigned hpk;
                    asm("v_cvt_pk_bf16_f32 %0, %1, %2"
                        : "=v"(hpk) : "v"(p0), "v"(p1));
                    wh[rr] = hpk;
                    const float h0 = __uint_as_float(hpk << 16);
                    const float h1 = __uint_as_float(hpk & 0xFFFF0000u);
                    unsigned lpk;
                    asm("v_cvt_pk_bf16_f32 %0, %1, %2"
                        : "=v"(lpk) : "v"(p0 - h0), "v"(p1 - h1));
                    wl[rr] = lpk;
                }
                const int eo = lc * PSTR + kt * 16 + lq * 4;
                *reinterpret_cast<uint2*>(&Pwh[eo]) = make_uint2(wh[0], wh[1]);
                *reinterpret_cast<uint2*>(&Pwl[eo]) = make_uint2(wl[0], wl[1]);
            }
            pah[sub] = *reinterpret_cast<const bf16x8*>(&Pwh[lc * PSTR + lq * 8]);
            pal[sub] = *reinterpret_cast<const bf16x8*>(&Pwl[lc * PSTR + lq * 8]);
        }

        // barrier2: K(t+1), V(t) landed block-wide; K(t+2)/V(t+1) (the 8
        // newest loads) stay in flight across the barrier.
        if (it <= NT - 3)      { VMW(8); }
        else if (it == NT - 2) { VMW(4); }
        else                   { VMW(0); }
        BARRIER();
    }
    // ---- epilogue: PV(NT-1); V(NT-1) in buffer (NT-1)&1 ----
    {
        const ushort_t* Vh = Vhs[(NT - 1) & 1];
        const ushort_t* Vl = Vls[(NT - 1) & 1];
        #pragma unroll
        for (int ft = 0; ft < 8; ++ft) {
            const bf16x8 vh = *reinterpret_cast<const bf16x8*>(
                &Vh[(ft * 16 + lc) * BK + vc]);
            const bf16x8 vl = *reinterpret_cast<const bf16x8*>(
                &Vl[(ft * 16 + lc) * BK + vc]);
            #pragma unroll
            for (int sub = 0; sub < 2; ++sub) {
                oacc[sub][ft] = MFMA16(pah[sub], vh, oacc[sub][ft]);
                oacc[sub][ft] = MFMA16(pal[sub], vh, oacc[sub][ft]);
                oacc[sub][ft] = MFMA16(pah[sub], vl, oacc[sub][ft]);
            }
        }
    }
#undef STAGE_K
#undef STAGE_V
#undef LGKM0
#undef VMW
#undef BARRIER

    // denom: lane holds partial for query=lc over keys lq*4+r; reduce over lq.
    #pragma unroll
    for (int sub = 0; sub < 2; ++sub) {
        float ps = lrow[sub];
        ps += __shfl_xor(ps, 16, 64);
        ps += __shfl_xor(ps, 32, 64);
        lrow[sub] = ps;
    }
    #pragma unroll
    for (int sub = 0; sub < 2; ++sub) {
        #pragma unroll
        for (int r = 0; r < 4; ++r) {
            const int row = i0 + w * 32 + sub * 16 + lq * 4 + r;
            float* po = Opart + ((size_t)s * NN + row) * DD;
            #pragma unroll
            for (int ft = 0; ft < 8; ++ft) po[ft * 16 + lc] = oacc[sub][ft][r];
        }
        if (l < 16)
            lpart[s * NN + i0 + w * 32 + sub * 16 + l] = lrow[sub];
    }
}

// ------- merge slices + skip, emit H (in-place over HS), Hhi, SQ -----------
// float4-vectorized: 32 threads per node, 4 features per thread.
__global__ __launch_bounds__(256)
void attn_merge_kernel(const float* __restrict__ Opart, const float* __restrict__ lpart,
                       const float* __restrict__ HS, float* __restrict__ H,
                       ushort_t* __restrict__ Hhi, float* __restrict__ SQ)
{
    const int t = threadIdx.x;
    const int gid = blockIdx.x * 256 + t;
    const int i = gid >> 5;             // node
    const int f = (gid & 31) * 4;       // feature quad
    float ls = 0.f;
    float4 o = {0.f, 0.f, 0.f, 0.f};
    #pragma unroll
    for (int s = 0; s < ANS; ++s) {
        ls += lpart[s * NN + i];
        const float4 ov = *reinterpret_cast<const float4*>(
            Opart + ((size_t)s * NN + i) * DD + f);
        o.x += ov.x; o.y += ov.y; o.z += ov.z; o.w += ov.w;
    }
    const float4 hs = *reinterpret_cast<const float4*>(HS + i * DD + f);
    const float inv = 1.f / ls;
    float4 h;
    h.x = o.x * inv + hs.x; h.y = o.y * inv + hs.y;
    h.z = o.z * inv + hs.z; h.w = o.w * inv + hs.w;
    *reinterpret_cast<float4*>(H + i * DD + f) = h;
    ushort_t hb[4] = {f2b(h.x), f2b(h.y), f2b(h.z), f2b(h.w)};
    *reinterpret_cast<uint2*>(Hhi + i * DD + f) = *reinterpret_cast<const uint2*>(hb);
    float sq = h.x * h.x + h.y * h.y + h.z * h.z + h.w * h.w;
    sq += __shfl_xor(sq, 1, 64);
    sq += __shfl_xor(sq, 2, 64);
    sq += __shfl_xor(sq, 4, 64);
    sq += __shfl_xor(sq, 8, 64);
    sq += __shfl_xor(sq, 16, 64);       // xor<32 stays within the 32-lane node group
    if ((t & 31) == 0) SQ[i] = sq;
}

// ---------------- kNN: swapped-operand MFMA, register top-NL (u32) ---------
constexpr int KNSL = 16;                // key slices (512 keys each)
constexpr int KSL  = NN / KNSL;         // 512

__global__ __launch_bounds__(256, 4)
void knn_kernel(const ushort_t* __restrict__ Hhi, const float* __restrict__ SQg,
                unsigned* __restrict__ candV)
{
    __shared__ __align__(16) ushort_t Khi[64 * KSTR];
    __shared__ __align__(16) float sqs[64];

    const int t  = threadIdx.x;
    const int w  = t >> 6, l = t & 63;
    const int lc = l & 15, lq = l >> 4;
    const int b  = blockIdx.x;
    const int s  = b >> 6;              // slice 0..15
    const int qb = b & 63;
    const int i0 = qb * 128;
    const int k0 = s * KSL;

    const int kr = t >> 4, kc2 = t & 15;   // staging coords (4 chunks of 16 rows)

    const int gq0 = i0 + w * 32 + lc;          // sub=0 query
    const int gq1 = gq0 + 16;                  // sub=1 query
    const float sqi0 = SQg[gq0];
    const float sqi1 = SQg[gq1];

    bf16x8 qf[2][4];                    // B operand: B[n=query=lc][k=lq*8+j]
    #pragma unroll
    for (int sub = 0; sub < 2; ++sub) {
        const int row = i0 + w * 32 + sub * 16 + lc;
        #pragma unroll
        for (int kb = 0; kb < 4; ++kb)
            qf[sub][kb] = *reinterpret_cast<const bf16x8*>(Hhi + row * DD + kb * 32 + lq * 8);
    }

    unsigned lists[2][NL];              // ascending: [0] best .. [NL-1] worst
    #pragma unroll
    for (int sub = 0; sub < 2; ++sub)
        #pragma unroll
        for (int p = 0; p < NL; ++p) lists[sub][p] = 0xFFFFFFFFu;

    // prefetch tile 0 (knn has VGPR headroom, no spill at 4 waves/EU)
    uint4 pk[4]; float psq;
    #pragma unroll
    for (int p = 0; p < 4; ++p)
        pk[p] = *reinterpret_cast<const uint4*>(Hhi + (k0 + kr + p * 16) * DD + kc2 * 8);
    psq = (t < 64) ? SQg[k0 + t] : 0.f;

    const f32x4 zz = {0.f, 0.f, 0.f, 0.f};
    for (int jt0 = 0; jt0 < KSL; jt0 += 64) {
        const int jt = k0 + jt0;
        __syncthreads();                 // prev K-frag reads done
        #pragma unroll
        for (int p = 0; p < 4; ++p)
            *reinterpret_cast<uint4*>(&Khi[(kr + p * 16) * KSTR + kc2 * 8]) = pk[p];
        if (t < 64) sqs[t] = psq;
        __syncthreads();
        if (jt0 + 64 < KSL) {            // prefetch next during compute
            const int jn = jt + 64;
            #pragma unroll
            for (int p = 0; p < 4; ++p)
                pk[p] = *reinterpret_cast<const uint4*>(Hhi + (jn + kr + p * 16) * DD + kc2 * 8);
            psq = (t < 64) ? SQg[jn + t] : 0.f;
        }

        f32x4 acc[2][4];                 // [sub][kt]
        #pragma unroll
        for (int sub = 0; sub < 2; ++sub)
            #pragma unroll
            for (int kt = 0; kt < 4; ++kt) acc[sub][kt] = zz;
        #pragma unroll
        for (int kt = 0; kt < 4; ++kt) {
            #pragma unroll
            for (int kb = 0; kb < 4; ++kb) {
                const bf16x8 kf = *reinterpret_cast<const bf16x8*>(
                    &Khi[(kt * 16 + lc) * KSTR + kb * 32 + lq * 8]);
                acc[0][kt] = MFMA16(kf, qf[0][kb], acc[0][kt]);   // A=key, B=query
                acc[1][kt] = MFMA16(kf, qf[1][kb], acc[1][kt]);
            }
        }

        const bool ovl = ((jt & ~127) == i0);
        #pragma unroll
        for (int kt = 0; kt < 4; ++kt) {
            const float4 sq4 = *reinterpret_cast<const float4*>(&sqs[kt * 16 + lq * 4]);
            const float sqj[4] = {sq4.x, sq4.y, sq4.z, sq4.w};
            #pragma unroll
            for (int r = 0; r < 4; ++r) {
                const int gk = jt + kt * 16 + lq * 4 + r;
                float d0 = fmaf(-2.f, acc[0][kt][r], sqi0 + sqj[r]);
                float d1 = fmaf(-2.f, acc[1][kt][r], sqi1 + sqj[r]);
                if (ovl) {
                    if (gk == gq0) d0 = INFINITY;
                    if (gk == gq1) d1 = INFINITY;
                }
                const unsigned u0 = (__float_as_uint(d0) & 0xFFFFE000u) | (unsigned)gk;
                const unsigned u1 = (__float_as_uint(d1) & 0xFFFFE000u) | (unsigned)gk;
                ins_asc<NL>(lists[0], u0);
                ins_asc<NL>(lists[1], u1);
            }
        }
    }

    // ---- in-kernel lq-merge: Khi is dead, reuse as scratch ----
    __syncthreads();                     // all waves done with Khi MFMA reads
    unsigned* msw = reinterpret_cast<unsigned*>(Khi) + w * (16 * 4 * NL);
    #pragma unroll
    for (int sub = 0; sub < 2; ++sub) {
        #pragma unroll
        for (int p = 0; p < NL; ++p)
            msw[lc * (4 * NL) + lq * NL + p] = lists[sub][p];
        __syncthreads();
        if (lq == 0) {                   // 16 lanes/wave: one query each
            unsigned bk[NL];             // seed with lane-0 list (ascending)
            #pragma unroll
            for (int p = 0; p < NL; ++p) bk[p] = msw[lc * (4 * NL) + p];
            #pragma unroll
            for (int o = 1; o < 4; ++o)
                #pragma unroll
                for (int e = 0; e < NL; ++e)
                    ins_asc<NL>(bk, msw[lc * (4 * NL) + o * NL + e]);
            const int node = i0 + w * 32 + sub * 16 + lc;
            #pragma unroll
            for (int p = 0; p < NL; ++p)
                candV[((size_t)s * NL + p) * NN + node] = bk[p];
        }
        __syncthreads();
    }
}

// ------- final merge: 16 slice lists -> top-12 candidates per node ---------
__global__ __launch_bounds__(64)
void knn_merge_kernel(const unsigned* __restrict__ candV, int* __restrict__ CAND)
{
    const int q = blockIdx.x * 64 + threadIdx.x;
    unsigned bk[NCAND];
    #pragma unroll
    for (int p = 0; p < NCAND; ++p) bk[p] = 0xFFFFFFFFu;
    for (int s = 0; s < KNSL; ++s)
        #pragma unroll
        for (int e = 0; e < NL; ++e)
            ins_asc<NCAND>(bk, candV[((size_t)s * NL + e) * NN + q]);
    #pragma unroll
    for (int p = 0; p < NCAND; ++p)
        CAND[q * NCAND + p] = (int)(bk[p] & 8191u);
}

// ---------------- exact fp32 re-rank of candidates -> IDX ----------------
__global__ __launch_bounds__(256)
void rerank_kernel(const float* __restrict__ H, const float* __restrict__ SQ,
                   const int* __restrict__ CAND, int* __restrict__ IDX)
{
    const int t = threadIdx.x;
    const int w = t >> 6, l = t & 63;
    const int node = blockIdx.x * 4 + w;
    const float h0 = H[node * DD + l];
    const float h1 = H[node * DD + 64 + l];
    float dk[NCAND]; int di[NCAND];
    #pragma unroll
    for (int c = 0; c < NCAND; ++c) {
        const int j = CAND[node * NCAND + c];
        float p = h0 * H[j * DD + l] + h1 * H[j * DD + 64 + l];
        p += __shfl_xor(p, 1, 64);
        p += __shfl_xor(p, 2, 64);
        p += __shfl_xor(p, 4, 64);
        p += __shfl_xor(p, 8, 64);
        p += __shfl_xor(p, 16, 64);
        p += __shfl_xor(p, 32, 64);
        dk[c] = SQ[j] - 2.f * p;
        di[c] = j;
    }
    if (l == 0) {
        #pragma unroll
        for (int s = 0; s < KNB; ++s) {
            int best = s;
            #pragma unroll
            for (int c = s + 1; c < NCAND; ++c) {
                const bool lt = (dk[c] < dk[best]) ||
                                (dk[c] == dk[best] && di[c] < di[best]);
                if (lt) best = c;
            }
            const float tk = dk[s]; dk[s] = dk[best]; dk[best] = tk;
            const int   ti = di[s]; di[s] = di[best]; di[best] = ti;
            IDX[node * KNB + s] = di[s];
        }
    }
}

// ---------------- M1 = H @ W1 (f32, 8 rows/block) ----------------
__global__ __launch_bounds__(128)
void mat1_kernel(const float* __restrict__ Hin, const float* __restrict__ W,
                 float* __restrict__ M)
{
    __shared__ float xs[PR][DD];
    const int i0 = blockIdx.x * PR, t = threadIdx.x;
    #pragma unroll
    for (int r = 0; r < PR; ++r) xs[r][t] = Hin[(i0 + r) * DD + t];
    __syncthreads();
    float a[PR];
    #pragma unroll
    for (int r = 0; r < PR; ++r) a[r] = 0.f;
    #pragma unroll 4
    for (int c = 0; c < DD; ++c) {
        const float wv = W[c * DD + t];
        #pragma unroll
        for (int r = 0; r < PR; ++r) a[r] = fmaf(xs[r][c], wv, a[r]);
    }
    #pragma unroll
    for (int r = 0; r < PR; ++r) M[(i0 + r) * DD + t] = a[r];
}

// -------- fused: H1 = relu((sum_nbr M1 + M1)/8 + b1); M2 = H1.W2 ----------
__global__ __launch_bounds__(128)
void g1m2_kernel(const float* __restrict__ M1, const int* __restrict__ IDX,
                 const float* __restrict__ b1, const float* __restrict__ W2,
                 float* __restrict__ M2)
{
    __shared__ float red[128];
    const int i = blockIdx.x, t = threadIdx.x;
    float s = M1[i * DD + t];
    #pragma unroll
    for (int p = 0; p < KNB; ++p) s += M1[IDX[i * KNB + p] * DD + t];
    const float h1 = fmaxf(s * 0.125f + b1[t], 0.f);
    red[t] = h1 * W2[t];
    __syncthreads();
    for (int s2 = 64; s2 > 0; s2 >>= 1) {
        if (t < s2) red[t] += red[t + s2];
        __syncthreads();
    }
    if (t == 0) M2[i] = red[0];
}

// ---------------- out = (sum_nbr M2 + M2)/8 + b2 ----------------
__global__ __launch_bounds__(256)
void out_kernel(const float* __restrict__ M2, const int* __restrict__ IDX,
                const float* __restrict__ b2, float* __restrict__ out)
{
    const int i = blockIdx.x * 256 + threadIdx.x;
    if (i < NN) {
        float s = M2[i];
        #pragma unroll
        for (int p = 0; p < KNB; ++p) s += M2[IDX[i * KNB + p]];
        out[i] = s * 0.125f + b2[0];
    }
}

// ---------------------------------------------------------------------------
extern "C" void kernel_launch(void* const* d_in, const int* in_sizes, int n_in,
                              void* d_out, int out_size, void* d_ws, size_t ws_size,
                              hipStream_t stream)
{
    const float* x   = (const float*)d_in[0];
    const float* Wq  = (const float*)d_in[1];
    const float* bq  = (const float*)d_in[2];
    const float* Wk  = (const float*)d_in[3];
    const float* bk  = (const float*)d_in[4];
    const float* Wv  = (const float*)d_in[5];
    const float* bv  = (const float*)d_in[6];
    const float* Wsk = (const float*)d_in[7];
    const float* bsk = (const float*)d_in[8];
    const float* W1  = (const float*)d_in[9];
    const float* b1  = (const float*)d_in[10];
    const float* W2  = (const float*)d_in[11];
    const float* b2  = (const float*)d_in[12];

    constexpr size_t MB = 1024 * 1024;
    char* W = (char*)d_ws;
    // persistent: [0,8) Q/K splits, [8,12) VT splits, [12,16) HS (->H in place)
    ushort_t* Qhi  = (ushort_t*)(W + 0 * MB);
    ushort_t* Qlo  = (ushort_t*)(W + 2 * MB);
    ushort_t* Khi  = (ushort_t*)(W + 4 * MB);
    ushort_t* Klo  = (ushort_t*)(W + 6 * MB);
    ushort_t* VThi = (ushort_t*)(W + 8 * MB);
    ushort_t* VTlo = (ushort_t*)(W + 10 * MB);
    float*    HS   = (float*)(W + 12 * MB);
    float*    H    = HS;                                   // in-place merge
    ushort_t* Hhi  = Qhi;            // Q dead after attn; Hhi written by merge
    // small: [16,17)
    float* lpart = (float*)(W + 16 * MB);                  // 256KB
    float* SQ    = (float*)(W + 16 * MB + 256 * 1024);     // 32KB
    float* M2    = SQ + NN;                                // 32KB
    int*   IDX   = (int*)(M2 + NN);                        // 224KB
    // union: [17,49):
    //   Vf32  [17,21)   dead after vt
    //   Opart [17,49)   dead after attn_merge
    //   candV [17,22.25) written by knn, dead after knn_merge (5.25MB)
    //   CAND  [23,23.4) written by knn_merge, dead after rerank
    //   M1    [24,28)   written by mat1
    float*    Vf32  = (float*)(W + 17 * MB);
    float*    Opart = (float*)(W + 17 * MB);
    unsigned* candV = (unsigned*)(W + 17 * MB);
    int*      CAND  = (int*)(W + 23 * MB);
    float*    M1    = (float*)(W + 24 * MB);

    proj_kernel<<<NN / PR, 128, 0, stream>>>(x, Wq, bq, Wk, bk, Wv, bv, Wsk, bsk,
                                             Qhi, Qlo, Khi, Klo, Vf32, HS);
    vt_kernel<<<NN / 64, 256, 0, stream>>>(Vf32, VThi, VTlo);
    attn_kernel<<<ANS * 64, 256, 0, stream>>>(Qhi, Qlo, Khi, Klo, VThi, VTlo,
                                              Opart, lpart);
    attn_merge_kernel<<<(NN * 32) / 256, 256, 0, stream>>>(Opart, lpart, HS, H,
                                                           Hhi, SQ);
    knn_kernel<<<KNSL * 64, 256, 0, stream>>>(Hhi, SQ, candV);
    knn_merge_kernel<<<NN / 64, 64, 0, stream>>>(candV, CAND);
    rerank_kernel<<<NN / 4, 256, 0, stream>>>(H, SQ, CAND, IDX);
    mat1_kernel<<<NN / PR, 128, 0, stream>>>(H, W1, M1);
    g1m2_kernel<<<NN, 128, 0, stream>>>(M1, IDX, b1, W2, M2);
    out_kernel<<<NN / 256, 256, 0, stream>>>(M2, IDX, b2, (float*)d_out);
}

// Round 11
// 322.276 us; speedup vs baseline: 1.0344x; 1.0309x over previous
//
#include <hip/hip_runtime.h>
#include <cmath>

// ---------------------------------------------------------------------------
// GraphTransformer on MI355X.  N=8192, D=128, k=7, OUT=1.
// Attention: split-bf16 (hi/lo) MFMA flash, fixed max (logits bounded).
//   FROZEN config (every deviation regressed):
//   - QK^T 3-term split (round-10: plain bf16 QK flips kNN neighbors)
//   - NO register prefetch of K tiles (round-8 spills) -- global_load_lds
//   - PSTR=40 row stride for P (round-12)
//   - swapped QK^T (A=K,B=Q) + packed-b64 P round-trip (r15)
//   - branchless med3 top-K insert in kNN (r16)
//   - cross-tile PV pipeline (r17); cvt_pk exp pack (r20)
//   - ANS=8 / grid 512 (r19 ERRATum: finer key-split didn't raise occupancy)
//   - T4 counted-vmcnt pipeline (r21: attn 97->93.6us, best)
//   - proj/mat1 8-row blocking (r22: within noise -- tail is not traffic-bound)
// Round-23 (this round): tail STRUCTURE, both bit-identical:
//   1. g1m2: 8192x128 blocks w/ 7 syncthreads -> 2048x256, one node per
//      wave, shfl_xor reduce in order 32,16,8,4,2,1 (replays the old LDS
//      tree pairing exactly -> bit-identical M2).  No LDS, no barriers.
//   2. mat1 fused into attn_merge (H already in registers; 8x132 LDS tile,
//      one barrier, then 2-half x 128-col matmul phase; same c-order ->
//      bit-identical M1).  Saves H re-read + one launch.  M1 moved to
//      [49,53)MB -- old [24,28) overlapped Opart [17,49) which the fused
//      kernel still reads (ws>=81MB confirmed in r19's big path).
// kNN: swapped-operand bf16 MFMA, per-lane register top-10 (u32-packed),
// in-kernel lq-merge -> candV, parallel final merge, exact fp32 re-rank.
// ---------------------------------------------------------------------------

typedef unsigned short ushort_t;

constexpr int   NN    = 8192;
constexpr int   DD    = 128;
constexpr int   KNB   = 7;
constexpr int   NL    = 10;              // per-lane kept candidates (knn)
constexpr int   NCAND = 12;              // merged candidates per node
constexpr float SCALE = 0.088388347648318447f;   // 1/sqrt(128)

using bf16x8 = __attribute__((ext_vector_type(8))) short;   // 8 bf16 = 4 VGPR
using f32x4  = __attribute__((ext_vector_type(4))) float;   // mfma acc

#define MFMA16(a, b, c) __builtin_amdgcn_mfma_f32_16x16x32_bf16((a), (b), (c), 0, 0, 0)

__device__ __forceinline__ ushort_t f2b(float f) {
    union { float f; unsigned int u; } v; v.f = f;
    return (ushort_t)((v.u + 0x8000u) >> 16);
}
__device__ __forceinline__ float b2f(ushort_t h) {
    union { unsigned int u; float f; } v; v.u = ((unsigned int)h) << 16;
    return v.f;
}

// direct global->LDS copy, 16B per lane; LDS dest is wave-uniform base + lane*16
__device__ __forceinline__ void gload16(const void* g, void* l) {
    __builtin_amdgcn_global_load_lds(
        (const __attribute__((address_space(1))) unsigned int*)g,
        (__attribute__((address_space(3))) unsigned int*)l, 16, 0, 0);
}

__device__ __forceinline__ unsigned umin_(unsigned a, unsigned b) { return a < b ? a : b; }
__device__ __forceinline__ unsigned umax_(unsigned a, unsigned b) { return a > b ? a : b; }

// Branchless top-K keep-smallest insert into ASCENDING sorted list
// (a[0] best .. a[K-1] worst).  med3 identity: since a[p-1] <= a[p],
//   new a[p] = med3(x, a[p-1], a[p]) = min(max(x, a[p-1]), a[p]).
// Kept SET identical to a guarded strict-less shift insert.  2 VALU
// ops/element, no branch, no divergence.
template<int K>
__device__ __forceinline__ void ins_asc(unsigned* a, unsigned x)
{
    #pragma unroll
    for (int p = K - 1; p >= 1; --p)
        a[p] = umin_(umax_(x, a[p - 1]), a[p]);
    a[0] = umin_(a[0], x);
}

// ---------------- projections: Q,K (split bf16), V (f32), skip (f32) -------
// 8 rows/block: W L2 traffic 256MB; per-row accumulation unchanged.
constexpr int PR = 8;
__global__ __launch_bounds__(128)
void proj_kernel(const float* __restrict__ x,
                 const float* __restrict__ Wq, const float* __restrict__ bq,
                 const float* __restrict__ Wk, const float* __restrict__ bk,
                 const float* __restrict__ Wv, const float* __restrict__ bv,
                 const float* __restrict__ Ws, const float* __restrict__ bs,
                 ushort_t* __restrict__ Qhi, ushort_t* __restrict__ Qlo,
                 ushort_t* __restrict__ Khi, ushort_t* __restrict__ Klo,
                 float* __restrict__ Vf, float* __restrict__ HS)
{
    __shared__ float xs[PR][DD];
    const int i0 = blockIdx.x * PR, t = threadIdx.x;
    #pragma unroll
    for (int r = 0; r < PR; ++r) xs[r][t] = x[(i0 + r) * DD + t];
    __syncthreads();
    float aq[PR], ak[PR], av[PR], ah[PR];
    #pragma unroll
    for (int r = 0; r < PR; ++r) { aq[r] = 0.f; ak[r] = 0.f; av[r] = 0.f; ah[r] = 0.f; }
    #pragma unroll 4
    for (int c = 0; c < DD; ++c) {
        const float wq = Wq[c * DD + t], wk = Wk[c * DD + t];
        const float wv = Wv[c * DD + t], ws = Ws[c * DD + t];
        #pragma unroll
        for (int r = 0; r < PR; ++r) {
            const float xv = xs[r][c];
            aq[r] = fmaf(xv, wq, aq[r]); ak[r] = fmaf(xv, wk, ak[r]);
            av[r] = fmaf(xv, wv, av[r]); ah[r] = fmaf(xv, ws, ah[r]);
        }
    }
    #pragma unroll
    for (int r = 0; r < PR; ++r) {
        const int o = (i0 + r) * DD + t;
        const float q = aq[r] + bq[t];
        const float k = ak[r] + bk[t];
        const ushort_t qh = f2b(q); Qhi[o] = qh; Qlo[o] = f2b(q - b2f(qh));
        const ushort_t kh = f2b(k); Khi[o] = kh; Klo[o] = f2b(k - b2f(kh));
        Vf[o] = av[r] + bv[t];
        HS[o] = ah[r] + bs[t];
    }
}

// ---------------- V transpose + split: VT{hi,lo}[f][n] = split(V[n][f]) ----
__global__ __launch_bounds__(256)
void vt_kernel(const float* __restrict__ Vf,
               ushort_t* __restrict__ VThi, ushort_t* __restrict__ VTlo)
{
    __shared__ float tile[64 * 132];
    const int k0 = blockIdx.x * 64, t = threadIdx.x;
    #pragma unroll
    for (int p = 0; p < 8; ++p) {
        const int slot = t + p * 256;        // 2048 slots: 64 rows x 32 f4-chunks
        const int r = slot >> 5, c4 = slot & 31;
        *reinterpret_cast<float4*>(&tile[r * 132 + c4 * 4]) =
            *reinterpret_cast<const float4*>(Vf + (k0 + r) * DD + c4 * 4);
    }
    __syncthreads();
    #pragma unroll
    for (int p = 0; p < 4; ++p) {
        const int slot = t + p * 256;        // 1024 slots: 128 feats x 8 chunks
        const int f = slot >> 3, kc = slot & 7;
        ushort_t hh[8], ll[8];
        #pragma unroll
        for (int i = 0; i < 8; ++i) {
            const float v = tile[(kc * 8 + i) * 132 + f];
            hh[i] = f2b(v); ll[i] = f2b(v - b2f(hh[i]));
        }
        *reinterpret_cast<uint4*>(VThi + f * NN + k0 + kc * 8) =
            *reinterpret_cast<const uint4*>(hh);
        *reinterpret_cast<uint4*>(VTlo + f * NN + k0 + kc * 8) =
            *reinterpret_cast<const uint4*>(ll);
    }
}

// ---------------- split-bf16 MFMA flash attention, fixed max ---------------
// 256-thread blocks (4 waves x 32 queries = 128 queries/block), grid 512.
// K/V DOUBLE-buffered via global_load_lds; K staged 2 windows ahead, V 1.
// Counted-vmcnt barriers (never 0 mid-loop); 2 blocks/CU.
constexpr int ANS  = 8;                 // key slices
constexpr int AKS  = NN / ANS;          // 1024 keys per slice
constexpr int BK   = 32;                // keys per tile
constexpr int PSTR = 40;                // P row stride (frozen)
constexpr int KSTR = 136;               // (knn kernel LDS stride; unchanged)

__global__ __launch_bounds__(256, 2)
void attn_kernel(const ushort_t* __restrict__ Qhi, const ushort_t* __restrict__ Qlo,
                 const ushort_t* __restrict__ Khg, const ushort_t* __restrict__ Klg,
                 const ushort_t* __restrict__ Vhg, const ushort_t* __restrict__ Vlg,
                 float* __restrict__ Opart, float* __restrict__ lpart)
{
    // K tiles: 32 rows x 128 bf16, linear rows; chunk XOR-swizzled (c^row&7)
    //          on global source + read side -> conflict-free ds_read_b128.
    // V tiles: 128 rows x 32 bf16, chunk XOR-swizzled (c^(row>>1)&3).
    // P strip: 16 rows x PSTR per wave (row = query lc; sub0/sub1 reuse).
    // Buffer map: K(t) in K?s[t&1], V(t) in V?s[t&1].
    __shared__ __align__(16) ushort_t Khs[2][BK * DD];
    __shared__ __align__(16) ushort_t Kls[2][BK * DD];
    __shared__ __align__(16) ushort_t Vhs[2][DD * BK];
    __shared__ __align__(16) ushort_t Vls[2][DD * BK];
    __shared__ __align__(16) ushort_t Phs[4][16 * PSTR];
    __shared__ __align__(16) ushort_t Pls[4][16 * PSTR];

    const int t  = threadIdx.x;
    const int w  = t >> 6, l = t & 63;
    const int lc = l & 15, lq = l >> 4;
    const int b  = blockIdx.x;
    const int s  = b >> 6;              // slice 0..7
    const int qb = b & 63;
    const int i0 = qb * 128;
    const int k0 = s * AKS;
    ushort_t* Pwh = Phs[w];
    ushort_t* Pwl = Pls[w];

    // staging coordinates (per thread, loop-invariant).
    const int lrK = w * 4 + (l >> 4);
    const int kchunk = ((l & 15) ^ (lrK & 7)) * 8;
    const ushort_t* gKh = Khg + (size_t)(k0 + lrK) * DD + kchunk;
    const ushort_t* gKl = Klg + (size_t)(k0 + lrK) * DD + kchunk;
    const int lrV = w * 16 + (l >> 2);
    const int vchunk = ((l & 3) ^ ((l >> 3) & 3)) * 8;
    const ushort_t* gVh = Vhg + (size_t)lrV * NN + k0 + vchunk;
    const ushort_t* gVl = Vlg + (size_t)lrV * NN + k0 + vchunk;

#define STAGE_K(buf, koff) do {                                              \
    gload16(gKh + (size_t)(koff) * DD,        &Khs[buf][(w * 4) * DD]);      \
    gload16(gKh + (size_t)((koff) + 16) * DD, &Khs[buf][(16 + w * 4) * DD]); \
    gload16(gKl + (size_t)(koff) * DD,        &Kls[buf][(w * 4) * DD]);      \
    gload16(gKl + (size_t)((koff) + 16) * DD, &Kls[buf][(16 + w * 4) * DD]); \
  } while (0)
#define STAGE_V(buf, koff) do {                                              \
    gload16(gVh + (koff),                     &Vhs[buf][(w * 16) * BK]);     \
    gload16(gVh + (size_t)64 * NN + (koff),   &Vhs[buf][(64 + w * 16) * BK]);\
    gload16(gVl + (koff),                     &Vls[buf][(w * 16) * BK]);     \
    gload16(gVl + (size_t)64 * NN + (koff),   &Vls[buf][(64 + w * 16) * BK]);\
  } while (0)
#define LGKM0() asm volatile("s_waitcnt lgkmcnt(0)" ::: "memory")
#define VMW(n)  asm volatile("s_waitcnt vmcnt(" #n ")" ::: "memory")
#define BARRIER() do { __builtin_amdgcn_s_barrier(); \
                       __builtin_amdgcn_sched_barrier(0); } while (0)

    bf16x8 qh[2][4], ql[2][4];
    #pragma unroll
    for (int sub = 0; sub < 2; ++sub) {
        const int row = i0 + w * 32 + sub * 16 + lc;
        #pragma unroll
        for (int kb = 0; kb < 4; ++kb) {
            qh[sub][kb] = *reinterpret_cast<const bf16x8*>(Qhi + row * DD + kb * 32 + lq * 8);
            ql[sub][kb] = *reinterpret_cast<const bf16x8*>(Qlo + row * DD + kb * 32 + lq * 8);
        }
    }

    const f32x4 zz = {0.f, 0.f, 0.f, 0.f};
    f32x4 oacc[2][8];
    #pragma unroll
    for (int sub = 0; sub < 2; ++sub)
        #pragma unroll
        for (int ft = 0; ft < 8; ++ft) oacc[sub][ft] = zz;
    float lrow[2] = {0.f, 0.f};         // per-lane partial denom, query = lc

    bf16x8 pah[2] = {}, pal[2] = {};    // carried P fragments (tile t-1)
    const int vc = (lq ^ ((lc >> 1) & 3)) * 8;   // V read-side unswizzle

    // prologue: K(0), K(1), V(0) issued; wait K(0) (allow 8 newer in flight)
    STAGE_K(0, 0);
    STAGE_K(1, BK);
    STAGE_V(0, 0);
    VMW(8);
    BARRIER();

    constexpr int NT = AKS / BK;        // 32 tiles
    for (int it = 0; it < NT; ++it) {
        const int jt  = k0 + it * BK;
        const int cur = it & 1;
        const ushort_t* Kh = Khs[cur];
        const ushort_t* Kl = Kls[cur];
        const ushort_t* Vph = Vhs[cur ^ 1];   // V(t-1)
        const ushort_t* Vpl = Vls[cur ^ 1];

        // ---- S^T = K Q^T (swapped: A=K, B=Q; bit-identical products) ----
        f32x4 sacc[2][2];               // [sub][kt]
        #pragma unroll
        for (int sub = 0; sub < 2; ++sub)
            #pragma unroll
            for (int kt = 0; kt < 2; ++kt) sacc[sub][kt] = zz;
        __builtin_amdgcn_s_setprio(1);
        #pragma unroll
        for (int kt = 0; kt < 2; ++kt) {
            const int kro = (kt * 16 + lc) * DD;
            #pragma unroll
            for (int kb = 0; kb < 4; ++kb) {
                const int cp = ((kb * 4 + lq) ^ (lc & 7)) * 8;  // read-side unswizzle
                const bf16x8 kh = *reinterpret_cast<const bf16x8*>(&Kh[kro + cp]);
                const bf16x8 kl = *reinterpret_cast<const bf16x8*>(&Kl[kro + cp]);
                #pragma unroll
                for (int sub = 0; sub < 2; ++sub) {
                    sacc[sub][kt] = MFMA16(kh, qh[sub][kb], sacc[sub][kt]);
                    sacc[sub][kt] = MFMA16(kh, ql[sub][kb], sacc[sub][kt]);
                    sacc[sub][kt] = MFMA16(kl, qh[sub][kb], sacc[sub][kt]);
                }
            }
        }
        __builtin_amdgcn_s_setprio(0);

        // ---- O += P(t-1) V(t-1) ----
        if (it > 0) {
            __builtin_amdgcn_s_setprio(1);
            #pragma unroll
            for (int ft = 0; ft < 8; ++ft) {
                const bf16x8 vh = *reinterpret_cast<const bf16x8*>(
                    &Vph[(ft * 16 + lc) * BK + vc]);
                const bf16x8 vl = *reinterpret_cast<const bf16x8*>(
                    &Vpl[(ft * 16 + lc) * BK + vc]);
                #pragma unroll
                for (int sub = 0; sub < 2; ++sub) {
                    oacc[sub][ft] = MFMA16(pah[sub], vh, oacc[sub][ft]);
                    oacc[sub][ft] = MFMA16(pal[sub], vh, oacc[sub][ft]);
                    oacc[sub][ft] = MFMA16(pah[sub], vl, oacc[sub][ft]);
                }
            }
            __builtin_amdgcn_s_setprio(0);
        }

        // barrier1: all waves' K(t)/V(t-1) ds_reads retired (lgkm only —
        // staged loads stay in flight).
        LGKM0();
        BARRIER();

        // deep prefetch: K(t+2) overwrites K(t)'s buffer (reads retired);
        // V(t+1) overwrites V(t-1)'s buffer (reads retired).
        if (it <= NT - 3) STAGE_K(cur, (it + 2) * BK);
        if (it <= NT - 2) STAGE_V(cur ^ 1, (it + 1) * BK);

        if ((jt & ~127) == i0) {            // diagonal mask
            #pragma unroll
            for (int sub = 0; sub < 2; ++sub) {
                const int gq = i0 + w * 32 + sub * 16 + lc;
                #pragma unroll
                for (int kt = 0; kt < 2; ++kt)
                    #pragma unroll
                    for (int r = 0; r < 4; ++r) {
                        const int gk = jt + kt * 16 + lq * 4 + r;
                        if (gk == gq) sacc[sub][kt][r] = -INFINITY;
                    }
            }
        }
        // ---- P = exp(S*SCALE): cvt_pk split; b64 write, b128 read to regs
        #pragma unroll
        for (int sub = 0; sub < 2; ++sub) {
            #pragma unroll
            for (int kt = 0; kt < 2; ++kt) {
                unsigned wh[2], wl[2];
                #pragma unroll
                for (int rr = 0; rr < 2; ++rr) {
                    const float p0 = __expf(sacc[sub][kt][rr * 2 + 0] * SCALE);
                    const float p1 = __expf(sacc[sub][kt][rr * 2 + 1] * SCALE);
                    lrow[sub] += p0;
                    lrow[sub] += p1;
                    unsigned hpk;
                    asm("v_cvt_pk_bf16_f32 %0, %1, %2"
                        : "=v"(hpk) : "v"(p0), "v"(p1));
                    wh[rr] = hpk;
                    const float h0 = __uint_as_float(hpk << 16);
                    const float h1 = __uint_as_float(hpk & 0xFFFF0000u);
                    unsigned lpk;
                    asm("v_cvt_pk_bf16_f32 %0, %1, %2"
                        : "=v"(lpk) : "v"(p0 - h0), "v"(p1 - h1));
                    wl[rr] = lpk;
                }
                const int eo = lc * PSTR + kt * 16 + lq * 4;
                *reinterpret_cast<uint2*>(&Pwh[eo]) = make_uint2(wh[0], wh[1]);
                *reinterpret_cast<uint2*>(&Pwl[eo]) = make_uint2(wl[0], wl[1]);
            }
            pah[sub] = *reinterpret_cast<const bf16x8*>(&Pwh[lc * PSTR + lq * 8]);
            pal[sub] = *reinterpret_cast<const bf16x8*>(&Pwl[lc * PSTR + lq * 8]);
        }

        // barrier2: K(t+1), V(t) landed block-wide; K(t+2)/V(t+1) (the 8
        // newest loads) stay in flight across the barrier.
        if (it <= NT - 3)      { VMW(8); }
        else if (it == NT - 2) { VMW(4); }
        else                   { VMW(0); }
        BARRIER();
    }
    // ---- epilogue: PV(NT-1); V(NT-1) in buffer (NT-1)&1 ----
    {
        const ushort_t* Vh = Vhs[(NT - 1) & 1];
        const ushort_t* Vl = Vls[(NT - 1) & 1];
        #pragma unroll
        for (int ft = 0; ft < 8; ++ft) {
            const bf16x8 vh = *reinterpret_cast<const bf16x8*>(
                &Vh[(ft * 16 + lc) * BK + vc]);
            const bf16x8 vl = *reinterpret_cast<const bf16x8*>(
                &Vl[(ft * 16 + lc) * BK + vc]);
            #pragma unroll
            for (int sub = 0; sub < 2; ++sub) {
                oacc[sub][ft] = MFMA16(pah[sub], vh, oacc[sub][ft]);
                oacc[sub][ft] = MFMA16(pal[sub], vh, oacc[sub][ft]);
                oacc[sub][ft] = MFMA16(pah[sub], vl, oacc[sub][ft]);
            }
        }
    }
#undef STAGE_K
#undef STAGE_V
#undef LGKM0
#undef VMW
#undef BARRIER

    // denom: lane holds partial for query=lc over keys lq*4+r; reduce over lq.
    #pragma unroll
    for (int sub = 0; sub < 2; ++sub) {
        float ps = lrow[sub];
        ps += __shfl_xor(ps, 16, 64);
        ps += __shfl_xor(ps, 32, 64);
        lrow[sub] = ps;
    }
    #pragma unroll
    for (int sub = 0; sub < 2; ++sub) {
        #pragma unroll
        for (int r = 0; r < 4; ++r) {
            const int row = i0 + w * 32 + sub * 16 + lq * 4 + r;
            float* po = Opart + ((size_t)s * NN + row) * DD;
            #pragma unroll
            for (int ft = 0; ft < 8; ++ft) po[ft * 16 + lc] = oacc[sub][ft][r];
        }
        if (l < 16)
            lpart[s * NN + i0 + w * 32 + sub * 16 + l] = lrow[sub];
    }
}

// ------- merge slices + skip, emit H/Hhi/SQ; FUSED mat1 (M1 = H @ W1) -----
// Phase 1: 32 threads/node, 4 features each (as before).  h quads also go
// to an 8x132 LDS tile.  Phase 2 (after one barrier): 2 halves x 128 cols,
// 4 rows each; c-sequential fmaf chain == old mat1 -> bit-identical M1.
__global__ __launch_bounds__(256)
void attn_merge_kernel(const float* __restrict__ Opart, const float* __restrict__ lpart,
                       const float* __restrict__ HS, float* __restrict__ H,
                       ushort_t* __restrict__ Hhi, float* __restrict__ SQ,
                       const float* __restrict__ W1, float* __restrict__ M1)
{
    __shared__ float xs[8][132];
    const int t = threadIdx.x;
    const int gid = blockIdx.x * 256 + t;
    const int i = gid >> 5;             // node
    const int f = (gid & 31) * 4;       // feature quad
    float ls = 0.f;
    float4 o = {0.f, 0.f, 0.f, 0.f};
    #pragma unroll
    for (int s = 0; s < ANS; ++s) {
        ls += lpart[s * NN + i];
        const float4 ov = *reinterpret_cast<const float4*>(
            Opart + ((size_t)s * NN + i) * DD + f);
        o.x += ov.x; o.y += ov.y; o.z += ov.z; o.w += ov.w;
    }
    const float4 hs = *reinterpret_cast<const float4*>(HS + i * DD + f);
    const float inv = 1.f / ls;
    float4 h;
    h.x = o.x * inv + hs.x; h.y = o.y * inv + hs.y;
    h.z = o.z * inv + hs.z; h.w = o.w * inv + hs.w;
    *reinterpret_cast<float4*>(H + i * DD + f) = h;
    *reinterpret_cast<float4*>(&xs[t >> 5][f]) = h;
    ushort_t hb[4] = {f2b(h.x), f2b(h.y), f2b(h.z), f2b(h.w)};
    *reinterpret_cast<uint2*>(Hhi + i * DD + f) = *reinterpret_cast<const uint2*>(hb);
    float sq = h.x * h.x + h.y * h.y + h.z * h.z + h.w * h.w;
    sq += __shfl_xor(sq, 1, 64);
    sq += __shfl_xor(sq, 2, 64);
    sq += __shfl_xor(sq, 4, 64);
    sq += __shfl_xor(sq, 8, 64);
    sq += __shfl_xor(sq, 16, 64);       // xor<32 stays within the 32-lane node group
    if ((t & 31) == 0) SQ[i] = sq;

    __syncthreads();                    // xs tile complete
    // ---- mat1 phase: rows = this block's 8 nodes ----
    const int col = t & 127, half = t >> 7;   // half 0: rows 0-3; half 1: rows 4-7
    float a[4] = {0.f, 0.f, 0.f, 0.f};
    #pragma unroll 4
    for (int c = 0; c < DD; ++c) {
        const float wv = W1[c * DD + col];
        #pragma unroll
        for (int r = 0; r < 4; ++r)
            a[r] = fmaf(xs[half * 4 + r][c], wv, a[r]);
    }
    const int n0 = blockIdx.x * 8 + half * 4;
    #pragma unroll
    for (int r = 0; r < 4; ++r)
        M1[(n0 + r) * DD + col] = a[r];
}

// ---------------- kNN: swapped-operand MFMA, register top-NL (u32) ---------
constexpr int KNSL = 16;                // key slices (512 keys each)
constexpr int KSL  = NN / KNSL;         // 512

__global__ __launch_bounds__(256, 4)
void knn_kernel(const ushort_t* __restrict__ Hhi, const float* __restrict__ SQg,
                unsigned* __restrict__ candV)
{
    __shared__ __align__(16) ushort_t Khi[64 * KSTR];
    __shared__ __align__(16) float sqs[64];

    const int t  = threadIdx.x;
    const int w  = t >> 6, l = t & 63;
    const int lc = l & 15, lq = l >> 4;
    const int b  = blockIdx.x;
    const int s  = b >> 6;              // slice 0..15
    const int qb = b & 63;
    const int i0 = qb * 128;
    const int k0 = s * KSL;

    const int kr = t >> 4, kc2 = t & 15;   // staging coords (4 chunks of 16 rows)

    const int gq0 = i0 + w * 32 + lc;          // sub=0 query
    const int gq1 = gq0 + 16;                  // sub=1 query
    const float sqi0 = SQg[gq0];
    const float sqi1 = SQg[gq1];

    bf16x8 qf[2][4];                    // B operand: B[n=query=lc][k=lq*8+j]
    #pragma unroll
    for (int sub = 0; sub < 2; ++sub) {
        const int row = i0 + w * 32 + sub * 16 + lc;
        #pragma unroll
        for (int kb = 0; kb < 4; ++kb)
            qf[sub][kb] = *reinterpret_cast<const bf16x8*>(Hhi + row * DD + kb * 32 + lq * 8);
    }

    unsigned lists[2][NL];              // ascending: [0] best .. [NL-1] worst
    #pragma unroll
    for (int sub = 0; sub < 2; ++sub)
        #pragma unroll
        for (int p = 0; p < NL; ++p) lists[sub][p] = 0xFFFFFFFFu;

    // prefetch tile 0 (knn has VGPR headroom, no spill at 4 waves/EU)
    uint4 pk[4]; float psq;
    #pragma unroll
    for (int p = 0; p < 4; ++p)
        pk[p] = *reinterpret_cast<const uint4*>(Hhi + (k0 + kr + p * 16) * DD + kc2 * 8);
    psq = (t < 64) ? SQg[k0 + t] : 0.f;

    const f32x4 zz = {0.f, 0.f, 0.f, 0.f};
    for (int jt0 = 0; jt0 < KSL; jt0 += 64) {
        const int jt = k0 + jt0;
        __syncthreads();                 // prev K-frag reads done
        #pragma unroll
        for (int p = 0; p < 4; ++p)
            *reinterpret_cast<uint4*>(&Khi[(kr + p * 16) * KSTR + kc2 * 8]) = pk[p];
        if (t < 64) sqs[t] = psq;
        __syncthreads();
        if (jt0 + 64 < KSL) {            // prefetch next during compute
            const int jn = jt + 64;
            #pragma unroll
            for (int p = 0; p < 4; ++p)
                pk[p] = *reinterpret_cast<const uint4*>(Hhi + (jn + kr + p * 16) * DD + kc2 * 8);
            psq = (t < 64) ? SQg[jn + t] : 0.f;
        }

        f32x4 acc[2][4];                 // [sub][kt]
        #pragma unroll
        for (int sub = 0; sub < 2; ++sub)
            #pragma unroll
            for (int kt = 0; kt < 4; ++kt) acc[sub][kt] = zz;
        #pragma unroll
        for (int kt = 0; kt < 4; ++kt) {
            #pragma unroll
            for (int kb = 0; kb < 4; ++kb) {
                const bf16x8 kf = *reinterpret_cast<const bf16x8*>(
                    &Khi[(kt * 16 + lc) * KSTR + kb * 32 + lq * 8]);
                acc[0][kt] = MFMA16(kf, qf[0][kb], acc[0][kt]);   // A=key, B=query
                acc[1][kt] = MFMA16(kf, qf[1][kb], acc[1][kt]);
            }
        }

        const bool ovl = ((jt & ~127) == i0);
        #pragma unroll
        for (int kt = 0; kt < 4; ++kt) {
            const float4 sq4 = *reinterpret_cast<const float4*>(&sqs[kt * 16 + lq * 4]);
            const float sqj[4] = {sq4.x, sq4.y, sq4.z, sq4.w};
            #pragma unroll
            for (int r = 0; r < 4; ++r) {
                const int gk = jt + kt * 16 + lq * 4 + r;
                float d0 = fmaf(-2.f, acc[0][kt][r], sqi0 + sqj[r]);
                float d1 = fmaf(-2.f, acc[1][kt][r], sqi1 + sqj[r]);
                if (ovl) {
                    if (gk == gq0) d0 = INFINITY;
                    if (gk == gq1) d1 = INFINITY;
                }
                const unsigned u0 = (__float_as_uint(d0) & 0xFFFFE000u) | (unsigned)gk;
                const unsigned u1 = (__float_as_uint(d1) & 0xFFFFE000u) | (unsigned)gk;
                ins_asc<NL>(lists[0], u0);
                ins_asc<NL>(lists[1], u1);
            }
        }
    }

    // ---- in-kernel lq-merge: Khi is dead, reuse as scratch ----
    __syncthreads();                     // all waves done with Khi MFMA reads
    unsigned* msw = reinterpret_cast<unsigned*>(Khi) + w * (16 * 4 * NL);
    #pragma unroll
    for (int sub = 0; sub < 2; ++sub) {
        #pragma unroll
        for (int p = 0; p < NL; ++p)
            msw[lc * (4 * NL) + lq * NL + p] = lists[sub][p];
        __syncthreads();
        if (lq == 0) {                   // 16 lanes/wave: one query each
            unsigned bk[NL];             // seed with lane-0 list (ascending)
            #pragma unroll
            for (int p = 0; p < NL; ++p) bk[p] = msw[lc * (4 * NL) + p];
            #pragma unroll
            for (int o = 1; o < 4; ++o)
                #pragma unroll
                for (int e = 0; e < NL; ++e)
                    ins_asc<NL>(bk, msw[lc * (4 * NL) + o * NL + e]);
            const int node = i0 + w * 32 + sub * 16 + lc;
            #pragma unroll
            for (int p = 0; p < NL; ++p)
                candV[((size_t)s * NL + p) * NN + node] = bk[p];
        }
        __syncthreads();
    }
}

// ------- final merge: 16 slice lists -> top-12 candidates per node ---------
__global__ __launch_bounds__(64)
void knn_merge_kernel(const unsigned* __restrict__ candV, int* __restrict__ CAND)
{
    const int q = blockIdx.x * 64 + threadIdx.x;
    unsigned bk[NCAND];
    #pragma unroll
    for (int p = 0; p < NCAND; ++p) bk[p] = 0xFFFFFFFFu;
    for (int s = 0; s < KNSL; ++s)
        #pragma unroll
        for (int e = 0; e < NL; ++e)
            ins_asc<NCAND>(bk, candV[((size_t)s * NL + e) * NN + q]);
    #pragma unroll
    for (int p = 0; p < NCAND; ++p)
        CAND[q * NCAND + p] = (int)(bk[p] & 8191u);
}

// ---------------- exact fp32 re-rank of candidates -> IDX ----------------
__global__ __launch_bounds__(256)
void rerank_kernel(const float* __restrict__ H, const float* __restrict__ SQ,
                   const int* __restrict__ CAND, int* __restrict__ IDX)
{
    const int t = threadIdx.x;
    const int w = t >> 6, l = t & 63;
    const int node = blockIdx.x * 4 + w;
    const float h0 = H[node * DD + l];
    const float h1 = H[node * DD + 64 + l];
    float dk[NCAND]; int di[NCAND];
    #pragma unroll
    for (int c = 0; c < NCAND; ++c) {
        const int j = CAND[node * NCAND + c];
        float p = h0 * H[j * DD + l] + h1 * H[j * DD + 64 + l];
        p += __shfl_xor(p, 1, 64);
        p += __shfl_xor(p, 2, 64);
        p += __shfl_xor(p, 4, 64);
        p += __shfl_xor(p, 8, 64);
        p += __shfl_xor(p, 16, 64);
        p += __shfl_xor(p, 32, 64);
        dk[c] = SQ[j] - 2.f * p;
        di[c] = j;
    }
    if (l == 0) {
        #pragma unroll
        for (int s = 0; s < KNB; ++s) {
            int best = s;
            #pragma unroll
            for (int c = s + 1; c < NCAND; ++c) {
                const bool lt = (dk[c] < dk[best]) ||
                                (dk[c] == dk[best] && di[c] < di[best]);
                if (lt) best = c;
            }
            const float tk = dk[s]; dk[s] = dk[best]; dk[best] = tk;
            const int   ti = di[s]; di[s] = di[best]; di[best] = ti;
            IDX[node * KNB + s] = di[s];
        }
    }
}

// -------- fused: H1 = relu((sum_nbr M1 + M1)/8 + b1); M2 = H1.W2 ----------
// One node per wave; lane l handles features l and l+64.  shfl_xor reduce
// in order 32,16,8,4,2,1 replays the old LDS tree pairing -> bit-identical.
__global__ __launch_bounds__(256)
void g1m2_kernel(const float* __restrict__ M1, const int* __restrict__ IDX,
                 const float* __restrict__ b1, const float* __restrict__ W2,
                 float* __restrict__ M2)
{
    const int t = threadIdx.x;
    const int w = t >> 6, l = t & 63;
    const int i = blockIdx.x * 4 + w;
    float s0 = M1[i * DD + l];
    float s1 = M1[i * DD + 64 + l];
    #pragma unroll
    for (int p = 0; p < KNB; ++p) {
        const int j = IDX[i * KNB + p];
        s0 += M1[j * DD + l];
        s1 += M1[j * DD + 64 + l];
    }
    const float g0 = fmaxf(s0 * 0.125f + b1[l], 0.f);
    const float g1 = fmaxf(s1 * 0.125f + b1[64 + l], 0.f);
    float r = g0 * W2[l] + g1 * W2[64 + l];   // == old red[l] after s2=64 step
    r += __shfl_xor(r, 32, 64);
    r += __shfl_xor(r, 16, 64);
    r += __shfl_xor(r, 8, 64);
    r += __shfl_xor(r, 4, 64);
    r += __shfl_xor(r, 2, 64);
    r += __shfl_xor(r, 1, 64);
    if (l == 0) M2[i] = r;
}

// ---------------- out = (sum_nbr M2 + M2)/8 + b2 ----------------
__global__ __launch_bounds__(256)
void out_kernel(const float* __restrict__ M2, const int* __restrict__ IDX,
                const float* __restrict__ b2, float* __restrict__ out)
{
    const int i = blockIdx.x * 256 + threadIdx.x;
    if (i < NN) {
        float s = M2[i];
        #pragma unroll
        for (int p = 0; p < KNB; ++p) s += M2[IDX[i * KNB + p]];
        out[i] = s * 0.125f + b2[0];
    }
}

// ---------------------------------------------------------------------------
extern "C" void kernel_launch(void* const* d_in, const int* in_sizes, int n_in,
                              void* d_out, int out_size, void* d_ws, size_t ws_size,
                              hipStream_t stream)
{
    const float* x   = (const float*)d_in[0];
    const float* Wq  = (const float*)d_in[1];
    const float* bq  = (const float*)d_in[2];
    const float* Wk  = (const float*)d_in[3];
    const float* bk  = (const float*)d_in[4];
    const float* Wv  = (const float*)d_in[5];
    const float* bv  = (const float*)d_in[6];
    const float* Wsk = (const float*)d_in[7];
    const float* bsk = (const float*)d_in[8];
    const float* W1  = (const float*)d_in[9];
    const float* b1  = (const float*)d_in[10];
    const float* W2  = (const float*)d_in[11];
    const float* b2  = (const float*)d_in[12];

    constexpr size_t MB = 1024 * 1024;
    char* W = (char*)d_ws;
    // persistent: [0,8) Q/K splits, [8,12) VT splits, [12,16) HS (->H in place)
    ushort_t* Qhi  = (ushort_t*)(W + 0 * MB);
    ushort_t* Qlo  = (ushort_t*)(W + 2 * MB);
    ushort_t* Khi  = (ushort_t*)(W + 4 * MB);
    ushort_t* Klo  = (ushort_t*)(W + 6 * MB);
    ushort_t* VThi = (ushort_t*)(W + 8 * MB);
    ushort_t* VTlo = (ushort_t*)(W + 10 * MB);
    float*    HS   = (float*)(W + 12 * MB);
    float*    H    = HS;                                   // in-place merge
    ushort_t* Hhi  = Qhi;            // Q dead after attn; Hhi written by merge
    // small: [16,17)
    float* lpart = (float*)(W + 16 * MB);                  // 256KB
    float* SQ    = (float*)(W + 16 * MB + 256 * 1024);     // 32KB
    float* M2    = SQ + NN;                                // 32KB
    int*   IDX   = (int*)(M2 + NN);                        // 224KB
    // union: [17,49):
    //   Vf32  [17,21)   dead after vt
    //   Opart [17,49)   read by fused attn_merge (M1 must NOT overlap!)
    //   candV [17,22.25) written by knn, dead after knn_merge (5.25MB)
    //   CAND  [23,23.4) written by knn_merge, dead after rerank
    // M1 at [49,53): outside Opart (fused merge writes M1 while reading
    // Opart).  ws >= 81MB confirmed (r19 big path ran).
    float*    Vf32  = (float*)(W + 17 * MB);
    float*    Opart = (float*)(W + 17 * MB);
    unsigned* candV = (unsigned*)(W + 17 * MB);
    int*      CAND  = (int*)(W + 23 * MB);
    float*    M1    = (float*)(W + 49 * MB);

    proj_kernel<<<NN / PR, 128, 0, stream>>>(x, Wq, bq, Wk, bk, Wv, bv, Wsk, bsk,
                                             Qhi, Qlo, Khi, Klo, Vf32, HS);
    vt_kernel<<<NN / 64, 256, 0, stream>>>(Vf32, VThi, VTlo);
    attn_kernel<<<ANS * 64, 256, 0, stream>>>(Qhi, Qlo, Khi, Klo, VThi, VTlo,
                                              Opart, lpart);
    attn_merge_kernel<<<(NN * 32) / 256, 256, 0, stream>>>(Opart, lpart, HS, H,
                                                           Hhi, SQ, W1, M1);
    knn_kernel<<<KNSL * 64, 256, 0, stream>>>(Hhi, SQ, candV);
    knn_merge_kernel<<<NN / 64, 64, 0, stream>>>(candV, CAND);
    rerank_kernel<<<NN / 4, 256, 0, stream>>>(H, SQ, CAND, IDX);
    g1m2_kernel<<<NN / 4, 256, 0, stream>>>(M1, IDX, b1, W2, M2);
    out_kernel<<<NN / 256, 256, 0, stream>>>(M2, IDX, b2, (float*)d_out);
}

// Round 12
// 320.038 us; speedup vs baseline: 1.0416x; 1.0070x over previous
//
#include <hip/hip_runtime.h>
#include <cmath>

// ---------------------------------------------------------------------------
// GraphTransformer on MI355X.  N=8192, D=128, k=7, OUT=1.
// Attention: split-bf16 (hi/lo) MFMA flash, fixed max (logits bounded).
//   FROZEN config (every deviation regressed):
//   - QK^T 3-term split (round-10: plain bf16 QK flips kNN neighbors)
//   - NO register prefetch of K tiles (round-8 spills) -- global_load_lds
//   - PSTR=40 row stride for P (round-12)
//   - swapped QK^T (A=K,B=Q) + packed-b64 P round-trip (r15)
//   - branchless med3 top-K insert in kNN (r16)
//   - cross-tile PV pipeline (r17); cvt_pk exp pack (r20)
//   - ANS=8 / grid 512 (r19 ERRATum: finer key-split didn't raise occupancy;
//     2 blocks/CU is a hard cap -- LDS pool/granularity)
//   - T4 counted-vmcnt pipeline (r21: attn 93.6us best)
//   - g1m2 wave-per-node + mat1 fused into attn_merge (r23: total -10us;
//     STRUCTURE moves the tail, traffic arithmetic doesn't)
// Round-24 (this round): fuse vt INTO proj.  proj thread t owns feature t
// for 8 consecutive nodes == exactly one 16B chunk of VT[f][n] -> pack
// hi/lo uint4 and store VThi[t*NN+i0] directly.  Same split math ->
// bit-identical VThi/VTlo; Vf32 (4MB write + 4MB read) and the vt launch
// are eliminated.  Everything else = r23 winner.
// kNN: swapped-operand bf16 MFMA, per-lane register top-10 (u32-packed),
// in-kernel lq-merge -> candV, parallel final merge, exact fp32 re-rank.
// ---------------------------------------------------------------------------

typedef unsigned short ushort_t;

constexpr int   NN    = 8192;
constexpr int   DD    = 128;
constexpr int   KNB   = 7;
constexpr int   NL    = 10;              // per-lane kept candidates (knn)
constexpr int   NCAND = 12;              // merged candidates per node
constexpr float SCALE = 0.088388347648318447f;   // 1/sqrt(128)

using bf16x8 = __attribute__((ext_vector_type(8))) short;   // 8 bf16 = 4 VGPR
using f32x4  = __attribute__((ext_vector_type(4))) float;   // mfma acc

#define MFMA16(a, b, c) __builtin_amdgcn_mfma_f32_16x16x32_bf16((a), (b), (c), 0, 0, 0)

__device__ __forceinline__ ushort_t f2b(float f) {
    union { float f; unsigned int u; } v; v.f = f;
    return (ushort_t)((v.u + 0x8000u) >> 16);
}
__device__ __forceinline__ float b2f(ushort_t h) {
    union { unsigned int u; float f; } v; v.u = ((unsigned int)h) << 16;
    return v.f;
}

// direct global->LDS copy, 16B per lane; LDS dest is wave-uniform base + lane*16
__device__ __forceinline__ void gload16(const void* g, void* l) {
    __builtin_amdgcn_global_load_lds(
        (const __attribute__((address_space(1))) unsigned int*)g,
        (__attribute__((address_space(3))) unsigned int*)l, 16, 0, 0);
}

__device__ __forceinline__ unsigned umin_(unsigned a, unsigned b) { return a < b ? a : b; }
__device__ __forceinline__ unsigned umax_(unsigned a, unsigned b) { return a > b ? a : b; }

// Branchless top-K keep-smallest insert into ASCENDING sorted list
// (a[0] best .. a[K-1] worst).  med3 identity: since a[p-1] <= a[p],
//   new a[p] = med3(x, a[p-1], a[p]) = min(max(x, a[p-1]), a[p]).
// Kept SET identical to a guarded strict-less shift insert.  2 VALU
// ops/element, no branch, no divergence.
template<int K>
__device__ __forceinline__ void ins_asc(unsigned* a, unsigned x)
{
    #pragma unroll
    for (int p = K - 1; p >= 1; --p)
        a[p] = umin_(umax_(x, a[p - 1]), a[p]);
    a[0] = umin_(a[0], x);
}

// ----- projections: Q,K (split bf16), skip (f32), V DIRECT to VT splits ----
// 8 rows/block.  Thread t = feature t; its 8 per-node V values form one
// contiguous 16B chunk of VT[f][n] -> vt_kernel fused away (bit-identical
// split math; Vf32 round-trip eliminated).
constexpr int PR = 8;
__global__ __launch_bounds__(128)
void proj_kernel(const float* __restrict__ x,
                 const float* __restrict__ Wq, const float* __restrict__ bq,
                 const float* __restrict__ Wk, const float* __restrict__ bk,
                 const float* __restrict__ Wv, const float* __restrict__ bv,
                 const float* __restrict__ Ws, const float* __restrict__ bs,
                 ushort_t* __restrict__ Qhi, ushort_t* __restrict__ Qlo,
                 ushort_t* __restrict__ Khi, ushort_t* __restrict__ Klo,
                 ushort_t* __restrict__ VThi, ushort_t* __restrict__ VTlo,
                 float* __restrict__ HS)
{
    __shared__ float xs[PR][DD];
    const int i0 = blockIdx.x * PR, t = threadIdx.x;
    #pragma unroll
    for (int r = 0; r < PR; ++r) xs[r][t] = x[(i0 + r) * DD + t];
    __syncthreads();
    float aq[PR], ak[PR], av[PR], ah[PR];
    #pragma unroll
    for (int r = 0; r < PR; ++r) { aq[r] = 0.f; ak[r] = 0.f; av[r] = 0.f; ah[r] = 0.f; }
    #pragma unroll 4
    for (int c = 0; c < DD; ++c) {
        const float wq = Wq[c * DD + t], wk = Wk[c * DD + t];
        const float wv = Wv[c * DD + t], ws = Ws[c * DD + t];
        #pragma unroll
        for (int r = 0; r < PR; ++r) {
            const float xv = xs[r][c];
            aq[r] = fmaf(xv, wq, aq[r]); ak[r] = fmaf(xv, wk, ak[r]);
            av[r] = fmaf(xv, wv, av[r]); ah[r] = fmaf(xv, ws, ah[r]);
        }
    }
    ushort_t vh8[PR], vl8[PR];
    #pragma unroll
    for (int r = 0; r < PR; ++r) {
        const int o = (i0 + r) * DD + t;
        const float q = aq[r] + bq[t];
        const float k = ak[r] + bk[t];
        const ushort_t qh = f2b(q); Qhi[o] = qh; Qlo[o] = f2b(q - b2f(qh));
        const ushort_t kh = f2b(k); Khi[o] = kh; Klo[o] = f2b(k - b2f(kh));
        const float v = av[r] + bv[t];
        const ushort_t vh = f2b(v);
        vh8[r] = vh; vl8[r] = f2b(v - b2f(vh));
        HS[o] = ah[r] + bs[t];
    }
    *reinterpret_cast<uint4*>(VThi + (size_t)t * NN + i0) =
        *reinterpret_cast<const uint4*>(vh8);
    *reinterpret_cast<uint4*>(VTlo + (size_t)t * NN + i0) =
        *reinterpret_cast<const uint4*>(vl8);
}

// ---------------- split-bf16 MFMA flash attention, fixed max ---------------
// 256-thread blocks (4 waves x 32 queries = 128 queries/block), grid 512.
// K/V DOUBLE-buffered via global_load_lds; K staged 2 windows ahead, V 1.
// Counted-vmcnt barriers (never 0 mid-loop); 2 blocks/CU.
constexpr int ANS  = 8;                 // key slices
constexpr int AKS  = NN / ANS;          // 1024 keys per slice
constexpr int BK   = 32;                // keys per tile
constexpr int PSTR = 40;                // P row stride (frozen)
constexpr int KSTR = 136;               // (knn kernel LDS stride; unchanged)

__global__ __launch_bounds__(256, 2)
void attn_kernel(const ushort_t* __restrict__ Qhi, const ushort_t* __restrict__ Qlo,
                 const ushort_t* __restrict__ Khg, const ushort_t* __restrict__ Klg,
                 const ushort_t* __restrict__ Vhg, const ushort_t* __restrict__ Vlg,
                 float* __restrict__ Opart, float* __restrict__ lpart)
{
    // K tiles: 32 rows x 128 bf16, linear rows; chunk XOR-swizzled (c^row&7)
    //          on global source + read side -> conflict-free ds_read_b128.
    // V tiles: 128 rows x 32 bf16, chunk XOR-swizzled (c^(row>>1)&3).
    // P strip: 16 rows x PSTR per wave (row = query lc; sub0/sub1 reuse).
    // Buffer map: K(t) in K?s[t&1], V(t) in V?s[t&1].
    __shared__ __align__(16) ushort_t Khs[2][BK * DD];
    __shared__ __align__(16) ushort_t Kls[2][BK * DD];
    __shared__ __align__(16) ushort_t Vhs[2][DD * BK];
    __shared__ __align__(16) ushort_t Vls[2][DD * BK];
    __shared__ __align__(16) ushort_t Phs[4][16 * PSTR];
    __shared__ __align__(16) ushort_t Pls[4][16 * PSTR];

    const int t  = threadIdx.x;
    const int w  = t >> 6, l = t & 63;
    const int lc = l & 15, lq = l >> 4;
    const int b  = blockIdx.x;
    const int s  = b >> 6;              // slice 0..7
    const int qb = b & 63;
    const int i0 = qb * 128;
    const int k0 = s * AKS;
    ushort_t* Pwh = Phs[w];
    ushort_t* Pwl = Pls[w];

    // staging coordinates (per thread, loop-invariant).
    const int lrK = w * 4 + (l >> 4);
    const int kchunk = ((l & 15) ^ (lrK & 7)) * 8;
    const ushort_t* gKh = Khg + (size_t)(k0 + lrK) * DD + kchunk;
    const ushort_t* gKl = Klg + (size_t)(k0 + lrK) * DD + kchunk;
    const int lrV = w * 16 + (l >> 2);
    const int vchunk = ((l & 3) ^ ((l >> 3) & 3)) * 8;
    const ushort_t* gVh = Vhg + (size_t)lrV * NN + k0 + vchunk;
    const ushort_t* gVl = Vlg + (size_t)lrV * NN + k0 + vchunk;

#define STAGE_K(buf, koff) do {                                              \
    gload16(gKh + (size_t)(koff) * DD,        &Khs[buf][(w * 4) * DD]);      \
    gload16(gKh + (size_t)((koff) + 16) * DD, &Khs[buf][(16 + w * 4) * DD]); \
    gload16(gKl + (size_t)(koff) * DD,        &Kls[buf][(w * 4) * DD]);      \
    gload16(gKl + (size_t)((koff) + 16) * DD, &Kls[buf][(16 + w * 4) * DD]); \
  } while (0)
#define STAGE_V(buf, koff) do {                                              \
    gload16(gVh + (koff),                     &Vhs[buf][(w * 16) * BK]);     \
    gload16(gVh + (size_t)64 * NN + (koff),   &Vhs[buf][(64 + w * 16) * BK]);\
    gload16(gVl + (koff),                     &Vls[buf][(w * 16) * BK]);     \
    gload16(gVl + (size_t)64 * NN + (koff),   &Vls[buf][(64 + w * 16) * BK]);\
  } while (0)
#define LGKM0() asm volatile("s_waitcnt lgkmcnt(0)" ::: "memory")
#define VMW(n)  asm volatile("s_waitcnt vmcnt(" #n ")" ::: "memory")
#define BARRIER() do { __builtin_amdgcn_s_barrier(); \
                       __builtin_amdgcn_sched_barrier(0); } while (0)

    bf16x8 qh[2][4], ql[2][4];
    #pragma unroll
    for (int sub = 0; sub < 2; ++sub) {
        const int row = i0 + w * 32 + sub * 16 + lc;
        #pragma unroll
        for (int kb = 0; kb < 4; ++kb) {
            qh[sub][kb] = *reinterpret_cast<const bf16x8*>(Qhi + row * DD + kb * 32 + lq * 8);
            ql[sub][kb] = *reinterpret_cast<const bf16x8*>(Qlo + row * DD + kb * 32 + lq * 8);
        }
    }

    const f32x4 zz = {0.f, 0.f, 0.f, 0.f};
    f32x4 oacc[2][8];
    #pragma unroll
    for (int sub = 0; sub < 2; ++sub)
        #pragma unroll
        for (int ft = 0; ft < 8; ++ft) oacc[sub][ft] = zz;
    float lrow[2] = {0.f, 0.f};         // per-lane partial denom, query = lc

    bf16x8 pah[2] = {}, pal[2] = {};    // carried P fragments (tile t-1)
    const int vc = (lq ^ ((lc >> 1) & 3)) * 8;   // V read-side unswizzle

    // prologue: K(0), K(1), V(0) issued; wait K(0) (allow 8 newer in flight)
    STAGE_K(0, 0);
    STAGE_K(1, BK);
    STAGE_V(0, 0);
    VMW(8);
    BARRIER();

    constexpr int NT = AKS / BK;        // 32 tiles
    for (int it = 0; it < NT; ++it) {
        const int jt  = k0 + it * BK;
        const int cur = it & 1;
        const ushort_t* Kh = Khs[cur];
        const ushort_t* Kl = Kls[cur];
        const ushort_t* Vph = Vhs[cur ^ 1];   // V(t-1)
        const ushort_t* Vpl = Vls[cur ^ 1];

        // ---- S^T = K Q^T (swapped: A=K, B=Q; bit-identical products) ----
        f32x4 sacc[2][2];               // [sub][kt]
        #pragma unroll
        for (int sub = 0; sub < 2; ++sub)
            #pragma unroll
            for (int kt = 0; kt < 2; ++kt) sacc[sub][kt] = zz;
        __builtin_amdgcn_s_setprio(1);
        #pragma unroll
        for (int kt = 0; kt < 2; ++kt) {
            const int kro = (kt * 16 + lc) * DD;
            #pragma unroll
            for (int kb = 0; kb < 4; ++kb) {
                const int cp = ((kb * 4 + lq) ^ (lc & 7)) * 8;  // read-side unswizzle
                const bf16x8 kh = *reinterpret_cast<const bf16x8*>(&Kh[kro + cp]);
                const bf16x8 kl = *reinterpret_cast<const bf16x8*>(&Kl[kro + cp]);
                #pragma unroll
                for (int sub = 0; sub < 2; ++sub) {
                    sacc[sub][kt] = MFMA16(kh, qh[sub][kb], sacc[sub][kt]);
                    sacc[sub][kt] = MFMA16(kh, ql[sub][kb], sacc[sub][kt]);
                    sacc[sub][kt] = MFMA16(kl, qh[sub][kb], sacc[sub][kt]);
                }
            }
        }
        __builtin_amdgcn_s_setprio(0);

        // ---- O += P(t-1) V(t-1) ----
        if (it > 0) {
            __builtin_amdgcn_s_setprio(1);
            #pragma unroll
            for (int ft = 0; ft < 8; ++ft) {
                const bf16x8 vh = *reinterpret_cast<const bf16x8*>(
                    &Vph[(ft * 16 + lc) * BK + vc]);
                const bf16x8 vl = *reinterpret_cast<const bf16x8*>(
                    &Vpl[(ft * 16 + lc) * BK + vc]);
                #pragma unroll
                for (int sub = 0; sub < 2; ++sub) {
                    oacc[sub][ft] = MFMA16(pah[sub], vh, oacc[sub][ft]);
                    oacc[sub][ft] = MFMA16(pal[sub], vh, oacc[sub][ft]);
                    oacc[sub][ft] = MFMA16(pah[sub], vl, oacc[sub][ft]);
                }
            }
            __builtin_amdgcn_s_setprio(0);
        }

        // barrier1: all waves' K(t)/V(t-1) ds_reads retired (lgkm only —
        // staged loads stay in flight).
        LGKM0();
        BARRIER();

        // deep prefetch: K(t+2) overwrites K(t)'s buffer (reads retired);
        // V(t+1) overwrites V(t-1)'s buffer (reads retired).
        if (it <= NT - 3) STAGE_K(cur, (it + 2) * BK);
        if (it <= NT - 2) STAGE_V(cur ^ 1, (it + 1) * BK);

        if ((jt & ~127) == i0) {            // diagonal mask
            #pragma unroll
            for (int sub = 0; sub < 2; ++sub) {
                const int gq = i0 + w * 32 + sub * 16 + lc;
                #pragma unroll
                for (int kt = 0; kt < 2; ++kt)
                    #pragma unroll
                    for (int r = 0; r < 4; ++r) {
                        const int gk = jt + kt * 16 + lq * 4 + r;
                        if (gk == gq) sacc[sub][kt][r] = -INFINITY;
                    }
            }
        }
        // ---- P = exp(S*SCALE): cvt_pk split; b64 write, b128 read to regs
        #pragma unroll
        for (int sub = 0; sub < 2; ++sub) {
            #pragma unroll
            for (int kt = 0; kt < 2; ++kt) {
                unsigned wh[2], wl[2];
                #pragma unroll
                for (int rr = 0; rr < 2; ++rr) {
                    const float p0 = __expf(sacc[sub][kt][rr * 2 + 0] * SCALE);
                    const float p1 = __expf(sacc[sub][kt][rr * 2 + 1] * SCALE);
                    lrow[sub] += p0;
                    lrow[sub] += p1;
                    unsigned hpk;
                    asm("v_cvt_pk_bf16_f32 %0, %1, %2"
                        : "=v"(hpk) : "v"(p0), "v"(p1));
                    wh[rr] = hpk;
                    const float h0 = __uint_as_float(hpk << 16);
                    const float h1 = __uint_as_float(hpk & 0xFFFF0000u);
                    unsigned lpk;
                    asm("v_cvt_pk_bf16_f32 %0, %1, %2"
                        : "=v"(lpk) : "v"(p0 - h0), "v"(p1 - h1));
                    wl[rr] = lpk;
                }
                const int eo = lc * PSTR + kt * 16 + lq * 4;
                *reinterpret_cast<uint2*>(&Pwh[eo]) = make_uint2(wh[0], wh[1]);
                *reinterpret_cast<uint2*>(&Pwl[eo]) = make_uint2(wl[0], wl[1]);
            }
            pah[sub] = *reinterpret_cast<const bf16x8*>(&Pwh[lc * PSTR + lq * 8]);
            pal[sub] = *reinterpret_cast<const bf16x8*>(&Pwl[lc * PSTR + lq * 8]);
        }

        // barrier2: K(t+1), V(t) landed block-wide; K(t+2)/V(t+1) (the 8
        // newest loads) stay in flight across the barrier.
        if (it <= NT - 3)      { VMW(8); }
        else if (it == NT - 2) { VMW(4); }
        else                   { VMW(0); }
        BARRIER();
    }
    // ---- epilogue: PV(NT-1); V(NT-1) in buffer (NT-1)&1 ----
    {
        const ushort_t* Vh = Vhs[(NT - 1) & 1];
        const ushort_t* Vl = Vls[(NT - 1) & 1];
        #pragma unroll
        for (int ft = 0; ft < 8; ++ft) {
            const bf16x8 vh = *reinterpret_cast<const bf16x8*>(
                &Vh[(ft * 16 + lc) * BK + vc]);
            const bf16x8 vl = *reinterpret_cast<const bf16x8*>(
                &Vl[(ft * 16 + lc) * BK + vc]);
            #pragma unroll
            for (int sub = 0; sub < 2; ++sub) {
                oacc[sub][ft] = MFMA16(pah[sub], vh, oacc[sub][ft]);
                oacc[sub][ft] = MFMA16(pal[sub], vh, oacc[sub][ft]);
                oacc[sub][ft] = MFMA16(pah[sub], vl, oacc[sub][ft]);
            }
        }
    }
#undef STAGE_K
#undef STAGE_V
#undef LGKM0
#undef VMW
#undef BARRIER

    // denom: lane holds partial for query=lc over keys lq*4+r; reduce over lq.
    #pragma unroll
    for (int sub = 0; sub < 2; ++sub) {
        float ps = lrow[sub];
        ps += __shfl_xor(ps, 16, 64);
        ps += __shfl_xor(ps, 32, 64);
        lrow[sub] = ps;
    }
    #pragma unroll
    for (int sub = 0; sub < 2; ++sub) {
        #pragma unroll
        for (int r = 0; r < 4; ++r) {
            const int row = i0 + w * 32 + sub * 16 + lq * 4 + r;
            float* po = Opart + ((size_t)s * NN + row) * DD;
            #pragma unroll
            for (int ft = 0; ft < 8; ++ft) po[ft * 16 + lc] = oacc[sub][ft][r];
        }
        if (l < 16)
            lpart[s * NN + i0 + w * 32 + sub * 16 + l] = lrow[sub];
    }
}

// ------- merge slices + skip, emit H/Hhi/SQ; FUSED mat1 (M1 = H @ W1) -----
// Phase 1: 32 threads/node, 4 features each.  h quads also go to an 8x132
// LDS tile.  Phase 2 (after one barrier): 2 halves x 128 cols, 4 rows each;
// c-sequential fmaf chain == old mat1 -> bit-identical M1.
__global__ __launch_bounds__(256)
void attn_merge_kernel(const float* __restrict__ Opart, const float* __restrict__ lpart,
                       const float* __restrict__ HS, float* __restrict__ H,
                       ushort_t* __restrict__ Hhi, float* __restrict__ SQ,
                       const float* __restrict__ W1, float* __restrict__ M1)
{
    __shared__ float xs[8][132];
    const int t = threadIdx.x;
    const int gid = blockIdx.x * 256 + t;
    const int i = gid >> 5;             // node
    const int f = (gid & 31) * 4;       // feature quad
    float ls = 0.f;
    float4 o = {0.f, 0.f, 0.f, 0.f};
    #pragma unroll
    for (int s = 0; s < ANS; ++s) {
        ls += lpart[s * NN + i];
        const float4 ov = *reinterpret_cast<const float4*>(
            Opart + ((size_t)s * NN + i) * DD + f);
        o.x += ov.x; o.y += ov.y; o.z += ov.z; o.w += ov.w;
    }
    const float4 hs = *reinterpret_cast<const float4*>(HS + i * DD + f);
    const float inv = 1.f / ls;
    float4 h;
    h.x = o.x * inv + hs.x; h.y = o.y * inv + hs.y;
    h.z = o.z * inv + hs.z; h.w = o.w * inv + hs.w;
    *reinterpret_cast<float4*>(H + i * DD + f) = h;
    *reinterpret_cast<float4*>(&xs[t >> 5][f]) = h;
    ushort_t hb[4] = {f2b(h.x), f2b(h.y), f2b(h.z), f2b(h.w)};
    *reinterpret_cast<uint2*>(Hhi + i * DD + f) = *reinterpret_cast<const uint2*>(hb);
    float sq = h.x * h.x + h.y * h.y + h.z * h.z + h.w * h.w;
    sq += __shfl_xor(sq, 1, 64);
    sq += __shfl_xor(sq, 2, 64);
    sq += __shfl_xor(sq, 4, 64);
    sq += __shfl_xor(sq, 8, 64);
    sq += __shfl_xor(sq, 16, 64);       // xor<32 stays within the 32-lane node group
    if ((t & 31) == 0) SQ[i] = sq;

    __syncthreads();                    // xs tile complete
    // ---- mat1 phase: rows = this block's 8 nodes ----
    const int col = t & 127, half = t >> 7;   // half 0: rows 0-3; half 1: rows 4-7
    float a[4] = {0.f, 0.f, 0.f, 0.f};
    #pragma unroll 4
    for (int c = 0; c < DD; ++c) {
        const float wv = W1[c * DD + col];
        #pragma unroll
        for (int r = 0; r < 4; ++r)
            a[r] = fmaf(xs[half * 4 + r][c], wv, a[r]);
    }
    const int n0 = blockIdx.x * 8 + half * 4;
    #pragma unroll
    for (int r = 0; r < 4; ++r)
        M1[(n0 + r) * DD + col] = a[r];
}

// ---------------- kNN: swapped-operand MFMA, register top-NL (u32) ---------
constexpr int KNSL = 16;                // key slices (512 keys each)
constexpr int KSL  = NN / KNSL;         // 512

__global__ __launch_bounds__(256, 4)
void knn_kernel(const ushort_t* __restrict__ Hhi, const float* __restrict__ SQg,
                unsigned* __restrict__ candV)
{
    __shared__ __align__(16) ushort_t Khi[64 * KSTR];
    __shared__ __align__(16) float sqs[64];

    const int t  = threadIdx.x;
    const int w  = t >> 6, l = t & 63;
    const int lc = l & 15, lq = l >> 4;
    const int b  = blockIdx.x;
    const int s  = b >> 6;              // slice 0..15
    const int qb = b & 63;
    const int i0 = qb * 128;
    const int k0 = s * KSL;

    const int kr = t >> 4, kc2 = t & 15;   // staging coords (4 chunks of 16 rows)

    const int gq0 = i0 + w * 32 + lc;          // sub=0 query
    const int gq1 = gq0 + 16;                  // sub=1 query
    const float sqi0 = SQg[gq0];
    const float sqi1 = SQg[gq1];

    bf16x8 qf[2][4];                    // B operand: B[n=query=lc][k=lq*8+j]
    #pragma unroll
    for (int sub = 0; sub < 2; ++sub) {
        const int row = i0 + w * 32 + sub * 16 + lc;
        #pragma unroll
        for (int kb = 0; kb < 4; ++kb)
            qf[sub][kb] = *reinterpret_cast<const bf16x8*>(Hhi + row * DD + kb * 32 + lq * 8);
    }

    unsigned lists[2][NL];              // ascending: [0] best .. [NL-1] worst
    #pragma unroll
    for (int sub = 0; sub < 2; ++sub)
        #pragma unroll
        for (int p = 0; p < NL; ++p) lists[sub][p] = 0xFFFFFFFFu;

    // prefetch tile 0 (knn has VGPR headroom, no spill at 4 waves/EU)
    uint4 pk[4]; float psq;
    #pragma unroll
    for (int p = 0; p < 4; ++p)
        pk[p] = *reinterpret_cast<const uint4*>(Hhi + (k0 + kr + p * 16) * DD + kc2 * 8);
    psq = (t < 64) ? SQg[k0 + t] : 0.f;

    const f32x4 zz = {0.f, 0.f, 0.f, 0.f};
    for (int jt0 = 0; jt0 < KSL; jt0 += 64) {
        const int jt = k0 + jt0;
        __syncthreads();                 // prev K-frag reads done
        #pragma unroll
        for (int p = 0; p < 4; ++p)
            *reinterpret_cast<uint4*>(&Khi[(kr + p * 16) * KSTR + kc2 * 8]) = pk[p];
        if (t < 64) sqs[t] = psq;
        __syncthreads();
        if (jt0 + 64 < KSL) {            // prefetch next during compute
            const int jn = jt + 64;
            #pragma unroll
            for (int p = 0; p < 4; ++p)
                pk[p] = *reinterpret_cast<const uint4*>(Hhi + (jn + kr + p * 16) * DD + kc2 * 8);
            psq = (t < 64) ? SQg[jn + t] : 0.f;
        }

        f32x4 acc[2][4];                 // [sub][kt]
        #pragma unroll
        for (int sub = 0; sub < 2; ++sub)
            #pragma unroll
            for (int kt = 0; kt < 4; ++kt) acc[sub][kt] = zz;
        #pragma unroll
        for (int kt = 0; kt < 4; ++kt) {
            #pragma unroll
            for (int kb = 0; kb < 4; ++kb) {
                const bf16x8 kf = *reinterpret_cast<const bf16x8*>(
                    &Khi[(kt * 16 + lc) * KSTR + kb * 32 + lq * 8]);
                acc[0][kt] = MFMA16(kf, qf[0][kb], acc[0][kt]);   // A=key, B=query
                acc[1][kt] = MFMA16(kf, qf[1][kb], acc[1][kt]);
            }
        }

        const bool ovl = ((jt & ~127) == i0);
        #pragma unroll
        for (int kt = 0; kt < 4; ++kt) {
            const float4 sq4 = *reinterpret_cast<const float4*>(&sqs[kt * 16 + lq * 4]);
            const float sqj[4] = {sq4.x, sq4.y, sq4.z, sq4.w};
            #pragma unroll
            for (int r = 0; r < 4; ++r) {
                const int gk = jt + kt * 16 + lq * 4 + r;
                float d0 = fmaf(-2.f, acc[0][kt][r], sqi0 + sqj[r]);
                float d1 = fmaf(-2.f, acc[1][kt][r], sqi1 + sqj[r]);
                if (ovl) {
                    if (gk == gq0) d0 = INFINITY;
                    if (gk == gq1) d1 = INFINITY;
                }
                const unsigned u0 = (__float_as_uint(d0) & 0xFFFFE000u) | (unsigned)gk;
                const unsigned u1 = (__float_as_uint(d1) & 0xFFFFE000u) | (unsigned)gk;
                ins_asc<NL>(lists[0], u0);
                ins_asc<NL>(lists[1], u1);
            }
        }
    }

    // ---- in-kernel lq-merge: Khi is dead, reuse as scratch ----
    __syncthreads();                     // all waves done with Khi MFMA reads
    unsigned* msw = reinterpret_cast<unsigned*>(Khi) + w * (16 * 4 * NL);
    #pragma unroll
    for (int sub = 0; sub < 2; ++sub) {
        #pragma unroll
        for (int p = 0; p < NL; ++p)
            msw[lc * (4 * NL) + lq * NL + p] = lists[sub][p];
        __syncthreads();
        if (lq == 0) {                   // 16 lanes/wave: one query each
            unsigned bk[NL];             // seed with lane-0 list (ascending)
            #pragma unroll
            for (int p = 0; p < NL; ++p) bk[p] = msw[lc * (4 * NL) + p];
            #pragma unroll
            for (int o = 1; o < 4; ++o)
                #pragma unroll
                for (int e = 0; e < NL; ++e)
                    ins_asc<NL>(bk, msw[lc * (4 * NL) + o * NL + e]);
            const int node = i0 + w * 32 + sub * 16 + lc;
            #pragma unroll
            for (int p = 0; p < NL; ++p)
                candV[((size_t)s * NL + p) * NN + node] = bk[p];
        }
        __syncthreads();
    }
}

// ------- final merge: 16 slice lists -> top-12 candidates per node ---------
__global__ __launch_bounds__(64)
void knn_merge_kernel(const unsigned* __restrict__ candV, int* __restrict__ CAND)
{
    const int q = blockIdx.x * 64 + threadIdx.x;
    unsigned bk[NCAND];
    #pragma unroll
    for (int p = 0; p < NCAND; ++p) bk[p] = 0xFFFFFFFFu;
    for (int s = 0; s < KNSL; ++s)
        #pragma unroll
        for (int e = 0; e < NL; ++e)
            ins_asc<NCAND>(bk, candV[((size_t)s * NL + e) * NN + q]);
    #pragma unroll
    for (int p = 0; p < NCAND; ++p)
        CAND[q * NCAND + p] = (int)(bk[p] & 8191u);
}

// ---------------- exact fp32 re-rank of candidates -> IDX ----------------
__global__ __launch_bounds__(256)
void rerank_kernel(const float* __restrict__ H, const float* __restrict__ SQ,
                   const int* __restrict__ CAND, int* __restrict__ IDX)
{
    const int t = threadIdx.x;
    const int w = t >> 6, l = t & 63;
    const int node = blockIdx.x * 4 + w;
    const float h0 = H[node * DD + l];
    const float h1 = H[node * DD + 64 + l];
    float dk[NCAND]; int di[NCAND];
    #pragma unroll
    for (int c = 0; c < NCAND; ++c) {
        const int j = CAND[node * NCAND + c];
        float p = h0 * H[j * DD + l] + h1 * H[j * DD + 64 + l];
        p += __shfl_xor(p, 1, 64);
        p += __shfl_xor(p, 2, 64);
        p += __shfl_xor(p, 4, 64);
        p += __shfl_xor(p, 8, 64);
        p += __shfl_xor(p, 16, 64);
        p += __shfl_xor(p, 32, 64);
        dk[c] = SQ[j] - 2.f * p;
        di[c] = j;
    }
    if (l == 0) {
        #pragma unroll
        for (int s = 0; s < KNB; ++s) {
            int best = s;
            #pragma unroll
            for (int c = s + 1; c < NCAND; ++c) {
                const bool lt = (dk[c] < dk[best]) ||
                                (dk[c] == dk[best] && di[c] < di[best]);
                if (lt) best = c;
            }
            const float tk = dk[s]; dk[s] = dk[best]; dk[best] = tk;
            const int   ti = di[s]; di[s] = di[best]; di[best] = ti;
            IDX[node * KNB + s] = di[s];
        }
    }
}

// -------- fused: H1 = relu((sum_nbr M1 + M1)/8 + b1); M2 = H1.W2 ----------
// One node per wave; lane l handles features l and l+64.  shfl_xor reduce
// in order 32,16,8,4,2,1 replays the old LDS tree pairing -> bit-identical.
__global__ __launch_bounds__(256)
void g1m2_kernel(const float* __restrict__ M1, const int* __restrict__ IDX,
                 const float* __restrict__ b1, const float* __restrict__ W2,
                 float* __restrict__ M2)
{
    const int t = threadIdx.x;
    const int w = t >> 6, l = t & 63;
    const int i = blockIdx.x * 4 + w;
    float s0 = M1[i * DD + l];
    float s1 = M1[i * DD + 64 + l];
    #pragma unroll
    for (int p = 0; p < KNB; ++p) {
        const int j = IDX[i * KNB + p];
        s0 += M1[j * DD + l];
        s1 += M1[j * DD + 64 + l];
    }
    const float g0 = fmaxf(s0 * 0.125f + b1[l], 0.f);
    const float g1 = fmaxf(s1 * 0.125f + b1[64 + l], 0.f);
    float r = g0 * W2[l] + g1 * W2[64 + l];   // == old red[l] after s2=64 step
    r += __shfl_xor(r, 32, 64);
    r += __shfl_xor(r, 16, 64);
    r += __shfl_xor(r, 8, 64);
    r += __shfl_xor(r, 4, 64);
    r += __shfl_xor(r, 2, 64);
    r += __shfl_xor(r, 1, 64);
    if (l == 0) M2[i] = r;
}

// ---------------- out = (sum_nbr M2 + M2)/8 + b2 ----------------
__global__ __launch_bounds__(256)
void out_kernel(const float* __restrict__ M2, const int* __restrict__ IDX,
                const float* __restrict__ b2, float* __restrict__ out)
{
    const int i = blockIdx.x * 256 + threadIdx.x;
    if (i < NN) {
        float s = M2[i];
        #pragma unroll
        for (int p = 0; p < KNB; ++p) s += M2[IDX[i * KNB + p]];
        out[i] = s * 0.125f + b2[0];
    }
}

// ---------------------------------------------------------------------------
extern "C" void kernel_launch(void* const* d_in, const int* in_sizes, int n_in,
                              void* d_out, int out_size, void* d_ws, size_t ws_size,
                              hipStream_t stream)
{
    const float* x   = (const float*)d_in[0];
    const float* Wq  = (const float*)d_in[1];
    const float* bq  = (const float*)d_in[2];
    const float* Wk  = (const float*)d_in[3];
    const float* bk  = (const float*)d_in[4];
    const float* Wv  = (const float*)d_in[5];
    const float* bv  = (const float*)d_in[6];
    const float* Wsk = (const float*)d_in[7];
    const float* bsk = (const float*)d_in[8];
    const float* W1  = (const float*)d_in[9];
    const float* b1  = (const float*)d_in[10];
    const float* W2  = (const float*)d_in[11];
    const float* b2  = (const float*)d_in[12];

    constexpr size_t MB = 1024 * 1024;
    char* W = (char*)d_ws;
    // persistent: [0,8) Q/K splits, [8,12) VT splits, [12,16) HS (->H in place)
    ushort_t* Qhi  = (ushort_t*)(W + 0 * MB);
    ushort_t* Qlo  = (ushort_t*)(W + 2 * MB);
    ushort_t* Khi  = (ushort_t*)(W + 4 * MB);
    ushort_t* Klo  = (ushort_t*)(W + 6 * MB);
    ushort_t* VThi = (ushort_t*)(W + 8 * MB);
    ushort_t* VTlo = (ushort_t*)(W + 10 * MB);
    float*    HS   = (float*)(W + 12 * MB);
    float*    H    = HS;                                   // in-place merge
    ushort_t* Hhi  = Qhi;            // Q dead after attn; Hhi written by merge
    // small: [16,17)
    float* lpart = (float*)(W + 16 * MB);                  // 256KB
    float* SQ    = (float*)(W + 16 * MB + 256 * 1024);     // 32KB
    float* M2    = SQ + NN;                                // 32KB
    int*   IDX   = (int*)(M2 + NN);                        // 224KB
    // union: [17,49):
    //   Opart [17,49)   read by fused attn_merge (M1 must NOT overlap!)
    //   candV [17,22.25) written by knn, dead after knn_merge (5.25MB)
    //   CAND  [23,23.4) written by knn_merge, dead after rerank
    // M1 at [49,53): outside Opart (fused merge writes M1 while reading
    // Opart).  ws >= 81MB confirmed (r19 big path ran).
    float*    Opart = (float*)(W + 17 * MB);
    unsigned* candV = (unsigned*)(W + 17 * MB);
    int*      CAND  = (int*)(W + 23 * MB);
    float*    M1    = (float*)(W + 49 * MB);

    proj_kernel<<<NN / PR, 128, 0, stream>>>(x, Wq, bq, Wk, bk, Wv, bv, Wsk, bsk,
                                             Qhi, Qlo, Khi, Klo, VThi, VTlo, HS);
    attn_kernel<<<ANS * 64, 256, 0, stream>>>(Qhi, Qlo, Khi, Klo, VThi, VTlo,
                                              Opart, lpart);
    attn_merge_kernel<<<(NN * 32) / 256, 256, 0, stream>>>(Opart, lpart, HS, H,
                                                           Hhi, SQ, W1, M1);
    knn_kernel<<<KNSL * 64, 256, 0, stream>>>(Hhi, SQ, candV);
    knn_merge_kernel<<<NN / 64, 64, 0, stream>>>(candV, CAND);
    rerank_kernel<<<NN / 4, 256, 0, stream>>>(H, SQ, CAND, IDX);
    g1m2_kernel<<<NN / 4, 256, 0, stream>>>(M1, IDX, b1, W2, M2);
    out_kernel<<<NN / 256, 256, 0, stream>>>(M2, IDX, b2, (float*)d_out);
}

// Round 13
// 309.139 us; speedup vs baseline: 1.0784x; 1.0353x over previous
//
#include <hip/hip_runtime.h>
#include <cmath>

// ---------------------------------------------------------------------------
// GraphTransformer on MI355X.  N=8192, D=128, k=7, OUT=1.
// Attention: split-bf16 (hi/lo) MFMA flash, fixed max (logits bounded).
//   FROZEN config (every deviation regressed):
//   - QK^T 3-term split (round-10: plain bf16 QK flips kNN neighbors)
//   - PSTR=40 row stride for P (round-12)
//   - swapped QK^T (A=K,B=Q) + packed-b64 P round-trip (r15)
//   - branchless med3 top-K insert in kNN (r16)
//   - cross-tile PV pipeline (r17); cvt_pk exp pack (r20)
//   - ANS=8 / grid 512 (r19 ERRATum: finer key-split didn't raise occupancy;
//     2 blocks/CU is a hard cap)
//   - T4 counted-vmcnt pipeline (r21: attn 93.6us best)
//   - g1m2 wave-per-node + mat1 fused into attn_merge (r23: -10us)
//   - vt fused into proj (r24: -2.3us; STRUCTURE moves the tail)
// Round-25 (this round): port attn's proven staging to knn_kernel -- it still
// used the old register-prefetch + ds_write staging (the structure attn
// abandoned in r13).  Now: double-buffered LINEAR K tile via global_load_lds
// (XOR-swizzled source chunk^=(row&7), read-side unswizzle -- identical to
// attn's K), dbuf sqs, and {lgkmcnt(0)+barrier | stage(t+1) | distance phase
// (covers load flight) | vmcnt(0)+barrier}.  MFMA operands bit-identical ->
// candV/CAND/IDX unchanged.  LDS 17.7->32.5KB (still 4 blocks/CU), VGPR -16.
// kNN: swapped-operand bf16 MFMA, per-lane register top-10 (u32-packed),
// in-kernel lq-merge -> candV, parallel final merge, exact fp32 re-rank.
// ---------------------------------------------------------------------------

typedef unsigned short ushort_t;

constexpr int   NN    = 8192;
constexpr int   DD    = 128;
constexpr int   KNB   = 7;
constexpr int   NL    = 10;              // per-lane kept candidates (knn)
constexpr int   NCAND = 12;              // merged candidates per node
constexpr float SCALE = 0.088388347648318447f;   // 1/sqrt(128)

using bf16x8 = __attribute__((ext_vector_type(8))) short;   // 8 bf16 = 4 VGPR
using f32x4  = __attribute__((ext_vector_type(4))) float;   // mfma acc

#define MFMA16(a, b, c) __builtin_amdgcn_mfma_f32_16x16x32_bf16((a), (b), (c), 0, 0, 0)

#define LGKM0() asm volatile("s_waitcnt lgkmcnt(0)" ::: "memory")
#define VMW(n)  asm volatile("s_waitcnt vmcnt(" #n ")" ::: "memory")
#define BARRIER() do { __builtin_amdgcn_s_barrier(); \
                       __builtin_amdgcn_sched_barrier(0); } while (0)

__device__ __forceinline__ ushort_t f2b(float f) {
    union { float f; unsigned int u; } v; v.f = f;
    return (ushort_t)((v.u + 0x8000u) >> 16);
}
__device__ __forceinline__ float b2f(ushort_t h) {
    union { unsigned int u; float f; } v; v.u = ((unsigned int)h) << 16;
    return v.f;
}

// direct global->LDS copy, 16B per lane; LDS dest is wave-uniform base + lane*16
__device__ __forceinline__ void gload16(const void* g, void* l) {
    __builtin_amdgcn_global_load_lds(
        (const __attribute__((address_space(1))) unsigned int*)g,
        (__attribute__((address_space(3))) unsigned int*)l, 16, 0, 0);
}

__device__ __forceinline__ unsigned umin_(unsigned a, unsigned b) { return a < b ? a : b; }
__device__ __forceinline__ unsigned umax_(unsigned a, unsigned b) { return a > b ? a : b; }

// Branchless top-K keep-smallest insert into ASCENDING sorted list
// (a[0] best .. a[K-1] worst).  med3 identity: since a[p-1] <= a[p],
//   new a[p] = med3(x, a[p-1], a[p]) = min(max(x, a[p-1]), a[p]).
// Kept SET identical to a guarded strict-less shift insert.  2 VALU
// ops/element, no branch, no divergence.
template<int K>
__device__ __forceinline__ void ins_asc(unsigned* a, unsigned x)
{
    #pragma unroll
    for (int p = K - 1; p >= 1; --p)
        a[p] = umin_(umax_(x, a[p - 1]), a[p]);
    a[0] = umin_(a[0], x);
}

// ----- projections: Q,K (split bf16), skip (f32), V DIRECT to VT splits ----
// 8 rows/block.  Thread t = feature t; its 8 per-node V values form one
// contiguous 16B chunk of VT[f][n] (vt_kernel fused away, bit-identical).
constexpr int PR = 8;
__global__ __launch_bounds__(128)
void proj_kernel(const float* __restrict__ x,
                 const float* __restrict__ Wq, const float* __restrict__ bq,
                 const float* __restrict__ Wk, const float* __restrict__ bk,
                 const float* __restrict__ Wv, const float* __restrict__ bv,
                 const float* __restrict__ Ws, const float* __restrict__ bs,
                 ushort_t* __restrict__ Qhi, ushort_t* __restrict__ Qlo,
                 ushort_t* __restrict__ Khi, ushort_t* __restrict__ Klo,
                 ushort_t* __restrict__ VThi, ushort_t* __restrict__ VTlo,
                 float* __restrict__ HS)
{
    __shared__ float xs[PR][DD];
    const int i0 = blockIdx.x * PR, t = threadIdx.x;
    #pragma unroll
    for (int r = 0; r < PR; ++r) xs[r][t] = x[(i0 + r) * DD + t];
    __syncthreads();
    float aq[PR], ak[PR], av[PR], ah[PR];
    #pragma unroll
    for (int r = 0; r < PR; ++r) { aq[r] = 0.f; ak[r] = 0.f; av[r] = 0.f; ah[r] = 0.f; }
    #pragma unroll 4
    for (int c = 0; c < DD; ++c) {
        const float wq = Wq[c * DD + t], wk = Wk[c * DD + t];
        const float wv = Wv[c * DD + t], ws = Ws[c * DD + t];
        #pragma unroll
        for (int r = 0; r < PR; ++r) {
            const float xv = xs[r][c];
            aq[r] = fmaf(xv, wq, aq[r]); ak[r] = fmaf(xv, wk, ak[r]);
            av[r] = fmaf(xv, wv, av[r]); ah[r] = fmaf(xv, ws, ah[r]);
        }
    }
    ushort_t vh8[PR], vl8[PR];
    #pragma unroll
    for (int r = 0; r < PR; ++r) {
        const int o = (i0 + r) * DD + t;
        const float q = aq[r] + bq[t];
        const float k = ak[r] + bk[t];
        const ushort_t qh = f2b(q); Qhi[o] = qh; Qlo[o] = f2b(q - b2f(qh));
        const ushort_t kh = f2b(k); Khi[o] = kh; Klo[o] = f2b(k - b2f(kh));
        const float v = av[r] + bv[t];
        const ushort_t vh = f2b(v);
        vh8[r] = vh; vl8[r] = f2b(v - b2f(vh));
        HS[o] = ah[r] + bs[t];
    }
    *reinterpret_cast<uint4*>(VThi + (size_t)t * NN + i0) =
        *reinterpret_cast<const uint4*>(vh8);
    *reinterpret_cast<uint4*>(VTlo + (size_t)t * NN + i0) =
        *reinterpret_cast<const uint4*>(vl8);
}

// ---------------- split-bf16 MFMA flash attention, fixed max ---------------
// 256-thread blocks (4 waves x 32 queries = 128 queries/block), grid 512.
// K/V DOUBLE-buffered via global_load_lds; K staged 2 windows ahead, V 1.
// Counted-vmcnt barriers (never 0 mid-loop); 2 blocks/CU.
constexpr int ANS  = 8;                 // key slices
constexpr int AKS  = NN / ANS;          // 1024 keys per slice
constexpr int BK   = 32;                // keys per tile
constexpr int PSTR = 40;                // P row stride (frozen)

__global__ __launch_bounds__(256, 2)
void attn_kernel(const ushort_t* __restrict__ Qhi, const ushort_t* __restrict__ Qlo,
                 const ushort_t* __restrict__ Khg, const ushort_t* __restrict__ Klg,
                 const ushort_t* __restrict__ Vhg, const ushort_t* __restrict__ Vlg,
                 float* __restrict__ Opart, float* __restrict__ lpart)
{
    // K tiles: 32 rows x 128 bf16, linear rows; chunk XOR-swizzled (c^row&7)
    //          on global source + read side -> conflict-free ds_read_b128.
    // V tiles: 128 rows x 32 bf16, chunk XOR-swizzled (c^(row>>1)&3).
    // P strip: 16 rows x PSTR per wave (row = query lc; sub0/sub1 reuse).
    // Buffer map: K(t) in K?s[t&1], V(t) in V?s[t&1].
    __shared__ __align__(16) ushort_t Khs[2][BK * DD];
    __shared__ __align__(16) ushort_t Kls[2][BK * DD];
    __shared__ __align__(16) ushort_t Vhs[2][DD * BK];
    __shared__ __align__(16) ushort_t Vls[2][DD * BK];
    __shared__ __align__(16) ushort_t Phs[4][16 * PSTR];
    __shared__ __align__(16) ushort_t Pls[4][16 * PSTR];

    const int t  = threadIdx.x;
    const int w  = t >> 6, l = t & 63;
    const int lc = l & 15, lq = l >> 4;
    const int b  = blockIdx.x;
    const int s  = b >> 6;              // slice 0..7
    const int qb = b & 63;
    const int i0 = qb * 128;
    const int k0 = s * AKS;
    ushort_t* Pwh = Phs[w];
    ushort_t* Pwl = Pls[w];

    // staging coordinates (per thread, loop-invariant).
    const int lrK = w * 4 + (l >> 4);
    const int kchunk = ((l & 15) ^ (lrK & 7)) * 8;
    const ushort_t* gKh = Khg + (size_t)(k0 + lrK) * DD + kchunk;
    const ushort_t* gKl = Klg + (size_t)(k0 + lrK) * DD + kchunk;
    const int lrV = w * 16 + (l >> 2);
    const int vchunk = ((l & 3) ^ ((l >> 3) & 3)) * 8;
    const ushort_t* gVh = Vhg + (size_t)lrV * NN + k0 + vchunk;
    const ushort_t* gVl = Vlg + (size_t)lrV * NN + k0 + vchunk;

#define STAGE_K(buf, koff) do {                                              \
    gload16(gKh + (size_t)(koff) * DD,        &Khs[buf][(w * 4) * DD]);      \
    gload16(gKh + (size_t)((koff) + 16) * DD, &Khs[buf][(16 + w * 4) * DD]); \
    gload16(gKl + (size_t)(koff) * DD,        &Kls[buf][(w * 4) * DD]);      \
    gload16(gKl + (size_t)((koff) + 16) * DD, &Kls[buf][(16 + w * 4) * DD]); \
  } while (0)
#define STAGE_V(buf, koff) do {                                              \
    gload16(gVh + (koff),                     &Vhs[buf][(w * 16) * BK]);     \
    gload16(gVh + (size_t)64 * NN + (koff),   &Vhs[buf][(64 + w * 16) * BK]);\
    gload16(gVl + (koff),                     &Vls[buf][(w * 16) * BK]);     \
    gload16(gVl + (size_t)64 * NN + (koff),   &Vls[buf][(64 + w * 16) * BK]);\
  } while (0)

    bf16x8 qh[2][4], ql[2][4];
    #pragma unroll
    for (int sub = 0; sub < 2; ++sub) {
        const int row = i0 + w * 32 + sub * 16 + lc;
        #pragma unroll
        for (int kb = 0; kb < 4; ++kb) {
            qh[sub][kb] = *reinterpret_cast<const bf16x8*>(Qhi + row * DD + kb * 32 + lq * 8);
            ql[sub][kb] = *reinterpret_cast<const bf16x8*>(Qlo + row * DD + kb * 32 + lq * 8);
        }
    }

    const f32x4 zz = {0.f, 0.f, 0.f, 0.f};
    f32x4 oacc[2][8];
    #pragma unroll
    for (int sub = 0; sub < 2; ++sub)
        #pragma unroll
        for (int ft = 0; ft < 8; ++ft) oacc[sub][ft] = zz;
    float lrow[2] = {0.f, 0.f};         // per-lane partial denom, query = lc

    bf16x8 pah[2] = {}, pal[2] = {};    // carried P fragments (tile t-1)
    const int vc = (lq ^ ((lc >> 1) & 3)) * 8;   // V read-side unswizzle

    // prologue: K(0), K(1), V(0) issued; wait K(0) (allow 8 newer in flight)
    STAGE_K(0, 0);
    STAGE_K(1, BK);
    STAGE_V(0, 0);
    VMW(8);
    BARRIER();

    constexpr int NT = AKS / BK;        // 32 tiles
    for (int it = 0; it < NT; ++it) {
        const int jt  = k0 + it * BK;
        const int cur = it & 1;
        const ushort_t* Kh = Khs[cur];
        const ushort_t* Kl = Kls[cur];
        const ushort_t* Vph = Vhs[cur ^ 1];   // V(t-1)
        const ushort_t* Vpl = Vls[cur ^ 1];

        // ---- S^T = K Q^T (swapped: A=K, B=Q; bit-identical products) ----
        f32x4 sacc[2][2];               // [sub][kt]
        #pragma unroll
        for (int sub = 0; sub < 2; ++sub)
            #pragma unroll
            for (int kt = 0; kt < 2; ++kt) sacc[sub][kt] = zz;
        __builtin_amdgcn_s_setprio(1);
        #pragma unroll
        for (int kt = 0; kt < 2; ++kt) {
            const int kro = (kt * 16 + lc) * DD;
            #pragma unroll
            for (int kb = 0; kb < 4; ++kb) {
                const int cp = ((kb * 4 + lq) ^ (lc & 7)) * 8;  // read-side unswizzle
                const bf16x8 kh = *reinterpret_cast<const bf16x8*>(&Kh[kro + cp]);
                const bf16x8 kl = *reinterpret_cast<const bf16x8*>(&Kl[kro + cp]);
                #pragma unroll
                for (int sub = 0; sub < 2; ++sub) {
                    sacc[sub][kt] = MFMA16(kh, qh[sub][kb], sacc[sub][kt]);
                    sacc[sub][kt] = MFMA16(kh, ql[sub][kb], sacc[sub][kt]);
                    sacc[sub][kt] = MFMA16(kl, qh[sub][kb], sacc[sub][kt]);
                }
            }
        }
        __builtin_amdgcn_s_setprio(0);

        // ---- O += P(t-1) V(t-1) ----
        if (it > 0) {
            __builtin_amdgcn_s_setprio(1);
            #pragma unroll
            for (int ft = 0; ft < 8; ++ft) {
                const bf16x8 vh = *reinterpret_cast<const bf16x8*>(
                    &Vph[(ft * 16 + lc) * BK + vc]);
                const bf16x8 vl = *reinterpret_cast<const bf16x8*>(
                    &Vpl[(ft * 16 + lc) * BK + vc]);
                #pragma unroll
                for (int sub = 0; sub < 2; ++sub) {
                    oacc[sub][ft] = MFMA16(pah[sub], vh, oacc[sub][ft]);
                    oacc[sub][ft] = MFMA16(pal[sub], vh, oacc[sub][ft]);
                    oacc[sub][ft] = MFMA16(pah[sub], vl, oacc[sub][ft]);
                }
            }
            __builtin_amdgcn_s_setprio(0);
        }

        // barrier1: all waves' K(t)/V(t-1) ds_reads retired (lgkm only —
        // staged loads stay in flight).
        LGKM0();
        BARRIER();

        // deep prefetch: K(t+2) overwrites K(t)'s buffer (reads retired);
        // V(t+1) overwrites V(t-1)'s buffer (reads retired).
        if (it <= NT - 3) STAGE_K(cur, (it + 2) * BK);
        if (it <= NT - 2) STAGE_V(cur ^ 1, (it + 1) * BK);

        if ((jt & ~127) == i0) {            // diagonal mask
            #pragma unroll
            for (int sub = 0; sub < 2; ++sub) {
                const int gq = i0 + w * 32 + sub * 16 + lc;
                #pragma unroll
                for (int kt = 0; kt < 2; ++kt)
                    #pragma unroll
                    for (int r = 0; r < 4; ++r) {
                        const int gk = jt + kt * 16 + lq * 4 + r;
                        if (gk == gq) sacc[sub][kt][r] = -INFINITY;
                    }
            }
        }
        // ---- P = exp(S*SCALE): cvt_pk split; b64 write, b128 read to regs
        #pragma unroll
        for (int sub = 0; sub < 2; ++sub) {
            #pragma unroll
            for (int kt = 0; kt < 2; ++kt) {
                unsigned wh[2], wl[2];
                #pragma unroll
                for (int rr = 0; rr < 2; ++rr) {
                    const float p0 = __expf(sacc[sub][kt][rr * 2 + 0] * SCALE);
                    const float p1 = __expf(sacc[sub][kt][rr * 2 + 1] * SCALE);
                    lrow[sub] += p0;
                    lrow[sub] += p1;
                    unsigned hpk;
                    asm("v_cvt_pk_bf16_f32 %0, %1, %2"
                        : "=v"(hpk) : "v"(p0), "v"(p1));
                    wh[rr] = hpk;
                    const float h0 = __uint_as_float(hpk << 16);
                    const float h1 = __uint_as_float(hpk & 0xFFFF0000u);
                    unsigned lpk;
                    asm("v_cvt_pk_bf16_f32 %0, %1, %2"
                        : "=v"(lpk) : "v"(p0 - h0), "v"(p1 - h1));
                    wl[rr] = lpk;
                }
                const int eo = lc * PSTR + kt * 16 + lq * 4;
                *reinterpret_cast<uint2*>(&Pwh[eo]) = make_uint2(wh[0], wh[1]);
                *reinterpret_cast<uint2*>(&Pwl[eo]) = make_uint2(wl[0], wl[1]);
            }
            pah[sub] = *reinterpret_cast<const bf16x8*>(&Pwh[lc * PSTR + lq * 8]);
            pal[sub] = *reinterpret_cast<const bf16x8*>(&Pwl[lc * PSTR + lq * 8]);
        }

        // barrier2: K(t+1), V(t) landed block-wide; K(t+2)/V(t+1) (the 8
        // newest loads) stay in flight across the barrier.
        if (it <= NT - 3)      { VMW(8); }
        else if (it == NT - 2) { VMW(4); }
        else                   { VMW(0); }
        BARRIER();
    }
    // ---- epilogue: PV(NT-1); V(NT-1) in buffer (NT-1)&1 ----
    {
        const ushort_t* Vh = Vhs[(NT - 1) & 1];
        const ushort_t* Vl = Vls[(NT - 1) & 1];
        #pragma unroll
        for (int ft = 0; ft < 8; ++ft) {
            const bf16x8 vh = *reinterpret_cast<const bf16x8*>(
                &Vh[(ft * 16 + lc) * BK + vc]);
            const bf16x8 vl = *reinterpret_cast<const bf16x8*>(
                &Vl[(ft * 16 + lc) * BK + vc]);
            #pragma unroll
            for (int sub = 0; sub < 2; ++sub) {
                oacc[sub][ft] = MFMA16(pah[sub], vh, oacc[sub][ft]);
                oacc[sub][ft] = MFMA16(pal[sub], vh, oacc[sub][ft]);
                oacc[sub][ft] = MFMA16(pah[sub], vl, oacc[sub][ft]);
            }
        }
    }
#undef STAGE_K
#undef STAGE_V

    // denom: lane holds partial for query=lc over keys lq*4+r; reduce over lq.
    #pragma unroll
    for (int sub = 0; sub < 2; ++sub) {
        float ps = lrow[sub];
        ps += __shfl_xor(ps, 16, 64);
        ps += __shfl_xor(ps, 32, 64);
        lrow[sub] = ps;
    }
    #pragma unroll
    for (int sub = 0; sub < 2; ++sub) {
        #pragma unroll
        for (int r = 0; r < 4; ++r) {
            const int row = i0 + w * 32 + sub * 16 + lq * 4 + r;
            float* po = Opart + ((size_t)s * NN + row) * DD;
            #pragma unroll
            for (int ft = 0; ft < 8; ++ft) po[ft * 16 + lc] = oacc[sub][ft][r];
        }
        if (l < 16)
            lpart[s * NN + i0 + w * 32 + sub * 16 + l] = lrow[sub];
    }
}

// ------- merge slices + skip, emit H/Hhi/SQ; FUSED mat1 (M1 = H @ W1) -----
// Phase 1: 32 threads/node, 4 features each.  h quads also go to an 8x132
// LDS tile.  Phase 2 (after one barrier): 2 halves x 128 cols, 4 rows each;
// c-sequential fmaf chain == old mat1 -> bit-identical M1.
__global__ __launch_bounds__(256)
void attn_merge_kernel(const float* __restrict__ Opart, const float* __restrict__ lpart,
                       const float* __restrict__ HS, float* __restrict__ H,
                       ushort_t* __restrict__ Hhi, float* __restrict__ SQ,
                       const float* __restrict__ W1, float* __restrict__ M1)
{
    __shared__ float xs[8][132];
    const int t = threadIdx.x;
    const int gid = blockIdx.x * 256 + t;
    const int i = gid >> 5;             // node
    const int f = (gid & 31) * 4;       // feature quad
    float ls = 0.f;
    float4 o = {0.f, 0.f, 0.f, 0.f};
    #pragma unroll
    for (int s = 0; s < ANS; ++s) {
        ls += lpart[s * NN + i];
        const float4 ov = *reinterpret_cast<const float4*>(
            Opart + ((size_t)s * NN + i) * DD + f);
        o.x += ov.x; o.y += ov.y; o.z += ov.z; o.w += ov.w;
    }
    const float4 hs = *reinterpret_cast<const float4*>(HS + i * DD + f);
    const float inv = 1.f / ls;
    float4 h;
    h.x = o.x * inv + hs.x; h.y = o.y * inv + hs.y;
    h.z = o.z * inv + hs.z; h.w = o.w * inv + hs.w;
    *reinterpret_cast<float4*>(H + i * DD + f) = h;
    *reinterpret_cast<float4*>(&xs[t >> 5][f]) = h;
    ushort_t hb[4] = {f2b(h.x), f2b(h.y), f2b(h.z), f2b(h.w)};
    *reinterpret_cast<uint2*>(Hhi + i * DD + f) = *reinterpret_cast<const uint2*>(hb);
    float sq = h.x * h.x + h.y * h.y + h.z * h.z + h.w * h.w;
    sq += __shfl_xor(sq, 1, 64);
    sq += __shfl_xor(sq, 2, 64);
    sq += __shfl_xor(sq, 4, 64);
    sq += __shfl_xor(sq, 8, 64);
    sq += __shfl_xor(sq, 16, 64);       // xor<32 stays within the 32-lane node group
    if ((t & 31) == 0) SQ[i] = sq;

    __syncthreads();                    // xs tile complete
    // ---- mat1 phase: rows = this block's 8 nodes ----
    const int col = t & 127, half = t >> 7;   // half 0: rows 0-3; half 1: rows 4-7
    float a[4] = {0.f, 0.f, 0.f, 0.f};
    #pragma unroll 4
    for (int c = 0; c < DD; ++c) {
        const float wv = W1[c * DD + col];
        #pragma unroll
        for (int r = 0; r < 4; ++r)
            a[r] = fmaf(xs[half * 4 + r][c], wv, a[r]);
    }
    const int n0 = blockIdx.x * 8 + half * 4;
    #pragma unroll
    for (int r = 0; r < 4; ++r)
        M1[(n0 + r) * DD + col] = a[r];
}

// ---------------- kNN: swapped-operand MFMA, register top-NL (u32) ---------
// K tiles: 64 rows x 128 bf16, LINEAR, double-buffered, staged by
// global_load_lds (source chunk XOR-swizzled c^(row&7); read-side unswizzle
// identical to attn's K).  Two-barrier scheme per tile; distance phase
// covers the staged loads' flight time.
constexpr int KNSL = 16;                // key slices (512 keys each)
constexpr int KSL  = NN / KNSL;         // 512

__global__ __launch_bounds__(256, 4)
void knn_kernel(const ushort_t* __restrict__ Hhi, const float* __restrict__ SQg,
                unsigned* __restrict__ candV)
{
    __shared__ __align__(16) ushort_t Khs[2][64 * DD];
    __shared__ __align__(16) float sqs[2][64];

    const int t  = threadIdx.x;
    const int w  = t >> 6, l = t & 63;
    const int lc = l & 15, lq = l >> 4;
    const int b  = blockIdx.x;
    const int s  = b >> 6;              // slice 0..15
    const int qb = b & 63;
    const int i0 = qb * 128;
    const int k0 = s * KSL;

    // staging: call p covers rows p*16 + w*4 + (l>>4); source chunk
    // (l&15)^(row&7) with row&7 invariant under +16.  Linear LDS dest.
    const int srow = w * 4 + (l >> 4);
    const int schunk = ((l & 15) ^ (srow & 7)) * 8;
    const ushort_t* gH = Hhi + (size_t)(k0 + srow) * DD + schunk;

#define KSTAGE(buf, koff) do {                                               \
    gload16(gH + (size_t)((koff) +  0) * DD, &Khs[buf][( 0 + w * 4) * DD]);  \
    gload16(gH + (size_t)((koff) + 16) * DD, &Khs[buf][(16 + w * 4) * DD]);  \
    gload16(gH + (size_t)((koff) + 32) * DD, &Khs[buf][(32 + w * 4) * DD]);  \
    gload16(gH + (size_t)((koff) + 48) * DD, &Khs[buf][(48 + w * 4) * DD]);  \
  } while (0)

    const int gq0 = i0 + w * 32 + lc;          // sub=0 query
    const int gq1 = gq0 + 16;                  // sub=1 query
    const float sqi0 = SQg[gq0];
    const float sqi1 = SQg[gq1];

    bf16x8 qf[2][4];                    // B operand: B[n=query=lc][k=lq*8+j]
    #pragma unroll
    for (int sub = 0; sub < 2; ++sub) {
        const int row = i0 + w * 32 + sub * 16 + lc;
        #pragma unroll
        for (int kb = 0; kb < 4; ++kb)
            qf[sub][kb] = *reinterpret_cast<const bf16x8*>(Hhi + row * DD + kb * 32 + lq * 8);
    }

    unsigned lists[2][NL];              // ascending: [0] best .. [NL-1] worst
    #pragma unroll
    for (int sub = 0; sub < 2; ++sub)
        #pragma unroll
        for (int p = 0; p < NL; ++p) lists[sub][p] = 0xFFFFFFFFu;

    // prologue: stage tile 0; prefetch sqs(0) to register
    KSTAGE(0, 0);
    float psq = (t < 64) ? SQg[k0 + t] : 0.f;
    VMW(0);
    BARRIER();

    const f32x4 zz = {0.f, 0.f, 0.f, 0.f};
    constexpr int KNT = KSL / 64;       // 8 tiles
    for (int ti = 0; ti < KNT; ++ti) {
        const int jt  = k0 + ti * 64;
        const int cur = ti & 1;

        // sqs(t) visible after barrier A below; prefetch sqs(t+1) register.
        if (t < 64) sqs[cur][t] = psq;
        if (ti + 1 < KNT) psq = (t < 64) ? SQg[jt + 64 + t] : 0.f;

        // ---- MFMA phase: reads Khs[cur] ----
        f32x4 acc[2][4];                 // [sub][kt]
        #pragma unroll
        for (int sub = 0; sub < 2; ++sub)
            #pragma unroll
            for (int kt = 0; kt < 4; ++kt) acc[sub][kt] = zz;
        #pragma unroll
        for (int kt = 0; kt < 4; ++kt) {
            const int kro = (kt * 16 + lc) * DD;
            #pragma unroll
            for (int kb = 0; kb < 4; ++kb) {
                const int cp = ((kb * 4 + lq) ^ (lc & 7)) * 8;  // unswizzle
                const bf16x8 kf = *reinterpret_cast<const bf16x8*>(&Khs[cur][kro + cp]);
                acc[0][kt] = MFMA16(kf, qf[0][kb], acc[0][kt]);   // A=key, B=query
                acc[1][kt] = MFMA16(kf, qf[1][kb], acc[1][kt]);
            }
        }

        // barrier A: K reads retired block-wide; sqs[cur] writes visible.
        LGKM0();
        BARRIER();

        // stage next tile into the other buffer; distance phase covers it.
        if (ti + 1 < KNT) KSTAGE(cur ^ 1, (ti + 1) * 64);

        const bool ovl = ((jt & ~127) == i0);
        #pragma unroll
        for (int kt = 0; kt < 4; ++kt) {
            const float4 sq4 = *reinterpret_cast<const float4*>(&sqs[cur][kt * 16 + lq * 4]);
            const float sqj[4] = {sq4.x, sq4.y, sq4.z, sq4.w};
            #pragma unroll
            for (int r = 0; r < 4; ++r) {
                const int gk = jt + kt * 16 + lq * 4 + r;
                float d0 = fmaf(-2.f, acc[0][kt][r], sqi0 + sqj[r]);
                float d1 = fmaf(-2.f, acc[1][kt][r], sqi1 + sqj[r]);
                if (ovl) {
                    if (gk == gq0) d0 = INFINITY;
                    if (gk == gq1) d1 = INFINITY;
                }
                const unsigned u0 = (__float_as_uint(d0) & 0xFFFFE000u) | (unsigned)gk;
                const unsigned u1 = (__float_as_uint(d1) & 0xFFFFE000u) | (unsigned)gk;
                ins_asc<NL>(lists[0], u0);
                ins_asc<NL>(lists[1], u1);
            }
        }

        // barrier B: staged tile landed block-wide.
        VMW(0);
        BARRIER();
    }
#undef KSTAGE

    // ---- in-kernel lq-merge: Khs is dead, reuse as scratch ----
    __syncthreads();                     // all waves past loop
    unsigned* msw = reinterpret_cast<unsigned*>(Khs[0]) + w * (16 * 4 * NL);
    #pragma unroll
    for (int sub = 0; sub < 2; ++sub) {
        #pragma unroll
        for (int p = 0; p < NL; ++p)
            msw[lc * (4 * NL) + lq * NL + p] = lists[sub][p];
        __syncthreads();
        if (lq == 0) {                   // 16 lanes/wave: one query each
            unsigned bk[NL];             // seed with lane-0 list (ascending)
            #pragma unroll
            for (int p = 0; p < NL; ++p) bk[p] = msw[lc * (4 * NL) + p];
            #pragma unroll
            for (int o = 1; o < 4; ++o)
                #pragma unroll
                for (int e = 0; e < NL; ++e)
                    ins_asc<NL>(bk, msw[lc * (4 * NL) + o * NL + e]);
            const int node = i0 + w * 32 + sub * 16 + lc;
            #pragma unroll
            for (int p = 0; p < NL; ++p)
                candV[((size_t)s * NL + p) * NN + node] = bk[p];
        }
        __syncthreads();
    }
}

// ------- final merge: 16 slice lists -> top-12 candidates per node ---------
__global__ __launch_bounds__(64)
void knn_merge_kernel(const unsigned* __restrict__ candV, int* __restrict__ CAND)
{
    const int q = blockIdx.x * 64 + threadIdx.x;
    unsigned bk[NCAND];
    #pragma unroll
    for (int p = 0; p < NCAND; ++p) bk[p] = 0xFFFFFFFFu;
    for (int s = 0; s < KNSL; ++s)
        #pragma unroll
        for (int e = 0; e < NL; ++e)
            ins_asc<NCAND>(bk, candV[((size_t)s * NL + e) * NN + q]);
    #pragma unroll
    for (int p = 0; p < NCAND; ++p)
        CAND[q * NCAND + p] = (int)(bk[p] & 8191u);
}

// ---------------- exact fp32 re-rank of candidates -> IDX ----------------
__global__ __launch_bounds__(256)
void rerank_kernel(const float* __restrict__ H, const float* __restrict__ SQ,
                   const int* __restrict__ CAND, int* __restrict__ IDX)
{
    const int t = threadIdx.x;
    const int w = t >> 6, l = t & 63;
    const int node = blockIdx.x * 4 + w;
    const float h0 = H[node * DD + l];
    const float h1 = H[node * DD + 64 + l];
    float dk[NCAND]; int di[NCAND];
    #pragma unroll
    for (int c = 0; c < NCAND; ++c) {
        const int j = CAND[node * NCAND + c];
        float p = h0 * H[j * DD + l] + h1 * H[j * DD + 64 + l];
        p += __shfl_xor(p, 1, 64);
        p += __shfl_xor(p, 2, 64);
        p += __shfl_xor(p, 4, 64);
        p += __shfl_xor(p, 8, 64);
        p += __shfl_xor(p, 16, 64);
        p += __shfl_xor(p, 32, 64);
        dk[c] = SQ[j] - 2.f * p;
        di[c] = j;
    }
    if (l == 0) {
        #pragma unroll
        for (int s = 0; s < KNB; ++s) {
            int best = s;
            #pragma unroll
            for (int c = s + 1; c < NCAND; ++c) {
                const bool lt = (dk[c] < dk[best]) ||
                                (dk[c] == dk[best] && di[c] < di[best]);
                if (lt) best = c;
            }
            const float tk = dk[s]; dk[s] = dk[best]; dk[best] = tk;
            const int   ti = di[s]; di[s] = di[best]; di[best] = ti;
            IDX[node * KNB + s] = di[s];
        }
    }
}

// -------- fused: H1 = relu((sum_nbr M1 + M1)/8 + b1); M2 = H1.W2 ----------
// One node per wave; lane l handles features l and l+64.  shfl_xor reduce
// in order 32,16,8,4,2,1 replays the old LDS tree pairing -> bit-identical.
__global__ __launch_bounds__(256)
void g1m2_kernel(const float* __restrict__ M1, const int* __restrict__ IDX,
                 const float* __restrict__ b1, const float* __restrict__ W2,
                 float* __restrict__ M2)
{
    const int t = threadIdx.x;
    const int w = t >> 6, l = t & 63;
    const int i = blockIdx.x * 4 + w;
    float s0 = M1[i * DD + l];
    float s1 = M1[i * DD + 64 + l];
    #pragma unroll
    for (int p = 0; p < KNB; ++p) {
        const int j = IDX[i * KNB + p];
        s0 += M1[j * DD + l];
        s1 += M1[j * DD + 64 + l];
    }
    const float g0 = fmaxf(s0 * 0.125f + b1[l], 0.f);
    const float g1 = fmaxf(s1 * 0.125f + b1[64 + l], 0.f);
    float r = g0 * W2[l] + g1 * W2[64 + l];   // == old red[l] after s2=64 step
    r += __shfl_xor(r, 32, 64);
    r += __shfl_xor(r, 16, 64);
    r += __shfl_xor(r, 8, 64);
    r += __shfl_xor(r, 4, 64);
    r += __shfl_xor(r, 2, 64);
    r += __shfl_xor(r, 1, 64);
    if (l == 0) M2[i] = r;
}

// ---------------- out = (sum_nbr M2 + M2)/8 + b2 ----------------
__global__ __launch_bounds__(256)
void out_kernel(const float* __restrict__ M2, const int* __restrict__ IDX,
                const float* __restrict__ b2, float* __restrict__ out)
{
    const int i = blockIdx.x * 256 + threadIdx.x;
    if (i < NN) {
        float s = M2[i];
        #pragma unroll
        for (int p = 0; p < KNB; ++p) s += M2[IDX[i * KNB + p]];
        out[i] = s * 0.125f + b2[0];
    }
}

// ---------------------------------------------------------------------------
extern "C" void kernel_launch(void* const* d_in, const int* in_sizes, int n_in,
                              void* d_out, int out_size, void* d_ws, size_t ws_size,
                              hipStream_t stream)
{
    const float* x   = (const float*)d_in[0];
    const float* Wq  = (const float*)d_in[1];
    const float* bq  = (const float*)d_in[2];
    const float* Wk  = (const float*)d_in[3];
    const float* bk  = (const float*)d_in[4];
    const float* Wv  = (const float*)d_in[5];
    const float* bv  = (const float*)d_in[6];
    const float* Wsk = (const float*)d_in[7];
    const float* bsk = (const float*)d_in[8];
    const float* W1  = (const float*)d_in[9];
    const float* b1  = (const float*)d_in[10];
    const float* W2  = (const float*)d_in[11];
    const float* b2  = (const float*)d_in[12];

    constexpr size_t MB = 1024 * 1024;
    char* W = (char*)d_ws;
    // persistent: [0,8) Q/K splits, [8,12) VT splits, [12,16) HS (->H in place)
    ushort_t* Qhi  = (ushort_t*)(W + 0 * MB);
    ushort_t* Qlo  = (ushort_t*)(W + 2 * MB);
    ushort_t* Khi  = (ushort_t*)(W + 4 * MB);
    ushort_t* Klo  = (ushort_t*)(W + 6 * MB);
    ushort_t* VThi = (ushort_t*)(W + 8 * MB);
    ushort_t* VTlo = (ushort_t*)(W + 10 * MB);
    float*    HS   = (float*)(W + 12 * MB);
    float*    H    = HS;                                   // in-place merge
    ushort_t* Hhi  = Qhi;            // Q dead after attn; Hhi written by merge
    // small: [16,17)
    float* lpart = (float*)(W + 16 * MB);                  // 256KB
    float* SQ    = (float*)(W + 16 * MB + 256 * 1024);     // 32KB
    float* M2    = SQ + NN;                                // 32KB
    int*   IDX   = (int*)(M2 + NN);                        // 224KB
    // union: [17,49):
    //   Opart [17,49)   read by fused attn_merge (M1 must NOT overlap!)
    //   candV [17,22.25) written by knn, dead after knn_merge (5.25MB)
    //   CAND  [23,23.4) written by knn_merge, dead after rerank
    // M1 at [49,53): outside Opart (fused merge writes M1 while reading
    // Opart).  ws >= 81MB confirmed (r19 big path ran).
    float*    Opart = (float*)(W + 17 * MB);
    unsigned* candV = (unsigned*)(W + 17 * MB);
    int*      CAND  = (int*)(W + 23 * MB);
    float*    M1    = (float*)(W + 49 * MB);

    proj_kernel<<<NN / PR, 128, 0, stream>>>(x, Wq, bq, Wk, bk, Wv, bv, Wsk, bsk,
                                             Qhi, Qlo, Khi, Klo, VThi, VTlo, HS);
    attn_kernel<<<ANS * 64, 256, 0, stream>>>(Qhi, Qlo, Khi, Klo, VThi, VTlo,
                                              Opart, lpart);
    attn_merge_kernel<<<(NN * 32) / 256, 256, 0, stream>>>(Opart, lpart, HS, H,
                                                           Hhi, SQ, W1, M1);
    knn_kernel<<<KNSL * 64, 256, 0, stream>>>(Hhi, SQ, candV);
    knn_merge_kernel<<<NN / 64, 64, 0, stream>>>(candV, CAND);
    rerank_kernel<<<NN / 4, 256, 0, stream>>>(H, SQ, CAND, IDX);
    g1m2_kernel<<<NN / 4, 256, 0, stream>>>(M1, IDX, b1, W2, M2);
    out_kernel<<<NN / 256, 256, 0, stream>>>(M2, IDX, b2, (float*)d_out);
}

// Round 14
// 308.732 us; speedup vs baseline: 1.0798x; 1.0013x over previous
//
#include <hip/hip_runtime.h>
#include <cmath>

// ---------------------------------------------------------------------------
// GraphTransformer on MI355X.  N=8192, D=128, k=7, OUT=1.
// Attention: split-bf16 (hi/lo) MFMA flash, fixed max (logits bounded).
//   FROZEN config (every deviation regressed):
//   - QK^T 3-term split (round-10: plain bf16 QK flips kNN neighbors)
//   - PSTR=40 row stride for P (round-12)
//   - swapped QK^T (A=K,B=Q) + packed-b64 P round-trip (r15)
//   - branchless med3 top-K insert in kNN (r16)
//   - cross-tile PV pipeline (r17); cvt_pk exp pack (r20)
//   - ANS=8 / grid 512 (2 blocks/CU is a hard occupancy cap)
//   - T4 counted-vmcnt pipeline in attn (r21: attn 93.6us best)
//   - g1m2 wave-per-node + mat1 fused into attn_merge (r23: -10us)
//   - vt fused into proj (r24); knn ported to gload_lds staging (r25: -11us)
// Round-26 (this round): HARDEN knn.  r25's rocprof showed one 30.45ms knn
// dispatch (normal ~8us; MfmaUtil 1.7, occ 6%) -- an intermittent stall in
// the raw s_barrier + sched_barrier(0) scheme at 4 blocks/CU (attn's same
// idiom at 2 blocks/CU has zero outliers in 5 rounds; buffer lifetimes
// re-audited safe; absmax 0.0 throughout).  Fix: knn's three raw barrier
// pairs -> plain __syncthreads() (adds only a 1-load drain at barrier A;
// staging still issues post-A, drains at B -> distance-phase overlap and
// all r25 gains preserved).  attn keeps its proven counted-vmcnt scheme.
// kNN: swapped-operand bf16 MFMA, per-lane register top-10 (u32-packed),
// in-kernel lq-merge -> candV, parallel final merge, exact fp32 re-rank.
// ---------------------------------------------------------------------------

typedef unsigned short ushort_t;

constexpr int   NN    = 8192;
constexpr int   DD    = 128;
constexpr int   KNB   = 7;
constexpr int   NL    = 10;              // per-lane kept candidates (knn)
constexpr int   NCAND = 12;              // merged candidates per node
constexpr float SCALE = 0.088388347648318447f;   // 1/sqrt(128)

using bf16x8 = __attribute__((ext_vector_type(8))) short;   // 8 bf16 = 4 VGPR
using f32x4  = __attribute__((ext_vector_type(4))) float;   // mfma acc

#define MFMA16(a, b, c) __builtin_amdgcn_mfma_f32_16x16x32_bf16((a), (b), (c), 0, 0, 0)

#define LGKM0() asm volatile("s_waitcnt lgkmcnt(0)" ::: "memory")
#define VMW(n)  asm volatile("s_waitcnt vmcnt(" #n ")" ::: "memory")
#define BARRIER() do { __builtin_amdgcn_s_barrier(); \
                       __builtin_amdgcn_sched_barrier(0); } while (0)

__device__ __forceinline__ ushort_t f2b(float f) {
    union { float f; unsigned int u; } v; v.f = f;
    return (ushort_t)((v.u + 0x8000u) >> 16);
}
__device__ __forceinline__ float b2f(ushort_t h) {
    union { unsigned int u; float f; } v; v.u = ((unsigned int)h) << 16;
    return v.f;
}

// direct global->LDS copy, 16B per lane; LDS dest is wave-uniform base + lane*16
__device__ __forceinline__ void gload16(const void* g, void* l) {
    __builtin_amdgcn_global_load_lds(
        (const __attribute__((address_space(1))) unsigned int*)g,
        (__attribute__((address_space(3))) unsigned int*)l, 16, 0, 0);
}

__device__ __forceinline__ unsigned umin_(unsigned a, unsigned b) { return a < b ? a : b; }
__device__ __forceinline__ unsigned umax_(unsigned a, unsigned b) { return a > b ? a : b; }

// Branchless top-K keep-smallest insert into ASCENDING sorted list
// (a[0] best .. a[K-1] worst).  med3 identity: since a[p-1] <= a[p],
//   new a[p] = med3(x, a[p-1], a[p]) = min(max(x, a[p-1]), a[p]).
// Kept SET identical to a guarded strict-less shift insert.  2 VALU
// ops/element, no branch, no divergence.
template<int K>
__device__ __forceinline__ void ins_asc(unsigned* a, unsigned x)
{
    #pragma unroll
    for (int p = K - 1; p >= 1; --p)
        a[p] = umin_(umax_(x, a[p - 1]), a[p]);
    a[0] = umin_(a[0], x);
}

// ----- projections: Q,K (split bf16), skip (f32), V DIRECT to VT splits ----
// 8 rows/block.  Thread t = feature t; its 8 per-node V values form one
// contiguous 16B chunk of VT[f][n] (vt_kernel fused away, bit-identical).
constexpr int PR = 8;
__global__ __launch_bounds__(128)
void proj_kernel(const float* __restrict__ x,
                 const float* __restrict__ Wq, const float* __restrict__ bq,
                 const float* __restrict__ Wk, const float* __restrict__ bk,
                 const float* __restrict__ Wv, const float* __restrict__ bv,
                 const float* __restrict__ Ws, const float* __restrict__ bs,
                 ushort_t* __restrict__ Qhi, ushort_t* __restrict__ Qlo,
                 ushort_t* __restrict__ Khi, ushort_t* __restrict__ Klo,
                 ushort_t* __restrict__ VThi, ushort_t* __restrict__ VTlo,
                 float* __restrict__ HS)
{
    __shared__ float xs[PR][DD];
    const int i0 = blockIdx.x * PR, t = threadIdx.x;
    #pragma unroll
    for (int r = 0; r < PR; ++r) xs[r][t] = x[(i0 + r) * DD + t];
    __syncthreads();
    float aq[PR], ak[PR], av[PR], ah[PR];
    #pragma unroll
    for (int r = 0; r < PR; ++r) { aq[r] = 0.f; ak[r] = 0.f; av[r] = 0.f; ah[r] = 0.f; }
    #pragma unroll 4
    for (int c = 0; c < DD; ++c) {
        const float wq = Wq[c * DD + t], wk = Wk[c * DD + t];
        const float wv = Wv[c * DD + t], ws = Ws[c * DD + t];
        #pragma unroll
        for (int r = 0; r < PR; ++r) {
            const float xv = xs[r][c];
            aq[r] = fmaf(xv, wq, aq[r]); ak[r] = fmaf(xv, wk, ak[r]);
            av[r] = fmaf(xv, wv, av[r]); ah[r] = fmaf(xv, ws, ah[r]);
        }
    }
    ushort_t vh8[PR], vl8[PR];
    #pragma unroll
    for (int r = 0; r < PR; ++r) {
        const int o = (i0 + r) * DD + t;
        const float q = aq[r] + bq[t];
        const float k = ak[r] + bk[t];
        const ushort_t qh = f2b(q); Qhi[o] = qh; Qlo[o] = f2b(q - b2f(qh));
        const ushort_t kh = f2b(k); Khi[o] = kh; Klo[o] = f2b(k - b2f(kh));
        const float v = av[r] + bv[t];
        const ushort_t vh = f2b(v);
        vh8[r] = vh; vl8[r] = f2b(v - b2f(vh));
        HS[o] = ah[r] + bs[t];
    }
    *reinterpret_cast<uint4*>(VThi + (size_t)t * NN + i0) =
        *reinterpret_cast<const uint4*>(vh8);
    *reinterpret_cast<uint4*>(VTlo + (size_t)t * NN + i0) =
        *reinterpret_cast<const uint4*>(vl8);
}

// ---------------- split-bf16 MFMA flash attention, fixed max ---------------
// 256-thread blocks (4 waves x 32 queries = 128 queries/block), grid 512.
// K/V DOUBLE-buffered via global_load_lds; K staged 2 windows ahead, V 1.
// Counted-vmcnt barriers (never 0 mid-loop); 2 blocks/CU.
constexpr int ANS  = 8;                 // key slices
constexpr int AKS  = NN / ANS;          // 1024 keys per slice
constexpr int BK   = 32;                // keys per tile
constexpr int PSTR = 40;                // P row stride (frozen)

__global__ __launch_bounds__(256, 2)
void attn_kernel(const ushort_t* __restrict__ Qhi, const ushort_t* __restrict__ Qlo,
                 const ushort_t* __restrict__ Khg, const ushort_t* __restrict__ Klg,
                 const ushort_t* __restrict__ Vhg, const ushort_t* __restrict__ Vlg,
                 float* __restrict__ Opart, float* __restrict__ lpart)
{
    // K tiles: 32 rows x 128 bf16, linear rows; chunk XOR-swizzled (c^row&7)
    //          on global source + read side -> conflict-free ds_read_b128.
    // V tiles: 128 rows x 32 bf16, chunk XOR-swizzled (c^(row>>1)&3).
    // P strip: 16 rows x PSTR per wave (row = query lc; sub0/sub1 reuse).
    // Buffer map: K(t) in K?s[t&1], V(t) in V?s[t&1].
    __shared__ __align__(16) ushort_t Khs[2][BK * DD];
    __shared__ __align__(16) ushort_t Kls[2][BK * DD];
    __shared__ __align__(16) ushort_t Vhs[2][DD * BK];
    __shared__ __align__(16) ushort_t Vls[2][DD * BK];
    __shared__ __align__(16) ushort_t Phs[4][16 * PSTR];
    __shared__ __align__(16) ushort_t Pls[4][16 * PSTR];

    const int t  = threadIdx.x;
    const int w  = t >> 6, l = t & 63;
    const int lc = l & 15, lq = l >> 4;
    const int b  = blockIdx.x;
    const int s  = b >> 6;              // slice 0..7
    const int qb = b & 63;
    const int i0 = qb * 128;
    const int k0 = s * AKS;
    ushort_t* Pwh = Phs[w];
    ushort_t* Pwl = Pls[w];

    // staging coordinates (per thread, loop-invariant).
    const int lrK = w * 4 + (l >> 4);
    const int kchunk = ((l & 15) ^ (lrK & 7)) * 8;
    const ushort_t* gKh = Khg + (size_t)(k0 + lrK) * DD + kchunk;
    const ushort_t* gKl = Klg + (size_t)(k0 + lrK) * DD + kchunk;
    const int lrV = w * 16 + (l >> 2);
    const int vchunk = ((l & 3) ^ ((l >> 3) & 3)) * 8;
    const ushort_t* gVh = Vhg + (size_t)lrV * NN + k0 + vchunk;
    const ushort_t* gVl = Vlg + (size_t)lrV * NN + k0 + vchunk;

#define STAGE_K(buf, koff) do {                                              \
    gload16(gKh + (size_t)(koff) * DD,        &Khs[buf][(w * 4) * DD]);      \
    gload16(gKh + (size_t)((koff) + 16) * DD, &Khs[buf][(16 + w * 4) * DD]); \
    gload16(gKl + (size_t)(koff) * DD,        &Kls[buf][(w * 4) * DD]);      \
    gload16(gKl + (size_t)((koff) + 16) * DD, &Kls[buf][(16 + w * 4) * DD]); \
  } while (0)
#define STAGE_V(buf, koff) do {                                              \
    gload16(gVh + (koff),                     &Vhs[buf][(w * 16) * BK]);     \
    gload16(gVh + (size_t)64 * NN + (koff),   &Vhs[buf][(64 + w * 16) * BK]);\
    gload16(gVl + (koff),                     &Vls[buf][(w * 16) * BK]);     \
    gload16(gVl + (size_t)64 * NN + (koff),   &Vls[buf][(64 + w * 16) * BK]);\
  } while (0)

    bf16x8 qh[2][4], ql[2][4];
    #pragma unroll
    for (int sub = 0; sub < 2; ++sub) {
        const int row = i0 + w * 32 + sub * 16 + lc;
        #pragma unroll
        for (int kb = 0; kb < 4; ++kb) {
            qh[sub][kb] = *reinterpret_cast<const bf16x8*>(Qhi + row * DD + kb * 32 + lq * 8);
            ql[sub][kb] = *reinterpret_cast<const bf16x8*>(Qlo + row * DD + kb * 32 + lq * 8);
        }
    }

    const f32x4 zz = {0.f, 0.f, 0.f, 0.f};
    f32x4 oacc[2][8];
    #pragma unroll
    for (int sub = 0; sub < 2; ++sub)
        #pragma unroll
        for (int ft = 0; ft < 8; ++ft) oacc[sub][ft] = zz;
    float lrow[2] = {0.f, 0.f};         // per-lane partial denom, query = lc

    bf16x8 pah[2] = {}, pal[2] = {};    // carried P fragments (tile t-1)
    const int vc = (lq ^ ((lc >> 1) & 3)) * 8;   // V read-side unswizzle

    // prologue: K(0), K(1), V(0) issued; wait K(0) (allow 8 newer in flight)
    STAGE_K(0, 0);
    STAGE_K(1, BK);
    STAGE_V(0, 0);
    VMW(8);
    BARRIER();

    constexpr int NT = AKS / BK;        // 32 tiles
    for (int it = 0; it < NT; ++it) {
        const int jt  = k0 + it * BK;
        const int cur = it & 1;
        const ushort_t* Kh = Khs[cur];
        const ushort_t* Kl = Kls[cur];
        const ushort_t* Vph = Vhs[cur ^ 1];   // V(t-1)
        const ushort_t* Vpl = Vls[cur ^ 1];

        // ---- S^T = K Q^T (swapped: A=K, B=Q; bit-identical products) ----
        f32x4 sacc[2][2];               // [sub][kt]
        #pragma unroll
        for (int sub = 0; sub < 2; ++sub)
            #pragma unroll
            for (int kt = 0; kt < 2; ++kt) sacc[sub][kt] = zz;
        __builtin_amdgcn_s_setprio(1);
        #pragma unroll
        for (int kt = 0; kt < 2; ++kt) {
            const int kro = (kt * 16 + lc) * DD;
            #pragma unroll
            for (int kb = 0; kb < 4; ++kb) {
                const int cp = ((kb * 4 + lq) ^ (lc & 7)) * 8;  // read-side unswizzle
                const bf16x8 kh = *reinterpret_cast<const bf16x8*>(&Kh[kro + cp]);
                const bf16x8 kl = *reinterpret_cast<const bf16x8*>(&Kl[kro + cp]);
                #pragma unroll
                for (int sub = 0; sub < 2; ++sub) {
                    sacc[sub][kt] = MFMA16(kh, qh[sub][kb], sacc[sub][kt]);
                    sacc[sub][kt] = MFMA16(kh, ql[sub][kb], sacc[sub][kt]);
                    sacc[sub][kt] = MFMA16(kl, qh[sub][kb], sacc[sub][kt]);
                }
            }
        }
        __builtin_amdgcn_s_setprio(0);

        // ---- O += P(t-1) V(t-1) ----
        if (it > 0) {
            __builtin_amdgcn_s_setprio(1);
            #pragma unroll
            for (int ft = 0; ft < 8; ++ft) {
                const bf16x8 vh = *reinterpret_cast<const bf16x8*>(
                    &Vph[(ft * 16 + lc) * BK + vc]);
                const bf16x8 vl = *reinterpret_cast<const bf16x8*>(
                    &Vpl[(ft * 16 + lc) * BK + vc]);
                #pragma unroll
                for (int sub = 0; sub < 2; ++sub) {
                    oacc[sub][ft] = MFMA16(pah[sub], vh, oacc[sub][ft]);
                    oacc[sub][ft] = MFMA16(pal[sub], vh, oacc[sub][ft]);
                    oacc[sub][ft] = MFMA16(pah[sub], vl, oacc[sub][ft]);
                }
            }
            __builtin_amdgcn_s_setprio(0);
        }

        // barrier1: all waves' K(t)/V(t-1) ds_reads retired (lgkm only —
        // staged loads stay in flight).
        LGKM0();
        BARRIER();

        // deep prefetch: K(t+2) overwrites K(t)'s buffer (reads retired);
        // V(t+1) overwrites V(t-1)'s buffer (reads retired).
        if (it <= NT - 3) STAGE_K(cur, (it + 2) * BK);
        if (it <= NT - 2) STAGE_V(cur ^ 1, (it + 1) * BK);

        if ((jt & ~127) == i0) {            // diagonal mask
            #pragma unroll
            for (int sub = 0; sub < 2; ++sub) {
                const int gq = i0 + w * 32 + sub * 16 + lc;
                #pragma unroll
                for (int kt = 0; kt < 2; ++kt)
                    #pragma unroll
                    for (int r = 0; r < 4; ++r) {
                        const int gk = jt + kt * 16 + lq * 4 + r;
                        if (gk == gq) sacc[sub][kt][r] = -INFINITY;
                    }
            }
        }
        // ---- P = exp(S*SCALE): cvt_pk split; b64 write, b128 read to regs
        #pragma unroll
        for (int sub = 0; sub < 2; ++sub) {
            #pragma unroll
            for (int kt = 0; kt < 2; ++kt) {
                unsigned wh[2], wl[2];
                #pragma unroll
                for (int rr = 0; rr < 2; ++rr) {
                    const float p0 = __expf(sacc[sub][kt][rr * 2 + 0] * SCALE);
                    const float p1 = __expf(sacc[sub][kt][rr * 2 + 1] * SCALE);
                    lrow[sub] += p0;
                    lrow[sub] += p1;
                    unsigned hpk;
                    asm("v_cvt_pk_bf16_f32 %0, %1, %2"
                        : "=v"(hpk) : "v"(p0), "v"(p1));
                    wh[rr] = hpk;
                    const float h0 = __uint_as_float(hpk << 16);
                    const float h1 = __uint_as_float(hpk & 0xFFFF0000u);
                    unsigned lpk;
                    asm("v_cvt_pk_bf16_f32 %0, %1, %2"
                        : "=v"(lpk) : "v"(p0 - h0), "v"(p1 - h1));
                    wl[rr] = lpk;
                }
                const int eo = lc * PSTR + kt * 16 + lq * 4;
                *reinterpret_cast<uint2*>(&Pwh[eo]) = make_uint2(wh[0], wh[1]);
                *reinterpret_cast<uint2*>(&Pwl[eo]) = make_uint2(wl[0], wl[1]);
            }
            pah[sub] = *reinterpret_cast<const bf16x8*>(&Pwh[lc * PSTR + lq * 8]);
            pal[sub] = *reinterpret_cast<const bf16x8*>(&Pwl[lc * PSTR + lq * 8]);
        }

        // barrier2: K(t+1), V(t) landed block-wide; K(t+2)/V(t+1) (the 8
        // newest loads) stay in flight across the barrier.
        if (it <= NT - 3)      { VMW(8); }
        else if (it == NT - 2) { VMW(4); }
        else                   { VMW(0); }
        BARRIER();
    }
    // ---- epilogue: PV(NT-1); V(NT-1) in buffer (NT-1)&1 ----
    {
        const ushort_t* Vh = Vhs[(NT - 1) & 1];
        const ushort_t* Vl = Vls[(NT - 1) & 1];
        #pragma unroll
        for (int ft = 0; ft < 8; ++ft) {
            const bf16x8 vh = *reinterpret_cast<const bf16x8*>(
                &Vh[(ft * 16 + lc) * BK + vc]);
            const bf16x8 vl = *reinterpret_cast<const bf16x8*>(
                &Vl[(ft * 16 + lc) * BK + vc]);
            #pragma unroll
            for (int sub = 0; sub < 2; ++sub) {
                oacc[sub][ft] = MFMA16(pah[sub], vh, oacc[sub][ft]);
                oacc[sub][ft] = MFMA16(pal[sub], vh, oacc[sub][ft]);
                oacc[sub][ft] = MFMA16(pah[sub], vl, oacc[sub][ft]);
            }
        }
    }
#undef STAGE_K
#undef STAGE_V

    // denom: lane holds partial for query=lc over keys lq*4+r; reduce over lq.
    #pragma unroll
    for (int sub = 0; sub < 2; ++sub) {
        float ps = lrow[sub];
        ps += __shfl_xor(ps, 16, 64);
        ps += __shfl_xor(ps, 32, 64);
        lrow[sub] = ps;
    }
    #pragma unroll
    for (int sub = 0; sub < 2; ++sub) {
        #pragma unroll
        for (int r = 0; r < 4; ++r) {
            const int row = i0 + w * 32 + sub * 16 + lq * 4 + r;
            float* po = Opart + ((size_t)s * NN + row) * DD;
            #pragma unroll
            for (int ft = 0; ft < 8; ++ft) po[ft * 16 + lc] = oacc[sub][ft][r];
        }
        if (l < 16)
            lpart[s * NN + i0 + w * 32 + sub * 16 + l] = lrow[sub];
    }
}

// ------- merge slices + skip, emit H/Hhi/SQ; FUSED mat1 (M1 = H @ W1) -----
// Phase 1: 32 threads/node, 4 features each.  h quads also go to an 8x132
// LDS tile.  Phase 2 (after one barrier): 2 halves x 128 cols, 4 rows each;
// c-sequential fmaf chain == old mat1 -> bit-identical M1.
__global__ __launch_bounds__(256)
void attn_merge_kernel(const float* __restrict__ Opart, const float* __restrict__ lpart,
                       const float* __restrict__ HS, float* __restrict__ H,
                       ushort_t* __restrict__ Hhi, float* __restrict__ SQ,
                       const float* __restrict__ W1, float* __restrict__ M1)
{
    __shared__ float xs[8][132];
    const int t = threadIdx.x;
    const int gid = blockIdx.x * 256 + t;
    const int i = gid >> 5;             // node
    const int f = (gid & 31) * 4;       // feature quad
    float ls = 0.f;
    float4 o = {0.f, 0.f, 0.f, 0.f};
    #pragma unroll
    for (int s = 0; s < ANS; ++s) {
        ls += lpart[s * NN + i];
        const float4 ov = *reinterpret_cast<const float4*>(
            Opart + ((size_t)s * NN + i) * DD + f);
        o.x += ov.x; o.y += ov.y; o.z += ov.z; o.w += ov.w;
    }
    const float4 hs = *reinterpret_cast<const float4*>(HS + i * DD + f);
    const float inv = 1.f / ls;
    float4 h;
    h.x = o.x * inv + hs.x; h.y = o.y * inv + hs.y;
    h.z = o.z * inv + hs.z; h.w = o.w * inv + hs.w;
    *reinterpret_cast<float4*>(H + i * DD + f) = h;
    *reinterpret_cast<float4*>(&xs[t >> 5][f]) = h;
    ushort_t hb[4] = {f2b(h.x), f2b(h.y), f2b(h.z), f2b(h.w)};
    *reinterpret_cast<uint2*>(Hhi + i * DD + f) = *reinterpret_cast<const uint2*>(hb);
    float sq = h.x * h.x + h.y * h.y + h.z * h.z + h.w * h.w;
    sq += __shfl_xor(sq, 1, 64);
    sq += __shfl_xor(sq, 2, 64);
    sq += __shfl_xor(sq, 4, 64);
    sq += __shfl_xor(sq, 8, 64);
    sq += __shfl_xor(sq, 16, 64);       // xor<32 stays within the 32-lane node group
    if ((t & 31) == 0) SQ[i] = sq;

    __syncthreads();                    // xs tile complete
    // ---- mat1 phase: rows = this block's 8 nodes ----
    const int col = t & 127, half = t >> 7;   // half 0: rows 0-3; half 1: rows 4-7
    float a[4] = {0.f, 0.f, 0.f, 0.f};
    #pragma unroll 4
    for (int c = 0; c < DD; ++c) {
        const float wv = W1[c * DD + col];
        #pragma unroll
        for (int r = 0; r < 4; ++r)
            a[r] = fmaf(xs[half * 4 + r][c], wv, a[r]);
    }
    const int n0 = blockIdx.x * 8 + half * 4;
    #pragma unroll
    for (int r = 0; r < 4; ++r)
        M1[(n0 + r) * DD + col] = a[r];
}

// ---------------- kNN: swapped-operand MFMA, register top-NL (u32) ---------
// K tiles: 64 rows x 128 bf16, LINEAR, double-buffered, staged by
// global_load_lds (source chunk XOR-swizzled c^(row&7); read-side unswizzle
// identical to attn's K).  __syncthreads barriers (r26 hardening); staging
// still issues post-barrier-A so the distance phase covers its flight.
constexpr int KNSL = 16;                // key slices (512 keys each)
constexpr int KSL  = NN / KNSL;         // 512

__global__ __launch_bounds__(256, 4)
void knn_kernel(const ushort_t* __restrict__ Hhi, const float* __restrict__ SQg,
                unsigned* __restrict__ candV)
{
    __shared__ __align__(16) ushort_t Khs[2][64 * DD];
    __shared__ __align__(16) float sqs[2][64];

    const int t  = threadIdx.x;
    const int w  = t >> 6, l = t & 63;
    const int lc = l & 15, lq = l >> 4;
    const int b  = blockIdx.x;
    const int s  = b >> 6;              // slice 0..15
    const int qb = b & 63;
    const int i0 = qb * 128;
    const int k0 = s * KSL;

    // staging: call p covers rows p*16 + w*4 + (l>>4); source chunk
    // (l&15)^(row&7) with row&7 invariant under +16.  Linear LDS dest.
    const int srow = w * 4 + (l >> 4);
    const int schunk = ((l & 15) ^ (srow & 7)) * 8;
    const ushort_t* gH = Hhi + (size_t)(k0 + srow) * DD + schunk;

#define KSTAGE(buf, koff) do {                                               \
    gload16(gH + (size_t)((koff) +  0) * DD, &Khs[buf][( 0 + w * 4) * DD]);  \
    gload16(gH + (size_t)((koff) + 16) * DD, &Khs[buf][(16 + w * 4) * DD]);  \
    gload16(gH + (size_t)((koff) + 32) * DD, &Khs[buf][(32 + w * 4) * DD]);  \
    gload16(gH + (size_t)((koff) + 48) * DD, &Khs[buf][(48 + w * 4) * DD]);  \
  } while (0)

    const int gq0 = i0 + w * 32 + lc;          // sub=0 query
    const int gq1 = gq0 + 16;                  // sub=1 query
    const float sqi0 = SQg[gq0];
    const float sqi1 = SQg[gq1];

    bf16x8 qf[2][4];                    // B operand: B[n=query=lc][k=lq*8+j]
    #pragma unroll
    for (int sub = 0; sub < 2; ++sub) {
        const int row = i0 + w * 32 + sub * 16 + lc;
        #pragma unroll
        for (int kb = 0; kb < 4; ++kb)
            qf[sub][kb] = *reinterpret_cast<const bf16x8*>(Hhi + row * DD + kb * 32 + lq * 8);
    }

    unsigned lists[2][NL];              // ascending: [0] best .. [NL-1] worst
    #pragma unroll
    for (int sub = 0; sub < 2; ++sub)
        #pragma unroll
        for (int p = 0; p < NL; ++p) lists[sub][p] = 0xFFFFFFFFu;

    // prologue: stage tile 0; prefetch sqs(0) to register
    KSTAGE(0, 0);
    float psq = (t < 64) ? SQg[k0 + t] : 0.f;
    __syncthreads();                    // tile 0 landed (full drain + barrier)

    const f32x4 zz = {0.f, 0.f, 0.f, 0.f};
    constexpr int KNT = KSL / 64;       // 8 tiles
    for (int ti = 0; ti < KNT; ++ti) {
        const int jt  = k0 + ti * 64;
        const int cur = ti & 1;

        // sqs(t) visible after barrier A below; prefetch sqs(t+1) register.
        if (t < 64) sqs[cur][t] = psq;
        if (ti + 1 < KNT) psq = (t < 64) ? SQg[jt + 64 + t] : 0.f;

        // ---- MFMA phase: reads Khs[cur] ----
        f32x4 acc[2][4];                 // [sub][kt]
        #pragma unroll
        for (int sub = 0; sub < 2; ++sub)
            #pragma unroll
            for (int kt = 0; kt < 4; ++kt) acc[sub][kt] = zz;
        #pragma unroll
        for (int kt = 0; kt < 4; ++kt) {
            const int kro = (kt * 16 + lc) * DD;
            #pragma unroll
            for (int kb = 0; kb < 4; ++kb) {
                const int cp = ((kb * 4 + lq) ^ (lc & 7)) * 8;  // unswizzle
                const bf16x8 kf = *reinterpret_cast<const bf16x8*>(&Khs[cur][kro + cp]);
                acc[0][kt] = MFMA16(kf, qf[0][kb], acc[0][kt]);   // A=key, B=query
                acc[1][kt] = MFMA16(kf, qf[1][kb], acc[1][kt]);
            }
        }

        // barrier A: K reads retired block-wide; sqs[cur] writes visible.
        __syncthreads();

        // stage next tile into the other buffer; distance phase covers it.
        if (ti + 1 < KNT) KSTAGE(cur ^ 1, (ti + 1) * 64);

        const bool ovl = ((jt & ~127) == i0);
        #pragma unroll
        for (int kt = 0; kt < 4; ++kt) {
            const float4 sq4 = *reinterpret_cast<const float4*>(&sqs[cur][kt * 16 + lq * 4]);
            const float sqj[4] = {sq4.x, sq4.y, sq4.z, sq4.w};
            #pragma unroll
            for (int r = 0; r < 4; ++r) {
                const int gk = jt + kt * 16 + lq * 4 + r;
                float d0 = fmaf(-2.f, acc[0][kt][r], sqi0 + sqj[r]);
                float d1 = fmaf(-2.f, acc[1][kt][r], sqi1 + sqj[r]);
                if (ovl) {
                    if (gk == gq0) d0 = INFINITY;
                    if (gk == gq1) d1 = INFINITY;
                }
                const unsigned u0 = (__float_as_uint(d0) & 0xFFFFE000u) | (unsigned)gk;
                const unsigned u1 = (__float_as_uint(d1) & 0xFFFFE000u) | (unsigned)gk;
                ins_asc<NL>(lists[0], u0);
                ins_asc<NL>(lists[1], u1);
            }
        }

        // barrier B: staged tile landed block-wide (full drain + barrier).
        __syncthreads();
    }
#undef KSTAGE

    // ---- in-kernel lq-merge: Khs is dead, reuse as scratch ----
    unsigned* msw = reinterpret_cast<unsigned*>(Khs[0]) + w * (16 * 4 * NL);
    #pragma unroll
    for (int sub = 0; sub < 2; ++sub) {
        #pragma unroll
        for (int p = 0; p < NL; ++p)
            msw[lc * (4 * NL) + lq * NL + p] = lists[sub][p];
        __syncthreads();
        if (lq == 0) {                   // 16 lanes/wave: one query each
            unsigned bk[NL];             // seed with lane-0 list (ascending)
            #pragma unroll
            for (int p = 0; p < NL; ++p) bk[p] = msw[lc * (4 * NL) + p];
            #pragma unroll
            for (int o = 1; o < 4; ++o)
                #pragma unroll
                for (int e = 0; e < NL; ++e)
                    ins_asc<NL>(bk, msw[lc * (4 * NL) + o * NL + e]);
            const int node = i0 + w * 32 + sub * 16 + lc;
            #pragma unroll
            for (int p = 0; p < NL; ++p)
                candV[((size_t)s * NL + p) * NN + node] = bk[p];
        }
        __syncthreads();
    }
}

// ------- final merge: 16 slice lists -> top-12 candidates per node ---------
__global__ __launch_bounds__(64)
void knn_merge_kernel(const unsigned* __restrict__ candV, int* __restrict__ CAND)
{
    const int q = blockIdx.x * 64 + threadIdx.x;
    unsigned bk[NCAND];
    #pragma unroll
    for (int p = 0; p < NCAND; ++p) bk[p] = 0xFFFFFFFFu;
    for (int s = 0; s < KNSL; ++s)
        #pragma unroll
        for (int e = 0; e < NL; ++e)
            ins_asc<NCAND>(bk, candV[((size_t)s * NL + e) * NN + q]);
    #pragma unroll
    for (int p = 0; p < NCAND; ++p)
        CAND[q * NCAND + p] = (int)(bk[p] & 8191u);
}

// ---------------- exact fp32 re-rank of candidates -> IDX ----------------
__global__ __launch_bounds__(256)
void rerank_kernel(const float* __restrict__ H, const float* __restrict__ SQ,
                   const int* __restrict__ CAND, int* __restrict__ IDX)
{
    const int t = threadIdx.x;
    const int w = t >> 6, l = t & 63;
    const int node = blockIdx.x * 4 + w;
    const float h0 = H[node * DD + l];
    const float h1 = H[node * DD + 64 + l];
    float dk[NCAND]; int di[NCAND];
    #pragma unroll
    for (int c = 0; c < NCAND; ++c) {
        const int j = CAND[node * NCAND + c];
        float p = h0 * H[j * DD + l] + h1 * H[j * DD + 64 + l];
        p += __shfl_xor(p, 1, 64);
        p += __shfl_xor(p, 2, 64);
        p += __shfl_xor(p, 4, 64);
        p += __shfl_xor(p, 8, 64);
        p += __shfl_xor(p, 16, 64);
        p += __shfl_xor(p, 32, 64);
        dk[c] = SQ[j] - 2.f * p;
        di[c] = j;
    }
    if (l == 0) {
        #pragma unroll
        for (int s = 0; s < KNB; ++s) {
            int best = s;
            #pragma unroll
            for (int c = s + 1; c < NCAND; ++c) {
                const bool lt = (dk[c] < dk[best]) ||
                                (dk[c] == dk[best] && di[c] < di[best]);
                if (lt) best = c;
            }
            const float tk = dk[s]; dk[s] = dk[best]; dk[best] = tk;
            const int   ti = di[s]; di[s] = di[best]; di[best] = ti;
            IDX[node * KNB + s] = di[s];
        }
    }
}

// -------- fused: H1 = relu((sum_nbr M1 + M1)/8 + b1); M2 = H1.W2 ----------
// One node per wave; lane l handles features l and l+64.  shfl_xor reduce
// in order 32,16,8,4,2,1 replays the old LDS tree pairing -> bit-identical.
__global__ __launch_bounds__(256)
void g1m2_kernel(const float* __restrict__ M1, const int* __restrict__ IDX,
                 const float* __restrict__ b1, const float* __restrict__ W2,
                 float* __restrict__ M2)
{
    const int t = threadIdx.x;
    const int w = t >> 6, l = t & 63;
    const int i = blockIdx.x * 4 + w;
    float s0 = M1[i * DD + l];
    float s1 = M1[i * DD + 64 + l];
    #pragma unroll
    for (int p = 0; p < KNB; ++p) {
        const int j = IDX[i * KNB + p];
        s0 += M1[j * DD + l];
        s1 += M1[j * DD + 64 + l];
    }
    const float g0 = fmaxf(s0 * 0.125f + b1[l], 0.f);
    const float g1 = fmaxf(s1 * 0.125f + b1[64 + l], 0.f);
    float r = g0 * W2[l] + g1 * W2[64 + l];   // == old red[l] after s2=64 step
    r += __shfl_xor(r, 32, 64);
    r += __shfl_xor(r, 16, 64);
    r += __shfl_xor(r, 8, 64);
    r += __shfl_xor(r, 4, 64);
    r += __shfl_xor(r, 2, 64);
    r += __shfl_xor(r, 1, 64);
    if (l == 0) M2[i] = r;
}

// ---------------- out = (sum_nbr M2 + M2)/8 + b2 ----------------
__global__ __launch_bounds__(256)
void out_kernel(const float* __restrict__ M2, const int* __restrict__ IDX,
                const float* __restrict__ b2, float* __restrict__ out)
{
    const int i = blockIdx.x * 256 + threadIdx.x;
    if (i < NN) {
        float s = M2[i];
        #pragma unroll
        for (int p = 0; p < KNB; ++p) s += M2[IDX[i * KNB + p]];
        out[i] = s * 0.125f + b2[0];
    }
}

// ---------------------------------------------------------------------------
extern "C" void kernel_launch(void* const* d_in, const int* in_sizes, int n_in,
                              void* d_out, int out_size, void* d_ws, size_t ws_size,
                              hipStream_t stream)
{
    const float* x   = (const float*)d_in[0];
    const float* Wq  = (const float*)d_in[1];
    const float* bq  = (const float*)d_in[2];
    const float* Wk  = (const float*)d_in[3];
    const float* bk  = (const float*)d_in[4];
    const float* Wv  = (const float*)d_in[5];
    const float* bv  = (const float*)d_in[6];
    const float* Wsk = (const float*)d_in[7];
    const float* bsk = (const float*)d_in[8];
    const float* W1  = (const float*)d_in[9];
    const float* b1  = (const float*)d_in[10];
    const float* W2  = (const float*)d_in[11];
    const float* b2  = (const float*)d_in[12];

    constexpr size_t MB = 1024 * 1024;
    char* W = (char*)d_ws;
    // persistent: [0,8) Q/K splits, [8,12) VT splits, [12,16) HS (->H in place)
    ushort_t* Qhi  = (ushort_t*)(W + 0 * MB);
    ushort_t* Qlo  = (ushort_t*)(W + 2 * MB);
    ushort_t* Khi  = (ushort_t*)(W + 4 * MB);
    ushort_t* Klo  = (ushort_t*)(W + 6 * MB);
    ushort_t* VThi = (ushort_t*)(W + 8 * MB);
    ushort_t* VTlo = (ushort_t*)(W + 10 * MB);
    float*    HS   = (float*)(W + 12 * MB);
    float*    H    = HS;                                   // in-place merge
    ushort_t* Hhi  = Qhi;            // Q dead after attn; Hhi written by merge
    // small: [16,17)
    float* lpart = (float*)(W + 16 * MB);                  // 256KB
    float* SQ    = (float*)(W + 16 * MB + 256 * 1024);     // 32KB
    float* M2    = SQ + NN;                                // 32KB
    int*   IDX   = (int*)(M2 + NN);                        // 224KB
    // union: [17,49):
    //   Opart [17,49)   read by fused attn_merge (M1 must NOT overlap!)
    //   candV [17,22.25) written by knn, dead after knn_merge (5.25MB)
    //   CAND  [23,23.4) written by knn_merge, dead after rerank
    // M1 at [49,53): outside Opart (fused merge writes M1 while reading
    // Opart).  ws >= 81MB confirmed (r19 big path ran).
    float*    Opart = (float*)(W + 17 * MB);
    unsigned* candV = (unsigned*)(W + 17 * MB);
    int*      CAND  = (int*)(W + 23 * MB);
    float*    M1    = (float*)(W + 49 * MB);

    proj_kernel<<<NN / PR, 128, 0, stream>>>(x, Wq, bq, Wk, bk, Wv, bv, Wsk, bsk,
                                             Qhi, Qlo, Khi, Klo, VThi, VTlo, HS);
    attn_kernel<<<ANS * 64, 256, 0, stream>>>(Qhi, Qlo, Khi, Klo, VThi, VTlo,
                                              Opart, lpart);
    attn_merge_kernel<<<(NN * 32) / 256, 256, 0, stream>>>(Opart, lpart, HS, H,
                                                           Hhi, SQ, W1, M1);
    knn_kernel<<<KNSL * 64, 256, 0, stream>>>(Hhi, SQ, candV);
    knn_merge_kernel<<<NN / 64, 64, 0, stream>>>(candV, CAND);
    rerank_kernel<<<NN / 4, 256, 0, stream>>>(H, SQ, CAND, IDX);
    g1m2_kernel<<<NN / 4, 256, 0, stream>>>(M1, IDX, b1, W2, M2);
    out_kernel<<<NN / 256, 256, 0, stream>>>(M2, IDX, b2, (float*)d_out);
}